// Round 1
// baseline (306.595 us; speedup 1.0000x reference)
//
#include <hip/hip_runtime.h>

typedef unsigned short u16;
typedef unsigned int u32;
typedef __bf16 bf16x8 __attribute__((ext_vector_type(8)));
typedef float f32x4 __attribute__((ext_vector_type(4)));

#define NBATCH 8
#define NPT    2048
#define NPTS   16384     // NBATCH*NPT
#define INDIM  256
#define DD     512
#define GG     64        // 8x8 grid cells
#define MEANROWS 640     // 512 mean rows + 9 pe rows, padded to 128-multiple

__device__ __forceinline__ u16 f2bf(float f){
  u32 u = __builtin_bit_cast(u32, f);
  u += 0x7fffu + ((u >> 16) & 1u);
  return (u16)(u >> 16);
}
__device__ __forceinline__ void load8(const float* __restrict__ p, float* r){
  float4 a = *(const float4*)p;
  float4 b = *(const float4*)(p + 4);
  r[0]=a.x;r[1]=a.y;r[2]=a.z;r[3]=a.w;r[4]=b.x;r[5]=b.y;r[6]=b.z;r[7]=b.w;
}
__device__ __forceinline__ void store8(float* __restrict__ p, const float* r){
  float4 a; a.x=r[0];a.y=r[1];a.z=r[2];a.w=r[3];
  float4 b; b.x=r[4];b.y=r[5];b.z=r[6];b.w=r[7];
  *(float4*)p = a; *(float4*)(p+4) = b;
}

// ---------------- elementwise f32 -> bf16 ----------------
__global__ void f2bf_kernel(const float* __restrict__ in, u16* __restrict__ out, int n){
  int i = blockIdx.x*256 + threadIdx.x;
  if (i < n) out[i] = f2bf(in[i]);
}

// ---------------- transpose f32[K][N] -> bf16[N][K] ----------------
__global__ void transpose_bf16_kernel(const float* __restrict__ in, u16* __restrict__ out, int K, int N){
  int i = blockIdx.x*256 + threadIdx.x;
  if (i < K*N){
    int k = i / N, n = i - k*N;
    out[(size_t)n*K + k] = f2bf(in[i]);
  }
}

// ---------------- cell ids ----------------
__global__ void cell_kernel(const float* __restrict__ coords, int* __restrict__ cell, int n){
  int i = blockIdx.x*256 + threadIdx.x;
  if (i < n){
    float x = coords[2*i], y = coords[2*i+1];
    int gx = (int)(x * (1.0f/32.0f)); gx = gx < 0 ? 0 : (gx > 7 ? 7 : gx);
    int gy = (int)(y * (1.0f/32.0f)); gy = gy < 0 ? 0 : (gy > 7 ? 7 : gy);
    cell[i] = gx*8 + gy;
  }
}

// ---------------- deterministic segment mean: one block per (b,g) ----------------
__global__ __launch_bounds__(256) void bucket_kernel(
    const float* __restrict__ feat, const int* __restrict__ cell,
    u16* __restrict__ meanA, int* __restrict__ counts)
{
  int bg = blockIdx.x;          // 0..511
  int b = bg >> 6, g = bg & 63;
  __shared__ int lc[NPT];
  for (int i = threadIdx.x; i < NPT; i += 256) lc[i] = cell[b*NPT + i];
  __syncthreads();
  int t = threadIdx.x;
  float a0 = 0.f, a1 = 0.f; int cnt = 0;
  for (int n = 0; n < NPT; n++){
    if (lc[n] == g){
      const float* fr = feat + (size_t)(b*NPT + n)*DD;
      a0 += fr[t]; a1 += fr[t+256]; cnt++;
    }
  }
  float inv = 1.f / (float)(cnt > 0 ? cnt : 1);
  meanA[(size_t)bg*DD + t]       = f2bf(a0*inv);
  meanA[(size_t)bg*DD + t + 256] = f2bf(a1*inv);
  if (t == 0) counts[bg] = cnt;
}

// ---------------- pos-enc MLP: one block per offset kk, writes meanA rows 512..520 ----------------
__global__ __launch_bounds__(256) void pe_kernel(
    const float* __restrict__ W_p1, const float* __restrict__ b_p1,
    const float* __restrict__ W_p2, const float* __restrict__ b_p2,
    u16* __restrict__ meanA)
{
  int kk = blockIdx.x;          // 0..8
  float dx = (float)(kk/3 - 1), dy = (float)(kk%3 - 1);
  __shared__ float h[256];
  int t = threadIdx.x;
  float hv = dx*W_p1[t] + dy*W_p1[256 + t] + b_p1[t];
  h[t] = hv > 0.f ? hv : 0.f;
  __syncthreads();
  float acc0 = b_p2[t], acc1 = b_p2[t + 256];
  for (int c = 0; c < 256; c++){
    float hc = h[c];
    acc0 += hc * W_p2[(size_t)c*DD + t];
    acc1 += hc * W_p2[(size_t)c*DD + t + 256];
  }
  meanA[(size_t)(512 + kk)*DD + t]       = f2bf(acc0);
  meanA[(size_t)(512 + kk)*DD + t + 256] = f2bf(acc1);
}

// ---------------- bf16 MFMA GEMM: C[M][N] = A[M][K] * Bt[N][K]^T (+bias) ----------------
// 128x128 tile, 4 waves (2x2), each wave 64x64 = 4x4 frags of 16x16x32.
#define BM 128
#define BN 128
#define LDK 40   // 32 + 8 pad (80B rows: 16B-aligned, ~2-way banks)
__global__ __launch_bounds__(256) void gemm_bf16(
    const u16* __restrict__ A, const u16* __restrict__ Bt,
    const float* __restrict__ bias,
    float* __restrict__ C, u16* __restrict__ Cbf,
    int M, int N, int K)
{
  __shared__ __align__(16) u16 lA[BM*LDK];
  __shared__ __align__(16) u16 lB[BN*LDK];
  int tid = threadIdx.x;
  int m0 = blockIdx.y * BM, n0 = blockIdx.x * BN;
  int lane = tid & 63;
  int wv = tid >> 6;
  int wm = (wv >> 1) * 64, wn = (wv & 1) * 64;
  int lr = lane & 15;
  int kg = (lane >> 4) << 3;
  f32x4 acc[4][4] = {};
  int sr = tid >> 2;            // 0..63
  int sc = (tid & 3) << 3;      // 0,8,16,24

  for (int kt = 0; kt < K; kt += 32){
    *(uint4*)&lA[sr*LDK + sc]      = *(const uint4*)(A + (size_t)(m0 + sr)*K + kt + sc);
    *(uint4*)&lA[(sr+64)*LDK + sc] = *(const uint4*)(A + (size_t)(m0 + sr + 64)*K + kt + sc);
    *(uint4*)&lB[sr*LDK + sc]      = *(const uint4*)(Bt + (size_t)(n0 + sr)*K + kt + sc);
    *(uint4*)&lB[(sr+64)*LDK + sc] = *(const uint4*)(Bt + (size_t)(n0 + sr + 64)*K + kt + sc);
    __syncthreads();
    bf16x8 af[4], bfv[4];
    #pragma unroll
    for (int i = 0; i < 4; i++) af[i]  = *(const bf16x8*)&lA[(wm + i*16 + lr)*LDK + kg];
    #pragma unroll
    for (int j = 0; j < 4; j++) bfv[j] = *(const bf16x8*)&lB[(wn + j*16 + lr)*LDK + kg];
    #pragma unroll
    for (int i = 0; i < 4; i++)
      #pragma unroll
      for (int j = 0; j < 4; j++)
        acc[i][j] = __builtin_amdgcn_mfma_f32_16x16x32_bf16(af[i], bfv[j], acc[i][j], 0, 0, 0);
    __syncthreads();
  }

  // verified C/D layout: col = lane&15, row = (lane>>4)*4 + reg
  int lrow = (lane >> 4) << 2;
  #pragma unroll
  for (int j = 0; j < 4; j++){
    int col = n0 + wn + j*16 + lr;
    float bcol = bias ? bias[col] : 0.f;
    #pragma unroll
    for (int i = 0; i < 4; i++){
      int row0 = m0 + wm + i*16 + lrow;
      #pragma unroll
      for (int r = 0; r < 4; r++){
        float v = acc[i][j][r] + bcol;
        C[(size_t)(row0 + r)*N + col] = v;
        if (Cbf) Cbf[(size_t)(row0 + r)*N + col] = f2bf(v);
      }
    }
  }
}

// ---------------- per-point attention over <=9 neighbor cells: one wave per point ----------------
__global__ __launch_bounds__(256) void attn_kernel(
    const float* __restrict__ q, const float* __restrict__ meanK,
    const float* __restrict__ meanV, const int* __restrict__ cell,
    const int* __restrict__ counts, const float* __restrict__ bk,
    const float* __restrict__ bv, u16* __restrict__ agg)
{
  int wv = threadIdx.x >> 6, lane = threadIdx.x & 63;
  int p = blockIdx.x * 4 + wv;          // 0..16383
  int b = p >> 11;
  int c = cell[p];
  int gx = c >> 3, gy = c & 7;
  int d0 = lane * 8;
  float qv[8], bkv[8], bvv[8];
  load8(q + (size_t)p*DD + d0, qv);
  load8(bk + d0, bkv);
  load8(bv + d0, bvv);

  float s[9]; int val[9]; int nrow[9];
  #pragma unroll
  for (int kk = 0; kk < 9; kk++){
    int dx = kk/3 - 1, dy = kk%3 - 1;
    int nx = gx + dx, ny = gy + dy;
    int inb = ((unsigned)nx < 8u) && ((unsigned)ny < 8u);
    int nidx = ((inb ? nx : 0) << 3) | (inb ? ny : 0);
    int row = b*GG + nidx;
    nrow[kk] = row;
    int v = inb && (counts[row] > 0);
    val[kk] = v;
    float partial = 0.f;
    if (v){
      float kv[8], pv[8];
      load8(meanK + (size_t)row*DD + d0, kv);
      load8(meanK + (size_t)(512 + kk)*DD + d0, pv);
      #pragma unroll
      for (int j = 0; j < 8; j++) partial += qv[j]*(kv[j] + pv[j] + bkv[j]);
    }
    partial += __shfl_xor(partial, 1);
    partial += __shfl_xor(partial, 2);
    partial += __shfl_xor(partial, 4);
    partial += __shfl_xor(partial, 8);
    s[kk] = v ? partial * 0.08838834764831843f : -1e30f;
  }
  float mx = s[0];
  #pragma unroll
  for (int kk = 1; kk < 9; kk++) mx = fmaxf(mx, s[kk]);
  float w[9], sum = 0.f;
  #pragma unroll
  for (int kk = 0; kk < 9; kk++){
    w[kk] = val[kk] ? __expf(s[kk] - mx) : 0.f;
    sum += w[kk];
  }
  float inv = 1.f / sum;
  float a[8] = {0,0,0,0,0,0,0,0};
  #pragma unroll
  for (int kk = 0; kk < 9; kk++){
    if (val[kk]){
      float wk = w[kk] * inv;
      float vv[8], pv[8];
      load8(meanV + (size_t)nrow[kk]*DD + d0, vv);
      load8(meanV + (size_t)(512 + kk)*DD + d0, pv);
      #pragma unroll
      for (int j = 0; j < 8; j++) a[j] += wk*(vv[j] + pv[j] + bvv[j]);
    }
  }
  uint4 pk;
  pk.x = (u32)f2bf(a[0]) | ((u32)f2bf(a[1]) << 16);
  pk.y = (u32)f2bf(a[2]) | ((u32)f2bf(a[3]) << 16);
  pk.z = (u32)f2bf(a[4]) | ((u32)f2bf(a[5]) << 16);
  pk.w = (u32)f2bf(a[6]) | ((u32)f2bf(a[7]) << 16);
  *(uint4*)&agg[(size_t)p*DD + d0] = pk;
}

// ---------------- residual + layernorm: one wave per row ----------------
__global__ __launch_bounds__(256) void ln_kernel(
    const float* __restrict__ feat, const float* __restrict__ lin,
    const float* __restrict__ gamma, const float* __restrict__ beta,
    float* __restrict__ out)
{
  int wv = threadIdx.x >> 6, lane = threadIdx.x & 63;
  size_t r = (size_t)blockIdx.x * 4 + wv;
  int d0 = lane * 8;
  float fv[8], lv[8];
  load8(feat + r*DD + d0, fv);
  load8(lin  + r*DD + d0, lv);
  float e[8], s1 = 0.f, s2 = 0.f;
  #pragma unroll
  for (int j = 0; j < 8; j++){ e[j] = fv[j] + lv[j]; s1 += e[j]; s2 += e[j]*e[j]; }
  #pragma unroll
  for (int m = 1; m < 64; m <<= 1){ s1 += __shfl_xor(s1, m); s2 += __shfl_xor(s2, m); }
  float mu  = s1 * (1.f/512.f);
  float var = s2 * (1.f/512.f) - mu*mu;
  float istd = rsqrtf(var + 1e-5f);
  float gv[8], bev[8];
  load8(gamma + d0, gv); load8(beta + d0, bev);
  float o[8];
  #pragma unroll
  for (int j = 0; j < 8; j++) o[j] = (e[j] - mu)*istd*gv[j] + bev[j];
  store8(out + r*DD + d0, o);
}

extern "C" void kernel_launch(void* const* d_in, const int* in_sizes, int n_in,
                              void* d_out, int out_size, void* d_ws, size_t ws_size,
                              hipStream_t stream) {
  (void)in_sizes; (void)n_in; (void)out_size; (void)ws_size;
  const float* features = (const float*)d_in[0];
  const float* coords   = (const float*)d_in[1];
  const float* W_feat   = (const float*)d_in[2];
  const float* b_feat   = (const float*)d_in[3];
  const float* W_p1     = (const float*)d_in[4];
  const float* b_p1     = (const float*)d_in[5];
  const float* W_p2     = (const float*)d_in[6];
  const float* b_p2     = (const float*)d_in[7];
  const float* Wq = (const float*)d_in[8];  const float* bq = (const float*)d_in[9];
  const float* Wk = (const float*)d_in[10]; const float* bk = (const float*)d_in[11];
  const float* Wv = (const float*)d_in[12]; const float* bv = (const float*)d_in[13];
  const float* Wo = (const float*)d_in[14]; const float* bo = (const float*)d_in[15];
  const float* gamma = (const float*)d_in[16]; const float* beta = (const float*)d_in[17];
  float* out = (float*)d_out;

  char* ws = (char*)d_ws;
  size_t off = 0;
  auto alloc = [&](size_t bytes) -> void* {
    void* p = ws + off;
    off = (off + bytes + 255) & ~(size_t)255;
    return p;
  };
  float* feat_f32  = (float*)alloc((size_t)NPTS*DD*4);     // 33.5 MB
  float* q_f32     = (float*)alloc((size_t)NPTS*DD*4);     // 33.5 MB (reused as lin after attention)
  u16*   featA     = (u16*)  alloc((size_t)NPTS*INDIM*2);  // 8.4 MB
  u16*   feat_bf   = (u16*)  alloc((size_t)NPTS*DD*2);     // 16.8 MB
  u16*   agg_bf    = (u16*)  alloc((size_t)NPTS*DD*2);     // 16.8 MB
  u16*   WfeatT    = (u16*)  alloc((size_t)DD*INDIM*2);
  u16*   WqT       = (u16*)  alloc((size_t)DD*DD*2);
  u16*   WkT       = (u16*)  alloc((size_t)DD*DD*2);
  u16*   WvT       = (u16*)  alloc((size_t)DD*DD*2);
  u16*   WoT       = (u16*)  alloc((size_t)DD*DD*2);
  u16*   meanA     = (u16*)  alloc((size_t)MEANROWS*DD*2); // rows 0..511 mean, 512..520 pe
  float* meanK     = (float*)alloc((size_t)MEANROWS*DD*4);
  float* meanV     = (float*)alloc((size_t)MEANROWS*DD*4);
  int*   cell      = (int*)  alloc((size_t)NPTS*4);
  int*   counts    = (int*)  alloc((size_t)NBATCH*GG*4);
  float* lin_f32   = q_f32;  // safe: GEMM3 runs after attention consumed q

  // conversions / transposes
  f2bf_kernel<<<(NPTS*INDIM + 255)/256, 256, 0, stream>>>(features, featA, NPTS*INDIM);
  transpose_bf16_kernel<<<(INDIM*DD + 255)/256, 256, 0, stream>>>(W_feat, WfeatT, INDIM, DD);
  transpose_bf16_kernel<<<(DD*DD + 255)/256, 256, 0, stream>>>(Wq, WqT, DD, DD);
  transpose_bf16_kernel<<<(DD*DD + 255)/256, 256, 0, stream>>>(Wk, WkT, DD, DD);
  transpose_bf16_kernel<<<(DD*DD + 255)/256, 256, 0, stream>>>(Wv, WvT, DD, DD);
  transpose_bf16_kernel<<<(DD*DD + 255)/256, 256, 0, stream>>>(Wo, WoT, DD, DD);
  cell_kernel<<<NPTS/256, 256, 0, stream>>>(coords, cell, NPTS);

  // feat = features @ W_feat + b_feat  (f32 + bf16 copies)
  gemm_bf16<<<dim3(DD/BN, NPTS/BM), 256, 0, stream>>>(featA, WfeatT, b_feat, feat_f32, feat_bf, NPTS, DD, INDIM);
  // segment mean + counts (deterministic), writes meanA rows 0..511
  bucket_kernel<<<NBATCH*GG, 256, 0, stream>>>(feat_f32, cell, meanA, counts);
  // pe rows 512..520
  pe_kernel<<<9, 256, 0, stream>>>(W_p1, b_p1, W_p2, b_p2, meanA);
  // meanK/meanV = [mean;pe] @ Wk/Wv  (bias added in attention)
  gemm_bf16<<<dim3(DD/BN, MEANROWS/BM), 256, 0, stream>>>(meanA, WkT, nullptr, meanK, nullptr, MEANROWS, DD, DD);
  gemm_bf16<<<dim3(DD/BN, MEANROWS/BM), 256, 0, stream>>>(meanA, WvT, nullptr, meanV, nullptr, MEANROWS, DD, DD);
  // q = feat @ Wq + bq
  gemm_bf16<<<dim3(DD/BN, NPTS/BM), 256, 0, stream>>>(feat_bf, WqT, bq, q_f32, nullptr, NPTS, DD, DD);
  // attention -> agg (bf16)
  attn_kernel<<<NPTS/4, 256, 0, stream>>>(q_f32, meanK, meanV, cell, counts, bk, bv, agg_bf);
  // lin = agg @ Wo + bo (into q buffer)
  gemm_bf16<<<dim3(DD/BN, NPTS/BM), 256, 0, stream>>>(agg_bf, WoT, bo, lin_f32, nullptr, NPTS, DD, DD);
  // out = LN(feat + lin) * gamma + beta
  ln_kernel<<<NPTS/4, 256, 0, stream>>>(feat_f32, lin_f32, gamma, beta, out);
}

// Round 2
// 196.271 us; speedup vs baseline: 1.5621x; 1.5621x over previous
//
#include <hip/hip_runtime.h>
#include <stdint.h>

typedef unsigned short u16;
typedef unsigned int u32;
typedef __bf16 bf16x8 __attribute__((ext_vector_type(8)));
typedef float f32x4 __attribute__((ext_vector_type(4)));

#define NBATCH 8
#define NPT    2048
#define NPTS   16384     // NBATCH*NPT
#define INDIM  256
#define DD     512
#define GG     64        // 8x8 grid cells
#define MEANROWS 640     // 512 mean rows + 9 pe rows, padded to 128-multiple

__device__ __forceinline__ u16 f2bf(float f){
  u32 u = __builtin_bit_cast(u32, f);
  u += 0x7fffu + ((u >> 16) & 1u);
  return (u16)(u >> 16);
}
__device__ __forceinline__ float bf2f(u16 h){
  u32 u = ((u32)h) << 16;
  return __builtin_bit_cast(float, u);
}
__device__ __forceinline__ void load8(const float* __restrict__ p, float* r){
  float4 a = *(const float4*)p;
  float4 b = *(const float4*)(p + 4);
  r[0]=a.x;r[1]=a.y;r[2]=a.z;r[3]=a.w;r[4]=b.x;r[5]=b.y;r[6]=b.z;r[7]=b.w;
}
__device__ __forceinline__ void load8bf(const u16* __restrict__ p, float* r){
  uint4 v = *(const uint4*)p;
  r[0]=bf2f((u16)v.x); r[1]=bf2f((u16)(v.x>>16));
  r[2]=bf2f((u16)v.y); r[3]=bf2f((u16)(v.y>>16));
  r[4]=bf2f((u16)v.z); r[5]=bf2f((u16)(v.z>>16));
  r[6]=bf2f((u16)v.w); r[7]=bf2f((u16)(v.w>>16));
}
__device__ __forceinline__ void store8(float* __restrict__ p, const float* r){
  float4 a; a.x=r[0];a.y=r[1];a.z=r[2];a.w=r[3];
  float4 b; b.x=r[4];b.y=r[5];b.z=r[6];b.w=r[7];
  *(float4*)p = a; *(float4*)(p+4) = b;
}
typedef __attribute__((address_space(1))) unsigned as1u;
typedef __attribute__((address_space(3))) unsigned as3u;
__device__ __forceinline__ void gload16(const void* g, void* l){
  __builtin_amdgcn_global_load_lds((as1u*)(uintptr_t)g, (as3u*)(uintptr_t)l, 16, 0, 0);
}

// ---------------- vectorized f32 -> bf16 (8/thread) ----------------
__global__ void f2bf8_kernel(const float* __restrict__ in, u16* __restrict__ out, int n8){
  int i = blockIdx.x*256 + threadIdx.x;
  if (i < n8){
    float r[8]; load8(in + (size_t)i*8, r);
    uint4 pk;
    pk.x = (u32)f2bf(r[0]) | ((u32)f2bf(r[1]) << 16);
    pk.y = (u32)f2bf(r[2]) | ((u32)f2bf(r[3]) << 16);
    pk.z = (u32)f2bf(r[4]) | ((u32)f2bf(r[5]) << 16);
    pk.w = (u32)f2bf(r[6]) | ((u32)f2bf(r[7]) << 16);
    *(uint4*)(out + (size_t)i*8) = pk;
  }
}

// ---------------- transpose f32[K][N] -> bf16[N][K] ----------------
__global__ void transpose_bf16_kernel(const float* __restrict__ in, u16* __restrict__ out, int K, int N){
  int i = blockIdx.x*256 + threadIdx.x;
  if (i < K*N){
    int k = i / N, n = i - k*N;
    out[(size_t)n*K + k] = f2bf(in[i]);
  }
}

// four 512x512 transposes in one launch (blockIdx.y selects matrix)
__global__ void transpose4_kernel(const float* __restrict__ s0, const float* __restrict__ s1,
                                  const float* __restrict__ s2, const float* __restrict__ s3,
                                  u16* __restrict__ d0, u16* __restrict__ d1,
                                  u16* __restrict__ d2, u16* __restrict__ d3){
  const float* src; u16* dst;
  switch (blockIdx.y){
    case 0: src = s0; dst = d0; break;
    case 1: src = s1; dst = d1; break;
    case 2: src = s2; dst = d2; break;
    default: src = s3; dst = d3; break;
  }
  int i = blockIdx.x*256 + threadIdx.x;
  int k = i >> 9, n = i & 511;
  dst[(size_t)n*DD + k] = f2bf(src[i]);
}

// ---------------- cell ids ----------------
__global__ void cell_kernel(const float* __restrict__ coords, int* __restrict__ cell, int n){
  int i = blockIdx.x*256 + threadIdx.x;
  if (i < n){
    float x = coords[2*i], y = coords[2*i+1];
    int gx = (int)(x * (1.0f/32.0f)); gx = gx < 0 ? 0 : (gx > 7 ? 7 : gx);
    int gy = (int)(y * (1.0f/32.0f)); gy = gy < 0 ? 0 : (gy > 7 ? 7 : gy);
    cell[i] = gx*8 + gy;
  }
}

// ---------------- stable counting sort (rank) per batch: deterministic ----------------
__global__ __launch_bounds__(256) void rank_kernel(
    const int* __restrict__ cell, int* __restrict__ order,
    int* __restrict__ counts, int* __restrict__ cellstart)
{
  int b = blockIdx.x;                 // 0..7
  __shared__ int lc[NPT];             // 8KB
  __shared__ u16 hist[256][65];       // 33.3KB, padded: scan reads are 2-way banked
  __shared__ int tot[GG], base[GG];
  int t = threadIdx.x;
  for (int i = t; i < NPT; i += 256) lc[i] = cell[b*NPT + i];
  #pragma unroll
  for (int i = 0; i < 65; i++) hist[t][i] = 0;
  __syncthreads();
  int myc[8];
  #pragma unroll
  for (int i = 0; i < 8; i++){ myc[i] = lc[t*8 + i]; hist[t][myc[i]]++; }
  __syncthreads();
  if (t < GG){
    int acc = 0;
    for (int tt = 0; tt < 256; tt++){ int v = hist[tt][t]; hist[tt][t] = (u16)acc; acc += v; }
    tot[t] = acc;
  }
  __syncthreads();
  if (t == 0){
    int acc = 0;
    for (int g = 0; g < GG; g++){ base[g] = acc; acc += tot[g]; }
  }
  __syncthreads();
  if (t < GG){
    counts[b*GG + t] = tot[t];
    cellstart[b*GG + t] = base[t];
  }
  #pragma unroll
  for (int i = 0; i < 8; i++){
    int g = myc[i];
    int local = 0;
    #pragma unroll
    for (int j = 0; j < 8; j++) local += (j < i && myc[j] == g) ? 1 : 0;
    order[b*NPT + base[g] + (int)hist[t][g] + local] = t*8 + i;
  }
}

// ---------------- segment mean via sorted gather: one block per (b,g) ----------------
__global__ __launch_bounds__(256) void mean_kernel(
    const u16* __restrict__ feat_bf, const int* __restrict__ order,
    const int* __restrict__ counts, const int* __restrict__ cellstart,
    u16* __restrict__ meanA)
{
  int bg = blockIdx.x;                // 0..511
  int b = bg >> 6;
  int t = threadIdx.x;                // owns dims 2t, 2t+1
  int cnt = counts[bg], start = cellstart[bg];
  const int* ord = order + b*NPT + start;
  float a0 = 0.f, a1 = 0.f;
  for (int n = 0; n < cnt; n++){
    int idx = ord[n];
    u32 v = *(const u32*)(feat_bf + (((size_t)(b*NPT + idx)) << 9) + t*2);
    a0 += bf2f((u16)v); a1 += bf2f((u16)(v >> 16));
  }
  float inv = 1.f / (float)(cnt > 0 ? cnt : 1);
  u32 pk = (u32)f2bf(a0*inv) | ((u32)f2bf(a1*inv) << 16);
  *(u32*)(meanA + (size_t)bg*DD + t*2) = pk;
}

// ---------------- pos-enc MLP: one block per offset kk, writes meanA rows 512..520 ----------------
__global__ __launch_bounds__(256) void pe_kernel(
    const float* __restrict__ W_p1, const float* __restrict__ b_p1,
    const float* __restrict__ W_p2, const float* __restrict__ b_p2,
    u16* __restrict__ meanA)
{
  int kk = blockIdx.x;          // 0..8
  float dx = (float)(kk/3 - 1), dy = (float)(kk%3 - 1);
  __shared__ float h[256];
  int t = threadIdx.x;
  float hv = dx*W_p1[t] + dy*W_p1[256 + t] + b_p1[t];
  h[t] = hv > 0.f ? hv : 0.f;
  __syncthreads();
  float acc0 = b_p2[t], acc1 = b_p2[t + 256];
  for (int c = 0; c < 256; c++){
    float hc = h[c];
    acc0 += hc * W_p2[(size_t)c*DD + t];
    acc1 += hc * W_p2[(size_t)c*DD + t + 256];
  }
  meanA[(size_t)(512 + kk)*DD + t]       = f2bf(acc0);
  meanA[(size_t)(512 + kk)*DD + t + 256] = f2bf(acc1);
}

// ---------------- bf16 MFMA GEMM: C[M][N] = A[M][K] * Bt[N][K]^T (+bias) ----------------
// 128x128 tile, 4 waves (2x2), global_load_lds staging into linear [128][32] LDS.
#define BM 128
#define BN 128
__global__ __launch_bounds__(256) void gemm_bf16(
    const u16* __restrict__ A, const u16* __restrict__ Bt,
    const float* __restrict__ bias,
    float* __restrict__ C, u16* __restrict__ Cbf,
    int M, int N, int K)
{
  __shared__ __align__(16) u16 lA[BM*32];   // 8KB, linear (required by global_load_lds)
  __shared__ __align__(16) u16 lB[BN*32];   // 8KB
  int tid = threadIdx.x;
  int m0 = blockIdx.y * BM, n0 = blockIdx.x * BN;
  int lane = tid & 63;
  int wv = tid >> 6;
  int wm = (wv >> 1) * 64, wn = (wv & 1) * 64;
  int lr = lane & 15;
  int kg = (lane >> 4) << 3;
  f32x4 acc[4][4] = {};

  // staging: wave wv stages A rows [wv*32, wv*32+32) and same for B, in 2 chunks of 16 rows.
  // lane l covers (row = chunk*16 + l/4, col8 = l%4): LDS elem off = l*8 == HW's lane*16B. 
  int srow = lane >> 2;               // 0..15
  int scol = (lane & 3) << 3;         // 0,8,16,24
  const u16* gA0 = A  + (size_t)(m0 + wv*32 + srow)*K + scol;
  const u16* gB0 = Bt + (size_t)(n0 + wv*32 + srow)*K + scol;
  u16* lA0 = lA + (wv*32)*32;         // wave-uniform LDS base
  u16* lB0 = lB + (wv*32)*32;

  for (int kt = 0; kt < K; kt += 32){
    gload16(gA0 + kt,                lA0);
    gload16(gA0 + kt + (size_t)16*K, lA0 + 16*32);
    gload16(gB0 + kt,                lB0);
    gload16(gB0 + kt + (size_t)16*K, lB0 + 16*32);
    __syncthreads();                  // drains vmcnt -> LDS tiles ready
    bf16x8 af[4], bfv[4];
    #pragma unroll
    for (int i = 0; i < 4; i++) af[i]  = *(const bf16x8*)&lA[(wm + i*16 + lr)*32 + kg];
    #pragma unroll
    for (int j = 0; j < 4; j++) bfv[j] = *(const bf16x8*)&lB[(wn + j*16 + lr)*32 + kg];
    #pragma unroll
    for (int i = 0; i < 4; i++)
      #pragma unroll
      for (int j = 0; j < 4; j++)
        acc[i][j] = __builtin_amdgcn_mfma_f32_16x16x32_bf16(af[i], bfv[j], acc[i][j], 0, 0, 0);
    __syncthreads();
  }

  // verified C/D layout: col = lane&15, row = (lane>>4)*4 + reg
  int lrow = (lane >> 4) << 2;
  #pragma unroll
  for (int j = 0; j < 4; j++){
    int col = n0 + wn + j*16 + lr;
    float bcol = bias ? bias[col] : 0.f;
    #pragma unroll
    for (int i = 0; i < 4; i++){
      int row0 = m0 + wm + i*16 + lrow;
      #pragma unroll
      for (int r = 0; r < 4; r++){
        float v = acc[i][j][r] + bcol;
        if (C)   C[(size_t)(row0 + r)*N + col] = v;
        if (Cbf) Cbf[(size_t)(row0 + r)*N + col] = f2bf(v);
      }
    }
  }
}

// ---------------- per-point attention over <=9 neighbor cells: one wave per point ----------------
__global__ __launch_bounds__(256) void attn_kernel(
    const u16* __restrict__ q, const float* __restrict__ meanK,
    const float* __restrict__ meanV, const int* __restrict__ cell,
    const int* __restrict__ counts, const float* __restrict__ bk,
    const float* __restrict__ bv, u16* __restrict__ agg)
{
  int wv = threadIdx.x >> 6, lane = threadIdx.x & 63;
  int p = blockIdx.x * 4 + wv;          // 0..16383
  int b = p >> 11;
  int c = cell[p];
  int gx = c >> 3, gy = c & 7;
  int d0 = lane * 8;
  float qv[8], bkv[8], bvv[8];
  load8bf(q + (size_t)p*DD + d0, qv);
  load8(bk + d0, bkv);
  load8(bv + d0, bvv);

  float s[9]; int val[9]; int nrow[9];
  #pragma unroll
  for (int kk = 0; kk < 9; kk++){
    int dx = kk/3 - 1, dy = kk%3 - 1;
    int nx = gx + dx, ny = gy + dy;
    int inb = ((unsigned)nx < 8u) && ((unsigned)ny < 8u);
    int nidx = ((inb ? nx : 0) << 3) | (inb ? ny : 0);
    int row = b*GG + nidx;
    nrow[kk] = row;
    int v = inb && (counts[row] > 0);
    val[kk] = v;
    float partial = 0.f;
    if (v){
      float kv[8], pv[8];
      load8(meanK + (size_t)row*DD + d0, kv);
      load8(meanK + (size_t)(512 + kk)*DD + d0, pv);
      #pragma unroll
      for (int j = 0; j < 8; j++) partial += qv[j]*(kv[j] + pv[j] + bkv[j]);
    }
    partial += __shfl_xor(partial, 1);
    partial += __shfl_xor(partial, 2);
    partial += __shfl_xor(partial, 4);
    partial += __shfl_xor(partial, 8);
    s[kk] = v ? partial * 0.08838834764831843f : -1e30f;
  }
  float mx = s[0];
  #pragma unroll
  for (int kk = 1; kk < 9; kk++) mx = fmaxf(mx, s[kk]);
  float w[9], sum = 0.f;
  #pragma unroll
  for (int kk = 0; kk < 9; kk++){
    w[kk] = val[kk] ? __expf(s[kk] - mx) : 0.f;
    sum += w[kk];
  }
  float inv = 1.f / sum;
  float a[8] = {0,0,0,0,0,0,0,0};
  #pragma unroll
  for (int kk = 0; kk < 9; kk++){
    if (val[kk]){
      float wk = w[kk] * inv;
      float vv[8], pv[8];
      load8(meanV + (size_t)nrow[kk]*DD + d0, vv);
      load8(meanV + (size_t)(512 + kk)*DD + d0, pv);
      #pragma unroll
      for (int j = 0; j < 8; j++) a[j] += wk*(vv[j] + pv[j] + bvv[j]);
    }
  }
  uint4 pk;
  pk.x = (u32)f2bf(a[0]) | ((u32)f2bf(a[1]) << 16);
  pk.y = (u32)f2bf(a[2]) | ((u32)f2bf(a[3]) << 16);
  pk.z = (u32)f2bf(a[4]) | ((u32)f2bf(a[5]) << 16);
  pk.w = (u32)f2bf(a[6]) | ((u32)f2bf(a[7]) << 16);
  *(uint4*)&agg[(size_t)p*DD + d0] = pk;
}

// ---------------- residual + layernorm (bf16 inputs): one wave per row ----------------
__global__ __launch_bounds__(256) void ln_kernel(
    const u16* __restrict__ feat, const u16* __restrict__ lin,
    const float* __restrict__ gamma, const float* __restrict__ beta,
    float* __restrict__ out)
{
  int wv = threadIdx.x >> 6, lane = threadIdx.x & 63;
  size_t r = (size_t)blockIdx.x * 4 + wv;
  int d0 = lane * 8;
  float fv[8], lv[8];
  load8bf(feat + r*DD + d0, fv);
  load8bf(lin  + r*DD + d0, lv);
  float e[8], s1 = 0.f, s2 = 0.f;
  #pragma unroll
  for (int j = 0; j < 8; j++){ e[j] = fv[j] + lv[j]; s1 += e[j]; s2 += e[j]*e[j]; }
  #pragma unroll
  for (int m = 1; m < 64; m <<= 1){ s1 += __shfl_xor(s1, m); s2 += __shfl_xor(s2, m); }
  float mu  = s1 * (1.f/512.f);
  float var = s2 * (1.f/512.f) - mu*mu;
  float istd = rsqrtf(var + 1e-5f);
  float gv[8], bev[8];
  load8(gamma + d0, gv); load8(beta + d0, bev);
  float o[8];
  #pragma unroll
  for (int j = 0; j < 8; j++) o[j] = (e[j] - mu)*istd*gv[j] + bev[j];
  store8(out + r*DD + d0, o);
}

extern "C" void kernel_launch(void* const* d_in, const int* in_sizes, int n_in,
                              void* d_out, int out_size, void* d_ws, size_t ws_size,
                              hipStream_t stream) {
  (void)in_sizes; (void)n_in; (void)out_size; (void)ws_size;
  const float* features = (const float*)d_in[0];
  const float* coords   = (const float*)d_in[1];
  const float* W_feat   = (const float*)d_in[2];
  const float* b_feat   = (const float*)d_in[3];
  const float* W_p1     = (const float*)d_in[4];
  const float* b_p1     = (const float*)d_in[5];
  const float* W_p2     = (const float*)d_in[6];
  const float* b_p2     = (const float*)d_in[7];
  const float* Wq = (const float*)d_in[8];  const float* bq = (const float*)d_in[9];
  const float* Wk = (const float*)d_in[10]; const float* bk = (const float*)d_in[11];
  const float* Wv = (const float*)d_in[12]; const float* bv = (const float*)d_in[13];
  const float* Wo = (const float*)d_in[14]; const float* bo = (const float*)d_in[15];
  const float* gamma = (const float*)d_in[16]; const float* beta = (const float*)d_in[17];
  float* out = (float*)d_out;

  char* ws = (char*)d_ws;
  size_t off = 0;
  auto alloc = [&](size_t bytes) -> void* {
    void* p = ws + off;
    off = (off + bytes + 255) & ~(size_t)255;
    return p;
  };
  u16*   featA     = (u16*)  alloc((size_t)NPTS*INDIM*2);  // 8.4 MB
  u16*   feat_bf   = (u16*)  alloc((size_t)NPTS*DD*2);     // 16.8 MB
  u16*   q_bf      = (u16*)  alloc((size_t)NPTS*DD*2);     // 16.8 MB
  u16*   agg_bf    = (u16*)  alloc((size_t)NPTS*DD*2);     // 16.8 MB
  u16*   lin_bf    = (u16*)  alloc((size_t)NPTS*DD*2);     // 16.8 MB
  u16*   WfeatT    = (u16*)  alloc((size_t)DD*INDIM*2);
  u16*   WqT       = (u16*)  alloc((size_t)DD*DD*2);
  u16*   WkT       = (u16*)  alloc((size_t)DD*DD*2);
  u16*   WvT       = (u16*)  alloc((size_t)DD*DD*2);
  u16*   WoT       = (u16*)  alloc((size_t)DD*DD*2);
  u16*   meanA     = (u16*)  alloc((size_t)MEANROWS*DD*2); // rows 0..511 mean, 512..520 pe
  float* meanK     = (float*)alloc((size_t)MEANROWS*DD*4);
  float* meanV     = (float*)alloc((size_t)MEANROWS*DD*4);
  int*   cell      = (int*)  alloc((size_t)NPTS*4);
  int*   order     = (int*)  alloc((size_t)NPTS*4);
  int*   counts    = (int*)  alloc((size_t)NBATCH*GG*4);
  int*   cellstart = (int*)  alloc((size_t)NBATCH*GG*4);

  // conversions / transposes / bucketing metadata
  f2bf8_kernel<<<(NPTS*INDIM/8 + 255)/256, 256, 0, stream>>>(features, featA, NPTS*INDIM/8);
  transpose_bf16_kernel<<<(INDIM*DD + 255)/256, 256, 0, stream>>>(W_feat, WfeatT, INDIM, DD);
  transpose4_kernel<<<dim3(DD*DD/256, 4), 256, 0, stream>>>(Wq, Wk, Wv, Wo, WqT, WkT, WvT, WoT);
  cell_kernel<<<NPTS/256, 256, 0, stream>>>(coords, cell, NPTS);
  rank_kernel<<<NBATCH, 256, 0, stream>>>(cell, order, counts, cellstart);

  // feat = features @ W_feat + b_feat  (bf16)
  gemm_bf16<<<dim3(DD/BN, NPTS/BM), 256, 0, stream>>>(featA, WfeatT, b_feat, nullptr, feat_bf, NPTS, DD, INDIM);
  // segment mean via sorted gather -> meanA rows 0..511
  mean_kernel<<<NBATCH*GG, 256, 0, stream>>>(feat_bf, order, counts, cellstart, meanA);
  // pe rows 512..520
  pe_kernel<<<9, 256, 0, stream>>>(W_p1, b_p1, W_p2, b_p2, meanA);
  // meanK/meanV = [mean;pe] @ Wk/Wv  (f32; bias added in attention)
  gemm_bf16<<<dim3(DD/BN, MEANROWS/BM), 256, 0, stream>>>(meanA, WkT, nullptr, meanK, nullptr, MEANROWS, DD, DD);
  gemm_bf16<<<dim3(DD/BN, MEANROWS/BM), 256, 0, stream>>>(meanA, WvT, nullptr, meanV, nullptr, MEANROWS, DD, DD);
  // q = feat @ Wq + bq (bf16)
  gemm_bf16<<<dim3(DD/BN, NPTS/BM), 256, 0, stream>>>(feat_bf, WqT, bq, nullptr, q_bf, NPTS, DD, DD);
  // attention -> agg (bf16)
  attn_kernel<<<NPTS/4, 256, 0, stream>>>(q_bf, meanK, meanV, cell, counts, bk, bv, agg_bf);
  // lin = agg @ Wo + bo (bf16)
  gemm_bf16<<<dim3(DD/BN, NPTS/BM), 256, 0, stream>>>(agg_bf, WoT, bo, nullptr, lin_bf, NPTS, DD, DD);
  // out = LN(feat + lin) * gamma + beta
  ln_kernel<<<NPTS/4, 256, 0, stream>>>(feat_bf, lin_bf, gamma, beta, out);
}

// Round 3
// 183.674 us; speedup vs baseline: 1.6692x; 1.0686x over previous
//
#include <hip/hip_runtime.h>
#include <stdint.h>

typedef unsigned short u16;
typedef unsigned int u32;
typedef __bf16 bf16x8 __attribute__((ext_vector_type(8)));
typedef float f32x4 __attribute__((ext_vector_type(4)));

#define NBATCH 8
#define NPT    2048
#define NPTS   16384     // NBATCH*NPT
#define INDIM  256
#define DD     512
#define GG     64        // 8x8 grid cells
#define MEANROWS 640     // 512 mean rows + 9 pe rows, padded to 128-multiple

__device__ __forceinline__ u16 f2bf(float f){
  u32 u = __builtin_bit_cast(u32, f);
  u += 0x7fffu + ((u >> 16) & 1u);
  return (u16)(u >> 16);
}
__device__ __forceinline__ float bf2f(u16 h){
  u32 u = ((u32)h) << 16;
  return __builtin_bit_cast(float, u);
}
__device__ __forceinline__ void load8(const float* __restrict__ p, float* r){
  float4 a = *(const float4*)p;
  float4 b = *(const float4*)(p + 4);
  r[0]=a.x;r[1]=a.y;r[2]=a.z;r[3]=a.w;r[4]=b.x;r[5]=b.y;r[6]=b.z;r[7]=b.w;
}
__device__ __forceinline__ void load8bf(const u16* __restrict__ p, float* r){
  uint4 v = *(const uint4*)p;
  r[0]=bf2f((u16)v.x); r[1]=bf2f((u16)(v.x>>16));
  r[2]=bf2f((u16)v.y); r[3]=bf2f((u16)(v.y>>16));
  r[4]=bf2f((u16)v.z); r[5]=bf2f((u16)(v.z>>16));
  r[6]=bf2f((u16)v.w); r[7]=bf2f((u16)(v.w>>16));
}
__device__ __forceinline__ void store8(float* __restrict__ p, const float* r){
  float4 a; a.x=r[0];a.y=r[1];a.z=r[2];a.w=r[3];
  float4 b; b.x=r[4];b.y=r[5];b.z=r[6];b.w=r[7];
  *(float4*)p = a; *(float4*)(p+4) = b;
}
__device__ __forceinline__ uint4 pack8(const float* a){
  uint4 pk;
  pk.x = (u32)f2bf(a[0]) | ((u32)f2bf(a[1]) << 16);
  pk.y = (u32)f2bf(a[2]) | ((u32)f2bf(a[3]) << 16);
  pk.z = (u32)f2bf(a[4]) | ((u32)f2bf(a[5]) << 16);
  pk.w = (u32)f2bf(a[6]) | ((u32)f2bf(a[7]) << 16);
  return pk;
}
typedef __attribute__((address_space(1))) unsigned as1u;
typedef __attribute__((address_space(3))) unsigned as3u;
__device__ __forceinline__ void gload16(const void* g, void* l){
  __builtin_amdgcn_global_load_lds((as1u*)(uintptr_t)g, (as3u*)(uintptr_t)l, 16, 0, 0);
}

// ---------------- vectorized f32 -> bf16 (8/thread) ----------------
__global__ void f2bf8_kernel(const float* __restrict__ in, u16* __restrict__ out, int n8){
  int i = blockIdx.x*256 + threadIdx.x;
  if (i < n8){
    float r[8]; load8(in + (size_t)i*8, r);
    *(uint4*)(out + (size_t)i*8) = pack8(r);
  }
}

// ---------------- transpose f32[K][N] -> bf16[N][K] ----------------
__global__ void transpose_bf16_kernel(const float* __restrict__ in, u16* __restrict__ out, int K, int N){
  int i = blockIdx.x*256 + threadIdx.x;
  if (i < K*N){
    int k = i / N, n = i - k*N;
    out[(size_t)n*K + k] = f2bf(in[i]);
  }
}

// four 512x512 transposes in one launch (blockIdx.y selects matrix)
__global__ void transpose4_kernel(const float* __restrict__ s0, const float* __restrict__ s1,
                                  const float* __restrict__ s2, const float* __restrict__ s3,
                                  u16* __restrict__ d0, u16* __restrict__ d1,
                                  u16* __restrict__ d2, u16* __restrict__ d3){
  const float* src; u16* dst;
  switch (blockIdx.y){
    case 0: src = s0; dst = d0; break;
    case 1: src = s1; dst = d1; break;
    case 2: src = s2; dst = d2; break;
    default: src = s3; dst = d3; break;
  }
  int i = blockIdx.x*256 + threadIdx.x;
  int k = i >> 9, n = i & 511;
  dst[(size_t)n*DD + k] = f2bf(src[i]);
}

// ---------------- cell ids ----------------
__global__ void cell_kernel(const float* __restrict__ coords, int* __restrict__ cell, int n){
  int i = blockIdx.x*256 + threadIdx.x;
  if (i < n){
    float x = coords[2*i], y = coords[2*i+1];
    int gx = (int)(x * (1.0f/32.0f)); gx = gx < 0 ? 0 : (gx > 7 ? 7 : gx);
    int gy = (int)(y * (1.0f/32.0f)); gy = gy < 0 ? 0 : (gy > 7 ? 7 : gy);
    cell[i] = gx*8 + gy;
  }
}

// ---------------- stable counting sort (rank) per batch: deterministic ----------------
__global__ __launch_bounds__(256) void rank_kernel(
    const int* __restrict__ cell, int* __restrict__ order,
    int* __restrict__ counts, int* __restrict__ cellstart)
{
  int b = blockIdx.x;                 // 0..7
  __shared__ int lc[NPT];             // 8KB
  __shared__ u16 hist[256][65];       // 33.3KB
  __shared__ int tot[GG], base[GG];
  int t = threadIdx.x;
  for (int i = t; i < NPT; i += 256) lc[i] = cell[b*NPT + i];
  #pragma unroll
  for (int i = 0; i < 65; i++) hist[t][i] = 0;
  __syncthreads();
  int myc[8];
  #pragma unroll
  for (int i = 0; i < 8; i++){ myc[i] = lc[t*8 + i]; hist[t][myc[i]]++; }
  __syncthreads();
  if (t < GG){
    int acc = 0;
    for (int tt = 0; tt < 256; tt++){ int v = hist[tt][t]; hist[tt][t] = (u16)acc; acc += v; }
    tot[t] = acc;
  }
  __syncthreads();
  if (t == 0){
    int acc = 0;
    for (int g = 0; g < GG; g++){ base[g] = acc; acc += tot[g]; }
  }
  __syncthreads();
  if (t < GG){
    counts[b*GG + t] = tot[t];
    cellstart[b*GG + t] = base[t];
  }
  #pragma unroll
  for (int i = 0; i < 8; i++){
    int g = myc[i];
    int local = 0;
    #pragma unroll
    for (int j = 0; j < 8; j++) local += (j < i && myc[j] == g) ? 1 : 0;
    order[b*NPT + base[g] + (int)hist[t][g] + local] = t*8 + i;
  }
}

// ---------------- segment mean via sorted gather: one block per (b,g) ----------------
__global__ __launch_bounds__(256) void mean_kernel(
    const u16* __restrict__ feat_bf, const int* __restrict__ order,
    const int* __restrict__ counts, const int* __restrict__ cellstart,
    u16* __restrict__ meanA)
{
  int bg = blockIdx.x;                // 0..511
  int b = bg >> 6;
  int t = threadIdx.x;                // owns dims 2t, 2t+1
  int cnt = counts[bg], start = cellstart[bg];
  const int* ord = order + b*NPT + start;
  float a0 = 0.f, a1 = 0.f;
  for (int n = 0; n < cnt; n++){
    int idx = ord[n];
    u32 v = *(const u32*)(feat_bf + (((size_t)(b*NPT + idx)) << 9) + t*2);
    a0 += bf2f((u16)v); a1 += bf2f((u16)(v >> 16));
  }
  float inv = 1.f / (float)(cnt > 0 ? cnt : 1);
  u32 pk = (u32)f2bf(a0*inv) | ((u32)f2bf(a1*inv) << 16);
  *(u32*)(meanA + (size_t)bg*DD + t*2) = pk;
}

// ---------------- pos-enc MLP: one block per offset kk, writes meanA rows 512..520 ----------------
__global__ __launch_bounds__(256) void pe_kernel(
    const float* __restrict__ W_p1, const float* __restrict__ b_p1,
    const float* __restrict__ W_p2, const float* __restrict__ b_p2,
    u16* __restrict__ meanA)
{
  int kk = blockIdx.x;          // 0..8
  float dx = (float)(kk/3 - 1), dy = (float)(kk%3 - 1);
  __shared__ float h[256];
  int t = threadIdx.x;
  float hv = dx*W_p1[t] + dy*W_p1[256 + t] + b_p1[t];
  h[t] = hv > 0.f ? hv : 0.f;
  __syncthreads();
  float acc0 = b_p2[t], acc1 = b_p2[t + 256];
  for (int c = 0; c < 256; c++){
    float hc = h[c];
    acc0 += hc * W_p2[(size_t)c*DD + t];
    acc1 += hc * W_p2[(size_t)c*DD + t + 256];
  }
  meanA[(size_t)(512 + kk)*DD + t]       = f2bf(acc0);
  meanA[(size_t)(512 + kk)*DD + t + 256] = f2bf(acc1);
}

// ---------------- bfq[i] = sum_k b_feat[k]*Wq[k][i] + bq[i]  (wave per i) ----------------
__global__ __launch_bounds__(256) void bfq_kernel(
    const u16* __restrict__ WqT, const float* __restrict__ b_feat,
    const float* __restrict__ bq, float* __restrict__ bfq)
{
  int wv = threadIdx.x >> 6, lane = threadIdx.x & 63;
  int i = blockIdx.x*4 + wv;    // 0..511
  float w8[8], b8[8];
  load8bf(WqT + (size_t)i*DD + lane*8, w8);
  load8(b_feat + lane*8, b8);
  float s = 0.f;
  #pragma unroll
  for (int j = 0; j < 8; j++) s += w8[j]*b8[j];
  #pragma unroll
  for (int m = 1; m < 64; m <<= 1) s += __shfl_xor(s, m);
  if (lane == 0) bfq[i] = s + bq[i];
}

// ======== shared GEMM main loop (128x128 tile, 4 waves, global_load_lds) ========
#define BM 128
#define BN 128
#define GEMM_MAIN(A, Bt, K)                                                        \
  __shared__ __align__(16) u16 lA[BM*32];                                          \
  __shared__ __align__(16) u16 lB[BN*32];                                          \
  int tid = threadIdx.x;                                                           \
  int m0 = blockIdx.y * BM, n0 = blockIdx.x * BN;                                  \
  int lane = tid & 63;                                                             \
  int wv = tid >> 6;                                                               \
  int wm = (wv >> 1) * 64, wn = (wv & 1) * 64;                                     \
  int lr = lane & 15;                                                              \
  int kg = (lane >> 4) << 3;                                                       \
  f32x4 acc[4][4] = {};                                                            \
  int srow = lane >> 2;                                                            \
  int scol = (lane & 3) << 3;                                                      \
  const u16* gA0 = (A)  + (size_t)(m0 + wv*32 + srow)*(K) + scol;                  \
  const u16* gB0 = (Bt) + (size_t)(n0 + wv*32 + srow)*(K) + scol;                  \
  u16* lA0 = lA + (wv*32)*32;                                                      \
  u16* lB0 = lB + (wv*32)*32;                                                      \
  for (int kt = 0; kt < (K); kt += 32){                                            \
    gload16(gA0 + kt,                  lA0);                                       \
    gload16(gA0 + kt + (size_t)16*(K), lA0 + 16*32);                               \
    gload16(gB0 + kt,                  lB0);                                       \
    gload16(gB0 + kt + (size_t)16*(K), lB0 + 16*32);                               \
    __syncthreads();                                                               \
    bf16x8 af[4], bfv[4];                                                          \
    _Pragma("unroll")                                                              \
    for (int i = 0; i < 4; i++) af[i]  = *(const bf16x8*)&lA[(wm + i*16 + lr)*32 + kg]; \
    _Pragma("unroll")                                                              \
    for (int j = 0; j < 4; j++) bfv[j] = *(const bf16x8*)&lB[(wn + j*16 + lr)*32 + kg]; \
    _Pragma("unroll")                                                              \
    for (int i = 0; i < 4; i++)                                                    \
      _Pragma("unroll")                                                            \
      for (int j = 0; j < 4; j++)                                                  \
        acc[i][j] = __builtin_amdgcn_mfma_f32_16x16x32_bf16(af[i], bfv[j], acc[i][j], 0, 0, 0); \
    __syncthreads();                                                               \
  }                                                                                \
  int lrow = (lane >> 4) << 2;

// ---------------- generic GEMM: C[M][N] = A[M][K]*Bt[N][K]^T (+bias) ----------------
__global__ __launch_bounds__(256) void gemm_bf16(
    const u16* __restrict__ A, const u16* __restrict__ Bt,
    const float* __restrict__ bias,
    float* __restrict__ C, u16* __restrict__ Cbf,
    int M, int N, int K)
{
  GEMM_MAIN(A, Bt, K)
  #pragma unroll
  for (int j = 0; j < 4; j++){
    int col = n0 + wn + j*16 + lr;
    float bcol = bias ? bias[col] : 0.f;
    #pragma unroll
    for (int i = 0; i < 4; i++){
      int row0 = m0 + wm + i*16 + lrow;
      #pragma unroll
      for (int r = 0; r < 4; r++){
        float v = acc[i][j][r] + bcol;
        if (C)   C[(size_t)(row0 + r)*N + col] = v;
        if (Cbf) Cbf[(size_t)(row0 + r)*N + col] = f2bf(v);
      }
    }
  }
}

// ---------------- fused feat+q GEMM: N=1024, cols<512 -> feat_bf, cols>=512 -> q_bf ----------------
__global__ __launch_bounds__(256) void gemm_featq(
    const u16* __restrict__ A, const u16* __restrict__ Bt,
    const float* __restrict__ bias0, const float* __restrict__ bias1,
    u16* __restrict__ out0, u16* __restrict__ out1, int K)
{
  GEMM_MAIN(A, Bt, K)
  int half = n0 >> 9;
  u16* outp = half ? out1 : out0;
  const float* bias = half ? bias1 : bias0;
  int nb = n0 & 511;
  #pragma unroll
  for (int j = 0; j < 4; j++){
    int col = nb + wn + j*16 + lr;
    float bcol = bias[col];
    #pragma unroll
    for (int i = 0; i < 4; i++){
      int row0 = m0 + wm + i*16 + lrow;
      #pragma unroll
      for (int r = 0; r < 4; r++)
        outp[(size_t)(row0 + r)*DD + col] = f2bf(acc[i][j][r] + bcol);
    }
  }
}

// ---------------- cell-centric attention: one block per (b,cell) ----------------
// meanKV: [640][1024] f32; cols 0..511 = K-proj, 512..1023 = V-proj; rows 512+kk = pe.
__global__ __launch_bounds__(256) void attn_cells(
    const u16* __restrict__ q, const float* __restrict__ meanKV,
    const int* __restrict__ order, const int* __restrict__ counts,
    const int* __restrict__ cellstart, const float* __restrict__ bk,
    const float* __restrict__ bv, u16* __restrict__ agg)
{
  int bg = blockIdx.x;            // 0..511
  int b = bg >> 6, c = bg & 63;
  int gx = c >> 3, gy = c & 7;
  __shared__ __align__(16) u16 Kf[9][DD];   // 9KB bf16
  __shared__ __align__(16) u16 Vf[9][DD];   // 9KB
  __shared__ int vrow[9];
  int t = threadIdx.x;
  if (t < 9){
    int dx = t/3 - 1, dy = t%3 - 1;
    int nx = gx + dx, ny = gy + dy;
    int inb = ((unsigned)nx < 8u) && ((unsigned)ny < 8u);
    int row = b*GG + (((nx&7) << 3) | (ny&7));
    vrow[t] = (inb && counts[row] > 0) ? row : -1;
  }
  __syncthreads();
  int d = 2*t;
  float bk0 = bk[d], bk1 = bk[d+1];
  float bv0 = bv[d], bv1 = bv[d+1];
  #pragma unroll
  for (int kk = 0; kk < 9; kk++){
    int row = vrow[kk];
    if (row >= 0){
      float2 mk = *(const float2*)&meanKV[(size_t)row*1024 + d];
      float2 pk = *(const float2*)&meanKV[(size_t)(512+kk)*1024 + d];
      float2 mv = *(const float2*)&meanKV[(size_t)row*1024 + 512 + d];
      float2 pv = *(const float2*)&meanKV[(size_t)(512+kk)*1024 + 512 + d];
      *(u32*)&Kf[kk][d] = (u32)f2bf(mk.x+pk.x+bk0) | ((u32)f2bf(mk.y+pk.y+bk1) << 16);
      *(u32*)&Vf[kk][d] = (u32)f2bf(mv.x+pv.x+bv0) | ((u32)f2bf(mv.y+pv.y+bv1) << 16);
    }
  }
  __syncthreads();
  int cnt = counts[bg];
  int wv = t >> 6, lane = t & 63;
  const int* ord = order + b*NPT + cellstart[bg];
  for (int i = wv; i < cnt; i += 4){
    size_t p = (size_t)b*NPT + ord[i];
    float qv[8];
    load8bf(q + p*DD + lane*8, qv);
    float s[9];
    #pragma unroll
    for (int kk = 0; kk < 9; kk++){
      float partial = 0.f;
      if (vrow[kk] >= 0){
        float kv[8]; load8bf(&Kf[kk][lane*8], kv);
        #pragma unroll
        for (int j = 0; j < 8; j++) partial += qv[j]*kv[j];
      }
      partial += __shfl_xor(partial, 1);
      partial += __shfl_xor(partial, 2);
      partial += __shfl_xor(partial, 4);
      partial += __shfl_xor(partial, 8);
      s[kk] = (vrow[kk] >= 0) ? partial * 0.08838834764831843f : -1e30f;
    }
    float mx = s[0];
    #pragma unroll
    for (int kk = 1; kk < 9; kk++) mx = fmaxf(mx, s[kk]);
    float w[9], sum = 0.f;
    #pragma unroll
    for (int kk = 0; kk < 9; kk++){
      w[kk] = (vrow[kk] >= 0) ? __expf(s[kk] - mx) : 0.f;
      sum += w[kk];
    }
    float inv = 1.f / sum;
    float a[8] = {0,0,0,0,0,0,0,0};
    #pragma unroll
    for (int kk = 0; kk < 9; kk++){
      if (vrow[kk] >= 0){
        float wk = w[kk] * inv;
        float vv[8]; load8bf(&Vf[kk][lane*8], vv);
        #pragma unroll
        for (int j = 0; j < 8; j++) a[j] += wk*vv[j];
      }
    }
    *(uint4*)&agg[p*DD + lane*8] = pack8(a);
  }
}

// ---------------- residual + layernorm (bf16 inputs): one wave per row ----------------
__global__ __launch_bounds__(256) void ln_kernel(
    const u16* __restrict__ feat, const u16* __restrict__ lin,
    const float* __restrict__ gamma, const float* __restrict__ beta,
    float* __restrict__ out)
{
  int wv = threadIdx.x >> 6, lane = threadIdx.x & 63;
  size_t r = (size_t)blockIdx.x * 4 + wv;
  int d0 = lane * 8;
  float fv[8], lv[8];
  load8bf(feat + r*DD + d0, fv);
  load8bf(lin  + r*DD + d0, lv);
  float e[8], s1 = 0.f, s2 = 0.f;
  #pragma unroll
  for (int j = 0; j < 8; j++){ e[j] = fv[j] + lv[j]; s1 += e[j]; s2 += e[j]*e[j]; }
  #pragma unroll
  for (int m = 1; m < 64; m <<= 1){ s1 += __shfl_xor(s1, m); s2 += __shfl_xor(s2, m); }
  float mu  = s1 * (1.f/512.f);
  float var = s2 * (1.f/512.f) - mu*mu;
  float istd = rsqrtf(var + 1e-5f);
  float gv[8], bev[8];
  load8(gamma + d0, gv); load8(beta + d0, bev);
  float o[8];
  #pragma unroll
  for (int j = 0; j < 8; j++) o[j] = (e[j] - mu)*istd*gv[j] + bev[j];
  store8(out + r*DD + d0, o);
}

extern "C" void kernel_launch(void* const* d_in, const int* in_sizes, int n_in,
                              void* d_out, int out_size, void* d_ws, size_t ws_size,
                              hipStream_t stream) {
  (void)in_sizes; (void)n_in; (void)out_size; (void)ws_size;
  const float* features = (const float*)d_in[0];
  const float* coords   = (const float*)d_in[1];
  const float* W_feat   = (const float*)d_in[2];
  const float* b_feat   = (const float*)d_in[3];
  const float* W_p1     = (const float*)d_in[4];
  const float* b_p1     = (const float*)d_in[5];
  const float* W_p2     = (const float*)d_in[6];
  const float* b_p2     = (const float*)d_in[7];
  const float* Wq = (const float*)d_in[8];  const float* bq = (const float*)d_in[9];
  const float* Wk = (const float*)d_in[10]; const float* bk = (const float*)d_in[11];
  const float* Wv = (const float*)d_in[12]; const float* bv = (const float*)d_in[13];
  const float* Wo = (const float*)d_in[14]; const float* bo = (const float*)d_in[15];
  const float* gamma = (const float*)d_in[16]; const float* beta = (const float*)d_in[17];
  float* out = (float*)d_out;

  char* ws = (char*)d_ws;
  size_t off = 0;
  auto alloc = [&](size_t bytes) -> void* {
    void* p = ws + off;
    off = (off + bytes + 255) & ~(size_t)255;
    return p;
  };
  u16*   featA     = (u16*)  alloc((size_t)NPTS*INDIM*2);   // 8.4 MB
  u16*   feat_bf   = (u16*)  alloc((size_t)NPTS*DD*2);      // 16.8 MB
  u16*   q_bf      = (u16*)  alloc((size_t)NPTS*DD*2);      // 16.8 MB
  u16*   agg_bf    = (u16*)  alloc((size_t)NPTS*DD*2);      // 16.8 MB
  u16*   lin_bf    = (u16*)  alloc((size_t)NPTS*DD*2);      // 16.8 MB
  u16*   WcatT     = (u16*)  alloc((size_t)1024*INDIM*2);   // rows 0..511 WfeatT, 512..1023 WfqT
  u16*   W_feat_bf = (u16*)  alloc((size_t)INDIM*DD*2);
  u16*   WqT       = (u16*)  alloc((size_t)DD*DD*2);
  u16*   WoT       = (u16*)  alloc((size_t)DD*DD*2);
  u16*   WkvT      = (u16*)  alloc((size_t)1024*DD*2);      // rows 0..511 WkT, 512..1023 WvT
  u16*   meanA     = (u16*)  alloc((size_t)MEANROWS*DD*2);  // rows 0..511 mean, 512..520 pe
  float* meanKV    = (float*)alloc((size_t)MEANROWS*1024*4);// [640][1024]: K | V
  float* bfq       = (float*)alloc((size_t)DD*4);
  int*   cell      = (int*)  alloc((size_t)NPTS*4);
  int*   order     = (int*)  alloc((size_t)NPTS*4);
  int*   counts    = (int*)  alloc((size_t)NBATCH*GG*4);
  int*   cellstart = (int*)  alloc((size_t)NBATCH*GG*4);
  u16*   WfeatT = WcatT;                  // [512][256]
  u16*   WfqT   = WcatT + (size_t)512*INDIM;  // [512][256]

  // conversions / transposes / bucketing metadata
  f2bf8_kernel<<<(NPTS*INDIM/8 + 255)/256, 256, 0, stream>>>(features, featA, NPTS*INDIM/8);
  f2bf8_kernel<<<(INDIM*DD/8 + 255)/256, 256, 0, stream>>>(W_feat, W_feat_bf, INDIM*DD/8);
  transpose_bf16_kernel<<<(INDIM*DD + 255)/256, 256, 0, stream>>>(W_feat, WfeatT, INDIM, DD);
  transpose4_kernel<<<dim3(DD*DD/256, 4), 256, 0, stream>>>(
      Wq, Wk, Wv, Wo, WqT, WkvT, WkvT + (size_t)512*DD, WoT);
  cell_kernel<<<NPTS/256, 256, 0, stream>>>(coords, cell, NPTS);
  rank_kernel<<<NBATCH, 256, 0, stream>>>(cell, order, counts, cellstart);

  // WfqT = Wq^T @ W_feat^T  [512][256]  (M=512,N=256,K=512)
  gemm_bf16<<<dim3(INDIM/BN + (INDIM%BN?1:0), DD/BM), 256, 0, stream>>>(
      WqT, W_feat_bf, nullptr, nullptr, WfqT, DD, INDIM, DD);
  // bfq = b_feat @ Wq + bq
  bfq_kernel<<<DD/4, 256, 0, stream>>>(WqT, b_feat, bq, bfq);

  // fused: [feat | q] = features @ [W_feat | Wfq]  (M=16384, N=1024, K=256)
  gemm_featq<<<dim3(1024/BN, NPTS/BM), 256, 0, stream>>>(
      featA, WcatT, b_feat, bfq, feat_bf, q_bf, INDIM);

  // segment mean -> meanA rows 0..511; pe rows 512..520
  mean_kernel<<<NBATCH*GG, 256, 0, stream>>>(feat_bf, order, counts, cellstart, meanA);
  pe_kernel<<<9, 256, 0, stream>>>(W_p1, b_p1, W_p2, b_p2, meanA);

  // meanKV = meanA @ [Wk | Wv]  (M=640, N=1024, K=512; biases folded later)
  gemm_bf16<<<dim3(1024/BN, MEANROWS/BM), 256, 0, stream>>>(
      meanA, WkvT, nullptr, meanKV, nullptr, MEANROWS, 1024, DD);

  // cell-centric attention -> agg (bf16)
  attn_cells<<<NBATCH*GG, 256, 0, stream>>>(q_bf, meanKV, order, counts, cellstart, bk, bv, agg_bf);

  // lin = agg @ Wo + bo (bf16)
  gemm_bf16<<<dim3(DD/BN, NPTS/BM), 256, 0, stream>>>(agg_bf, WoT, bo, nullptr, lin_bf, NPTS, DD, DD);
  // out = LN(feat + lin) * gamma + beta
  ln_kernel<<<NPTS/4, 256, 0, stream>>>(feat_bf, lin_bf, gamma, beta, out);
}

// Round 4
// 169.935 us; speedup vs baseline: 1.8042x; 1.0809x over previous
//
#include <hip/hip_runtime.h>
#include <stdint.h>

typedef unsigned short u16;
typedef unsigned int u32;
typedef __bf16 bf16x8 __attribute__((ext_vector_type(8)));
typedef float f32x4 __attribute__((ext_vector_type(4)));

#define NBATCH 8
#define NPT    2048
#define NPTS   16384     // NBATCH*NPT
#define INDIM  256
#define DD     512
#define GG     64        // 8x8 grid cells
#define MEANROWS 640     // 512 mean rows + 9 pe rows, padded to 128-multiple

__device__ __forceinline__ u16 f2bf(float f){
  u32 u = __builtin_bit_cast(u32, f);
  u += 0x7fffu + ((u >> 16) & 1u);
  return (u16)(u >> 16);
}
__device__ __forceinline__ float bf2f(u16 h){
  u32 u = ((u32)h) << 16;
  return __builtin_bit_cast(float, u);
}
__device__ __forceinline__ void load8(const float* __restrict__ p, float* r){
  float4 a = *(const float4*)p;
  float4 b = *(const float4*)(p + 4);
  r[0]=a.x;r[1]=a.y;r[2]=a.z;r[3]=a.w;r[4]=b.x;r[5]=b.y;r[6]=b.z;r[7]=b.w;
}
__device__ __forceinline__ void load8bf(const u16* __restrict__ p, float* r){
  uint4 v = *(const uint4*)p;
  r[0]=bf2f((u16)v.x); r[1]=bf2f((u16)(v.x>>16));
  r[2]=bf2f((u16)v.y); r[3]=bf2f((u16)(v.y>>16));
  r[4]=bf2f((u16)v.z); r[5]=bf2f((u16)(v.z>>16));
  r[6]=bf2f((u16)v.w); r[7]=bf2f((u16)(v.w>>16));
}
__device__ __forceinline__ void store8(float* __restrict__ p, const float* r){
  float4 a; a.x=r[0];a.y=r[1];a.z=r[2];a.w=r[3];
  float4 b; b.x=r[4];b.y=r[5];b.z=r[6];b.w=r[7];
  *(float4*)p = a; *(float4*)(p+4) = b;
}
__device__ __forceinline__ uint4 pack8(const float* a){
  uint4 pk;
  pk.x = (u32)f2bf(a[0]) | ((u32)f2bf(a[1]) << 16);
  pk.y = (u32)f2bf(a[2]) | ((u32)f2bf(a[3]) << 16);
  pk.z = (u32)f2bf(a[4]) | ((u32)f2bf(a[5]) << 16);
  pk.w = (u32)f2bf(a[6]) | ((u32)f2bf(a[7]) << 16);
  return pk;
}
typedef __attribute__((address_space(1))) unsigned as1u;
typedef __attribute__((address_space(3))) unsigned as3u;
__device__ __forceinline__ void gload16(const void* g, void* l){
  __builtin_amdgcn_global_load_lds((as1u*)(uintptr_t)g, (as3u*)(uintptr_t)l, 16, 0, 0);
}

// ---------------- vectorized f32 -> bf16 (8/thread) ----------------
__global__ void f2bf8_kernel(const float* __restrict__ in, u16* __restrict__ out, int n8){
  int i = blockIdx.x*256 + threadIdx.x;
  if (i < n8){
    float r[8]; load8(in + (size_t)i*8, r);
    *(uint4*)(out + (size_t)i*8) = pack8(r);
  }
}

// ---------------- transpose f32[K][N] -> bf16[N][K] ----------------
__global__ void transpose_bf16_kernel(const float* __restrict__ in, u16* __restrict__ out, int K, int N){
  int i = blockIdx.x*256 + threadIdx.x;
  if (i < K*N){
    int k = i / N, n = i - k*N;
    out[(size_t)n*K + k] = f2bf(in[i]);
  }
}

// four 512x512 transposes in one launch (blockIdx.y selects matrix)
__global__ void transpose4_kernel(const float* __restrict__ s0, const float* __restrict__ s1,
                                  const float* __restrict__ s2, const float* __restrict__ s3,
                                  u16* __restrict__ d0, u16* __restrict__ d1,
                                  u16* __restrict__ d2, u16* __restrict__ d3){
  const float* src; u16* dst;
  switch (blockIdx.y){
    case 0: src = s0; dst = d0; break;
    case 1: src = s1; dst = d1; break;
    case 2: src = s2; dst = d2; break;
    default: src = s3; dst = d3; break;
  }
  int i = blockIdx.x*256 + threadIdx.x;
  int k = i >> 9, n = i & 511;
  dst[(size_t)n*DD + k] = f2bf(src[i]);
}

// ---------------- cell ids ----------------
__global__ void cell_kernel(const float* __restrict__ coords, int* __restrict__ cell, int n){
  int i = blockIdx.x*256 + threadIdx.x;
  if (i < n){
    float x = coords[2*i], y = coords[2*i+1];
    int gx = (int)(x * (1.0f/32.0f)); gx = gx < 0 ? 0 : (gx > 7 ? 7 : gx);
    int gy = (int)(y * (1.0f/32.0f)); gy = gy < 0 ? 0 : (gy > 7 ? 7 : gy);
    cell[i] = gx*8 + gy;
  }
}

// ---------------- stable counting sort (rank) per batch: deterministic ----------------
__global__ __launch_bounds__(256) void rank_kernel(
    const int* __restrict__ cell, int* __restrict__ order,
    int* __restrict__ counts, int* __restrict__ cellstart)
{
  int b = blockIdx.x;                 // 0..7
  __shared__ int lc[NPT];             // 8KB
  __shared__ u16 hist[256][65];       // 33.3KB
  __shared__ int tot[GG], base[GG];
  int t = threadIdx.x;
  for (int i = t; i < NPT; i += 256) lc[i] = cell[b*NPT + i];
  #pragma unroll
  for (int i = 0; i < 65; i++) hist[t][i] = 0;
  __syncthreads();
  int myc[8];
  #pragma unroll
  for (int i = 0; i < 8; i++){ myc[i] = lc[t*8 + i]; hist[t][myc[i]]++; }
  __syncthreads();
  if (t < GG){
    int acc = 0;
    for (int tt = 0; tt < 256; tt++){ int v = hist[tt][t]; hist[tt][t] = (u16)acc; acc += v; }
    tot[t] = acc;
  }
  __syncthreads();
  if (t == 0){
    int acc = 0;
    for (int g = 0; g < GG; g++){ base[g] = acc; acc += tot[g]; }
  }
  __syncthreads();
  if (t < GG){
    counts[b*GG + t] = tot[t];
    cellstart[b*GG + t] = base[t];
  }
  #pragma unroll
  for (int i = 0; i < 8; i++){
    int g = myc[i];
    int local = 0;
    #pragma unroll
    for (int j = 0; j < 8; j++) local += (j < i && myc[j] == g) ? 1 : 0;
    order[b*NPT + base[g] + (int)hist[t][g] + local] = t*8 + i;
  }
}

// ---------------- segment mean via sorted gather: one block per (b,g), 2-wide ILP ----------------
__global__ __launch_bounds__(256) void mean_kernel(
    const u16* __restrict__ feat_bf, const int* __restrict__ order,
    const int* __restrict__ counts, const int* __restrict__ cellstart,
    u16* __restrict__ meanA)
{
  int bg = blockIdx.x;                // 0..511
  int b = bg >> 6;
  int t = threadIdx.x;                // owns dims 2t, 2t+1
  int cnt = counts[bg], start = cellstart[bg];
  const int* ord = order + b*NPT + start;
  float a0 = 0.f, a1 = 0.f, c0 = 0.f, c1 = 0.f;
  int n = 0;
  for (; n + 1 < cnt; n += 2){
    int idx0 = ord[n], idx1 = ord[n+1];
    u32 v0 = *(const u32*)(feat_bf + (((size_t)(b*NPT + idx0)) << 9) + t*2);
    u32 v1 = *(const u32*)(feat_bf + (((size_t)(b*NPT + idx1)) << 9) + t*2);
    a0 += bf2f((u16)v0); a1 += bf2f((u16)(v0 >> 16));
    c0 += bf2f((u16)v1); c1 += bf2f((u16)(v1 >> 16));
  }
  if (n < cnt){
    int idx = ord[n];
    u32 v = *(const u32*)(feat_bf + (((size_t)(b*NPT + idx)) << 9) + t*2);
    a0 += bf2f((u16)v); a1 += bf2f((u16)(v >> 16));
  }
  a0 += c0; a1 += c1;
  float inv = 1.f / (float)(cnt > 0 ? cnt : 1);
  u32 pk = (u32)f2bf(a0*inv) | ((u32)f2bf(a1*inv) << 16);
  *(u32*)(meanA + (size_t)bg*DD + t*2) = pk;
}

// ---------------- pos-enc MLP: one block per offset kk, writes meanA rows 512..520 ----------------
__global__ __launch_bounds__(256) void pe_kernel(
    const float* __restrict__ W_p1, const float* __restrict__ b_p1,
    const float* __restrict__ W_p2, const float* __restrict__ b_p2,
    u16* __restrict__ meanA)
{
  int kk = blockIdx.x;          // 0..8
  float dx = (float)(kk/3 - 1), dy = (float)(kk%3 - 1);
  __shared__ float h[256];
  int t = threadIdx.x;
  float hv = dx*W_p1[t] + dy*W_p1[256 + t] + b_p1[t];
  h[t] = hv > 0.f ? hv : 0.f;
  __syncthreads();
  float acc0 = b_p2[t], acc1 = b_p2[t + 256];
  for (int c = 0; c < 256; c++){
    float hc = h[c];
    acc0 += hc * W_p2[(size_t)c*DD + t];
    acc1 += hc * W_p2[(size_t)c*DD + t + 256];
  }
  meanA[(size_t)(512 + kk)*DD + t]       = f2bf(acc0);
  meanA[(size_t)(512 + kk)*DD + t + 256] = f2bf(acc1);
}

// ---------------- bfq[i] = sum_k b_feat[k]*Wq[k][i] + bq[i]  (wave per i) ----------------
__global__ __launch_bounds__(256) void bfq_kernel(
    const u16* __restrict__ WqT, const float* __restrict__ b_feat,
    const float* __restrict__ bq, float* __restrict__ bfq)
{
  int wv = threadIdx.x >> 6, lane = threadIdx.x & 63;
  int i = blockIdx.x*4 + wv;    // 0..511
  float w8[8], b8[8];
  load8bf(WqT + (size_t)i*DD + lane*8, w8);
  load8(b_feat + lane*8, b8);
  float s = 0.f;
  #pragma unroll
  for (int j = 0; j < 8; j++) s += w8[j]*b8[j];
  #pragma unroll
  for (int m = 1; m < 64; m <<= 1) s += __shfl_xor(s, m);
  if (lane == 0) bfq[i] = s + bq[i];
}

// ======== shared GEMM main loop (128x128 tile, 4 waves, global_load_lds) ========
#define BM 128
#define BN 128
#define GEMM_MAIN(A, Bt, K)                                                        \
  __shared__ __align__(16) u16 lA[BM*32];                                          \
  __shared__ __align__(16) u16 lB[BN*32];                                          \
  int tid = threadIdx.x;                                                           \
  int m0 = blockIdx.y * BM, n0 = blockIdx.x * BN;                                  \
  int lane = tid & 63;                                                             \
  int wv = tid >> 6;                                                               \
  int wm = (wv >> 1) * 64, wn = (wv & 1) * 64;                                     \
  int lr = lane & 15;                                                              \
  int kg = (lane >> 4) << 3;                                                       \
  f32x4 acc[4][4] = {};                                                            \
  int srow = lane >> 2;                                                            \
  int scol = (lane & 3) << 3;                                                      \
  const u16* gA0 = (A)  + (size_t)(m0 + wv*32 + srow)*(K) + scol;                  \
  const u16* gB0 = (Bt) + (size_t)(n0 + wv*32 + srow)*(K) + scol;                  \
  u16* lA0 = lA + (wv*32)*32;                                                      \
  u16* lB0 = lB + (wv*32)*32;                                                      \
  for (int kt = 0; kt < (K); kt += 32){                                            \
    gload16(gA0 + kt,                  lA0);                                       \
    gload16(gA0 + kt + (size_t)16*(K), lA0 + 16*32);                               \
    gload16(gB0 + kt,                  lB0);                                       \
    gload16(gB0 + kt + (size_t)16*(K), lB0 + 16*32);                               \
    __syncthreads();                                                               \
    bf16x8 af[4], bfv[4];                                                          \
    _Pragma("unroll")                                                              \
    for (int i = 0; i < 4; i++) af[i]  = *(const bf16x8*)&lA[(wm + i*16 + lr)*32 + kg]; \
    _Pragma("unroll")                                                              \
    for (int j = 0; j < 4; j++) bfv[j] = *(const bf16x8*)&lB[(wn + j*16 + lr)*32 + kg]; \
    _Pragma("unroll")                                                              \
    for (int i = 0; i < 4; i++)                                                    \
      _Pragma("unroll")                                                            \
      for (int j = 0; j < 4; j++)                                                  \
        acc[i][j] = __builtin_amdgcn_mfma_f32_16x16x32_bf16(af[i], bfv[j], acc[i][j], 0, 0, 0); \
    __syncthreads();                                                               \
  }                                                                                \
  int lrow = (lane >> 4) << 2;

// ---------------- generic GEMM: C[M][N] = A[M][K]*Bt[N][K]^T (+bias) ----------------
__global__ __launch_bounds__(256) void gemm_bf16(
    const u16* __restrict__ A, const u16* __restrict__ Bt,
    const float* __restrict__ bias,
    float* __restrict__ C, u16* __restrict__ Cbf,
    int M, int N, int K)
{
  GEMM_MAIN(A, Bt, K)
  #pragma unroll
  for (int j = 0; j < 4; j++){
    int col = n0 + wn + j*16 + lr;
    float bcol = bias ? bias[col] : 0.f;
    #pragma unroll
    for (int i = 0; i < 4; i++){
      int row0 = m0 + wm + i*16 + lrow;
      #pragma unroll
      for (int r = 0; r < 4; r++){
        float v = acc[i][j][r] + bcol;
        if (C)   C[(size_t)(row0 + r)*N + col] = v;
        if (Cbf) Cbf[(size_t)(row0 + r)*N + col] = f2bf(v);
      }
    }
  }
}

// ---------------- fused feat+q GEMM: N=1024, cols<512 -> feat_bf, cols>=512 -> q_bf ----------------
__global__ __launch_bounds__(256) void gemm_featq(
    const u16* __restrict__ A, const u16* __restrict__ Bt,
    const float* __restrict__ bias0, const float* __restrict__ bias1,
    u16* __restrict__ out0, u16* __restrict__ out1, int K)
{
  GEMM_MAIN(A, Bt, K)
  int half = n0 >> 9;
  u16* outp = half ? out1 : out0;
  const float* bias = half ? bias1 : bias0;
  int nb = n0 & 511;
  #pragma unroll
  for (int j = 0; j < 4; j++){
    int col = nb + wn + j*16 + lr;
    float bcol = bias[col];
    #pragma unroll
    for (int i = 0; i < 4; i++){
      int row0 = m0 + wm + i*16 + lrow;
      #pragma unroll
      for (int r = 0; r < 4; r++)
        outp[(size_t)(row0 + r)*DD + col] = f2bf(acc[i][j][r] + bcol);
    }
  }
}

// ---------------- cell-centric attention: 4 blocks per (b,cell) for occupancy ----------------
// meanKV: [640][1024] f32; cols 0..511 = K-proj, 512..1023 = V-proj; rows 512+kk = pe.
__global__ __launch_bounds__(256) void attn_cells(
    const u16* __restrict__ q, const float* __restrict__ meanKV,
    const int* __restrict__ order, const int* __restrict__ counts,
    const int* __restrict__ cellstart, const float* __restrict__ bk,
    const float* __restrict__ bv, u16* __restrict__ agg)
{
  int bg4 = blockIdx.x;           // 0..2047
  int bg = bg4 >> 2, part = bg4 & 3;
  int b = bg >> 6, c = bg & 63;
  int gx = c >> 3, gy = c & 7;
  __shared__ __align__(16) u16 Kf[9][DD];   // 9KB bf16
  __shared__ __align__(16) u16 Vf[9][DD];   // 9KB
  __shared__ int vrow[9];
  int t = threadIdx.x;
  if (t < 9){
    int dx = t/3 - 1, dy = t%3 - 1;
    int nx = gx + dx, ny = gy + dy;
    int inb = ((unsigned)nx < 8u) && ((unsigned)ny < 8u);
    int row = b*GG + (((nx&7) << 3) | (ny&7));
    vrow[t] = (inb && counts[row] > 0) ? row : -1;
  }
  __syncthreads();
  int d = 2*t;
  float bk0 = bk[d], bk1 = bk[d+1];
  float bv0 = bv[d], bv1 = bv[d+1];
  #pragma unroll
  for (int kk = 0; kk < 9; kk++){
    int row = vrow[kk];
    if (row >= 0){
      float2 mk = *(const float2*)&meanKV[(size_t)row*1024 + d];
      float2 pk = *(const float2*)&meanKV[(size_t)(512+kk)*1024 + d];
      float2 mv = *(const float2*)&meanKV[(size_t)row*1024 + 512 + d];
      float2 pv = *(const float2*)&meanKV[(size_t)(512+kk)*1024 + 512 + d];
      *(u32*)&Kf[kk][d] = (u32)f2bf(mk.x+pk.x+bk0) | ((u32)f2bf(mk.y+pk.y+bk1) << 16);
      *(u32*)&Vf[kk][d] = (u32)f2bf(mv.x+pv.x+bv0) | ((u32)f2bf(mv.y+pv.y+bv1) << 16);
    }
  }
  __syncthreads();
  int cnt = counts[bg];
  int wv = t >> 6, lane = t & 63;
  int widx = part*4 + wv;               // 0..15: global wave slot for this cell
  const int* ord = order + b*NPT + cellstart[bg];
  for (int i = widx; i < cnt; i += 16){
    size_t p = (size_t)b*NPT + ord[i];
    float qv[8];
    load8bf(q + p*DD + lane*8, qv);
    float s[9];
    #pragma unroll
    for (int kk = 0; kk < 9; kk++){
      float partial = 0.f;
      if (vrow[kk] >= 0){
        float kv[8]; load8bf(&Kf[kk][lane*8], kv);
        #pragma unroll
        for (int j = 0; j < 8; j++) partial += qv[j]*kv[j];
      }
      partial += __shfl_xor(partial, 1);
      partial += __shfl_xor(partial, 2);
      partial += __shfl_xor(partial, 4);
      partial += __shfl_xor(partial, 8);
      s[kk] = (vrow[kk] >= 0) ? partial * 0.08838834764831843f : -1e30f;
    }
    float mx = s[0];
    #pragma unroll
    for (int kk = 1; kk < 9; kk++) mx = fmaxf(mx, s[kk]);
    float w[9], sum = 0.f;
    #pragma unroll
    for (int kk = 0; kk < 9; kk++){
      w[kk] = (vrow[kk] >= 0) ? __expf(s[kk] - mx) : 0.f;
      sum += w[kk];
    }
    float inv = 1.f / sum;
    float a[8] = {0,0,0,0,0,0,0,0};
    #pragma unroll
    for (int kk = 0; kk < 9; kk++){
      if (vrow[kk] >= 0){
        float wk = w[kk] * inv;
        float vv[8]; load8bf(&Vf[kk][lane*8], vv);
        #pragma unroll
        for (int j = 0; j < 8; j++) a[j] += wk*vv[j];
      }
    }
    *(uint4*)&agg[p*DD + lane*8] = pack8(a);
  }
}

// ---------------- residual + layernorm (bf16 inputs): one wave per row ----------------
__global__ __launch_bounds__(256) void ln_kernel(
    const u16* __restrict__ feat, const u16* __restrict__ lin,
    const float* __restrict__ gamma, const float* __restrict__ beta,
    float* __restrict__ out)
{
  int wv = threadIdx.x >> 6, lane = threadIdx.x & 63;
  size_t r = (size_t)blockIdx.x * 4 + wv;
  int d0 = lane * 8;
  float fv[8], lv[8];
  load8bf(feat + r*DD + d0, fv);
  load8bf(lin  + r*DD + d0, lv);
  float e[8], s1 = 0.f, s2 = 0.f;
  #pragma unroll
  for (int j = 0; j < 8; j++){ e[j] = fv[j] + lv[j]; s1 += e[j]; s2 += e[j]*e[j]; }
  #pragma unroll
  for (int m = 1; m < 64; m <<= 1){ s1 += __shfl_xor(s1, m); s2 += __shfl_xor(s2, m); }
  float mu  = s1 * (1.f/512.f);
  float var = s2 * (1.f/512.f) - mu*mu;
  float istd = rsqrtf(var + 1e-5f);
  float gv[8], bev[8];
  load8(gamma + d0, gv); load8(beta + d0, bev);
  float o[8];
  #pragma unroll
  for (int j = 0; j < 8; j++) o[j] = (e[j] - mu)*istd*gv[j] + bev[j];
  store8(out + r*DD + d0, o);
}

extern "C" void kernel_launch(void* const* d_in, const int* in_sizes, int n_in,
                              void* d_out, int out_size, void* d_ws, size_t ws_size,
                              hipStream_t stream) {
  (void)in_sizes; (void)n_in; (void)out_size; (void)ws_size;
  const float* features = (const float*)d_in[0];
  const float* coords   = (const float*)d_in[1];
  const float* W_feat   = (const float*)d_in[2];
  const float* b_feat   = (const float*)d_in[3];
  const float* W_p1     = (const float*)d_in[4];
  const float* b_p1     = (const float*)d_in[5];
  const float* W_p2     = (const float*)d_in[6];
  const float* b_p2     = (const float*)d_in[7];
  const float* Wq = (const float*)d_in[8];  const float* bq = (const float*)d_in[9];
  const float* Wk = (const float*)d_in[10]; const float* bk = (const float*)d_in[11];
  const float* Wv = (const float*)d_in[12]; const float* bv = (const float*)d_in[13];
  const float* Wo = (const float*)d_in[14]; const float* bo = (const float*)d_in[15];
  const float* gamma = (const float*)d_in[16]; const float* beta = (const float*)d_in[17];
  float* out = (float*)d_out;

  char* ws = (char*)d_ws;
  size_t off = 0;
  auto alloc = [&](size_t bytes) -> void* {
    void* p = ws + off;
    off = (off + bytes + 255) & ~(size_t)255;
    return p;
  };
  u16*   featA     = (u16*)  alloc((size_t)NPTS*INDIM*2);   // 8.4 MB
  u16*   feat_bf   = (u16*)  alloc((size_t)NPTS*DD*2);      // 16.8 MB
  u16*   q_bf      = (u16*)  alloc((size_t)NPTS*DD*2);      // 16.8 MB
  u16*   agg_bf    = (u16*)  alloc((size_t)NPTS*DD*2);      // 16.8 MB
  u16*   lin_bf    = (u16*)  alloc((size_t)NPTS*DD*2);      // 16.8 MB
  u16*   WcatT     = (u16*)  alloc((size_t)1024*INDIM*2);   // rows 0..511 WfeatT, 512..1023 WfqT
  u16*   W_feat_bf = (u16*)  alloc((size_t)INDIM*DD*2);
  u16*   WqT       = (u16*)  alloc((size_t)DD*DD*2);
  u16*   WoT       = (u16*)  alloc((size_t)DD*DD*2);
  u16*   WkvT      = (u16*)  alloc((size_t)1024*DD*2);      // rows 0..511 WkT, 512..1023 WvT
  u16*   meanA     = (u16*)  alloc((size_t)MEANROWS*DD*2);  // rows 0..511 mean, 512..520 pe
  float* meanKV    = (float*)alloc((size_t)MEANROWS*1024*4);// [640][1024]: K | V
  float* bfq       = (float*)alloc((size_t)DD*4);
  int*   cell      = (int*)  alloc((size_t)NPTS*4);
  int*   order     = (int*)  alloc((size_t)NPTS*4);
  int*   counts    = (int*)  alloc((size_t)NBATCH*GG*4);
  int*   cellstart = (int*)  alloc((size_t)NBATCH*GG*4);
  u16*   WfeatT = WcatT;                  // [512][256]
  u16*   WfqT   = WcatT + (size_t)512*INDIM;  // [512][256]

  // conversions / transposes / bucketing metadata
  f2bf8_kernel<<<(NPTS*INDIM/8 + 255)/256, 256, 0, stream>>>(features, featA, NPTS*INDIM/8);
  f2bf8_kernel<<<(INDIM*DD/8 + 255)/256, 256, 0, stream>>>(W_feat, W_feat_bf, INDIM*DD/8);
  transpose_bf16_kernel<<<(INDIM*DD + 255)/256, 256, 0, stream>>>(W_feat, WfeatT, INDIM, DD);
  transpose4_kernel<<<dim3(DD*DD/256, 4), 256, 0, stream>>>(
      Wq, Wk, Wv, Wo, WqT, WkvT, WkvT + (size_t)512*DD, WoT);
  cell_kernel<<<NPTS/256, 256, 0, stream>>>(coords, cell, NPTS);
  rank_kernel<<<NBATCH, 256, 0, stream>>>(cell, order, counts, cellstart);

  // WfqT = Wq^T @ W_feat^T  [512][256]  (M=512,N=256,K=512)
  gemm_bf16<<<dim3(INDIM/BN + (INDIM%BN?1:0), DD/BM), 256, 0, stream>>>(
      WqT, W_feat_bf, nullptr, nullptr, WfqT, DD, INDIM, DD);
  // bfq = b_feat @ Wq + bq
  bfq_kernel<<<DD/4, 256, 0, stream>>>(WqT, b_feat, bq, bfq);

  // fused: [feat | q] = features @ [W_feat | Wfq]  (M=16384, N=1024, K=256)
  gemm_featq<<<dim3(1024/BN, NPTS/BM), 256, 0, stream>>>(
      featA, WcatT, b_feat, bfq, feat_bf, q_bf, INDIM);

  // segment mean -> meanA rows 0..511; pe rows 512..520
  mean_kernel<<<NBATCH*GG, 256, 0, stream>>>(feat_bf, order, counts, cellstart, meanA);
  pe_kernel<<<9, 256, 0, stream>>>(W_p1, b_p1, W_p2, b_p2, meanA);

  // meanKV = meanA @ [Wk | Wv]  (M=640, N=1024, K=512; biases folded later)
  gemm_bf16<<<dim3(1024/BN, MEANROWS/BM), 256, 0, stream>>>(
      meanA, WkvT, nullptr, meanKV, nullptr, MEANROWS, 1024, DD);

  // cell-centric attention (4 blocks per cell) -> agg (bf16)
  attn_cells<<<NBATCH*GG*4, 256, 0, stream>>>(q_bf, meanKV, order, counts, cellstart, bk, bv, agg_bf);

  // lin = agg @ Wo + bo (bf16)
  gemm_bf16<<<dim3(DD/BN, NPTS/BM), 256, 0, stream>>>(agg_bf, WoT, bo, nullptr, lin_bf, NPTS, DD, DD);
  // out = LN(feat + lin) * gamma + beta
  ln_kernel<<<NPTS/4, 256, 0, stream>>>(feat_bf, lin_bf, gamma, beta, out);
}

// Round 5
// 153.603 us; speedup vs baseline: 1.9960x; 1.1063x over previous
//
#include <hip/hip_runtime.h>
#include <stdint.h>

typedef unsigned short u16;
typedef unsigned int u32;
typedef __bf16 bf16x8 __attribute__((ext_vector_type(8)));
typedef float f32x4 __attribute__((ext_vector_type(4)));

#define NBATCH 8
#define NPT    2048
#define NPTS   16384     // NBATCH*NPT
#define INDIM  256
#define DD     512
#define GG     64        // 8x8 grid cells
#define MEANROWS 640     // 512 mean rows + 9 pe rows, padded to 128-multiple

__device__ __forceinline__ u16 f2bf(float f){
  u32 u = __builtin_bit_cast(u32, f);
  u += 0x7fffu + ((u >> 16) & 1u);
  return (u16)(u >> 16);
}
__device__ __forceinline__ float bf2f(u16 h){
  u32 u = ((u32)h) << 16;
  return __builtin_bit_cast(float, u);
}
__device__ __forceinline__ void load8(const float* __restrict__ p, float* r){
  float4 a = *(const float4*)p;
  float4 b = *(const float4*)(p + 4);
  r[0]=a.x;r[1]=a.y;r[2]=a.z;r[3]=a.w;r[4]=b.x;r[5]=b.y;r[6]=b.z;r[7]=b.w;
}
__device__ __forceinline__ void load8bf(const u16* __restrict__ p, float* r){
  uint4 v = *(const uint4*)p;
  r[0]=bf2f((u16)v.x); r[1]=bf2f((u16)(v.x>>16));
  r[2]=bf2f((u16)v.y); r[3]=bf2f((u16)(v.y>>16));
  r[4]=bf2f((u16)v.z); r[5]=bf2f((u16)(v.z>>16));
  r[6]=bf2f((u16)v.w); r[7]=bf2f((u16)(v.w>>16));
}
__device__ __forceinline__ void store8(float* __restrict__ p, const float* r){
  float4 a; a.x=r[0];a.y=r[1];a.z=r[2];a.w=r[3];
  float4 b; b.x=r[4];b.y=r[5];b.z=r[6];b.w=r[7];
  *(float4*)p = a; *(float4*)(p+4) = b;
}
__device__ __forceinline__ uint4 pack8(const float* a){
  uint4 pk;
  pk.x = (u32)f2bf(a[0]) | ((u32)f2bf(a[1]) << 16);
  pk.y = (u32)f2bf(a[2]) | ((u32)f2bf(a[3]) << 16);
  pk.z = (u32)f2bf(a[4]) | ((u32)f2bf(a[5]) << 16);
  pk.w = (u32)f2bf(a[6]) | ((u32)f2bf(a[7]) << 16);
  return pk;
}
typedef __attribute__((address_space(1))) unsigned as1u;
typedef __attribute__((address_space(3))) unsigned as3u;
__device__ __forceinline__ void gload16(const void* g, void* l){
  __builtin_amdgcn_global_load_lds((as1u*)(uintptr_t)g, (as3u*)(uintptr_t)l, 16, 0, 0);
}

// ---------------- rank: cell-id + stable counting sort per batch (deterministic) ----------------
__global__ __launch_bounds__(256) void rank_kernel(
    const float* __restrict__ coords, int* __restrict__ order,
    int* __restrict__ counts, int* __restrict__ cellstart)
{
  int b = blockIdx.x;                 // 0..7
  __shared__ u16 hist[256][65];       // 33.3KB
  __shared__ int tot[GG], base[GG];
  int t = threadIdx.x;
  #pragma unroll
  for (int i = 0; i < 65; i++) hist[t][i] = 0;
  int myc[8];
  float cxy[16];
  load8(coords + (size_t)(b*NPT + t*8)*2,     cxy);
  load8(coords + (size_t)(b*NPT + t*8)*2 + 8, cxy + 8);
  #pragma unroll
  for (int i = 0; i < 8; i++){
    int gx = (int)(cxy[2*i]   * (1.0f/32.0f)); gx = gx < 0 ? 0 : (gx > 7 ? 7 : gx);
    int gy = (int)(cxy[2*i+1] * (1.0f/32.0f)); gy = gy < 0 ? 0 : (gy > 7 ? 7 : gy);
    myc[i] = gx*8 + gy;
    hist[t][myc[i]]++;
  }
  __syncthreads();
  if (t < GG){
    int acc = 0;
    for (int tt = 0; tt < 256; tt++){ int v = hist[tt][t]; hist[tt][t] = (u16)acc; acc += v; }
    tot[t] = acc;
  }
  __syncthreads();
  if (t == 0){
    int acc = 0;
    for (int g = 0; g < GG; g++){ base[g] = acc; acc += tot[g]; }
  }
  __syncthreads();
  if (t < GG){
    counts[b*GG + t] = tot[t];
    cellstart[b*GG + t] = base[t];
  }
  #pragma unroll
  for (int i = 0; i < 8; i++){
    int g = myc[i];
    int local = 0;
    #pragma unroll
    for (int j = 0; j < 8; j++) local += (j < i && myc[j] == g) ? 1 : 0;
    order[b*NPT + base[g] + (int)hist[t][g] + local] = t*8 + i;
  }
}

// ---------------- fused prep: all independent preprocessing in one launch ----------------
// block ranges:
//  [0,2048)        f2bf features (8/thread)
//  [2048,6144)     transpose Wq/Wk/Wv/Wo -> WqT / WkvT lo / WkvT hi / WoT
//  [6144,6656)     transpose W_feat -> WcatT rows 0..511
//  [6656,6664)     f2bf W_feat -> W_feat_bf (8/thread)
//  [6664,6673)     pos-enc MLP -> meanA rows 512..520
//  [6673,6675)     bfq = b_feat @ Wq + bq
//  [6675]          biaskv = [bk | bv]
#define P_O1 2048
#define P_O2 6144
#define P_O3 6656
#define P_O4 6664
#define P_O5 6673
#define P_O6 6675
#define P_NB 6676
__global__ __launch_bounds__(256) void prep_kernel(
    const float* __restrict__ features, const float* __restrict__ W_feat,
    const float* __restrict__ Wq, const float* __restrict__ Wk,
    const float* __restrict__ Wv, const float* __restrict__ Wo,
    const float* __restrict__ W_p1, const float* __restrict__ b_p1,
    const float* __restrict__ W_p2, const float* __restrict__ b_p2,
    const float* __restrict__ b_feat, const float* __restrict__ bq,
    const float* __restrict__ bk, const float* __restrict__ bv,
    u16* __restrict__ featA, u16* __restrict__ WcatT, u16* __restrict__ W_feat_bf,
    u16* __restrict__ WqT, u16* __restrict__ WkvT, u16* __restrict__ WoT,
    u16* __restrict__ meanA, float* __restrict__ bfq, float* __restrict__ biaskv)
{
  int bid = blockIdx.x, t = threadIdx.x;
  if (bid < P_O1){
    int i = bid*256 + t;
    float r[8]; load8(features + (size_t)i*8, r);
    *(uint4*)(featA + (size_t)i*8) = pack8(r);
  } else if (bid < P_O2){
    int r = bid - P_O1;
    int mat = r >> 10;
    int i = (r & 1023)*256 + t;
    int k = i >> 9, n = i & 511;
    const float* src = mat==0 ? Wq : (mat==1 ? Wk : (mat==2 ? Wv : Wo));
    u16* dst = mat==0 ? WqT : (mat==1 ? WkvT : (mat==2 ? WkvT + (size_t)512*DD : WoT));
    dst[(size_t)n*DD + k] = f2bf(src[i]);
  } else if (bid < P_O3){
    int i = (bid - P_O2)*256 + t;       // over 256x512 elements of W_feat
    int k = i >> 9, n = i & 511;
    WcatT[(size_t)n*INDIM + k] = f2bf(W_feat[i]);
  } else if (bid < P_O4){
    int i = (bid - P_O3)*256 + t;
    float r[8]; load8(W_feat + (size_t)i*8, r);
    *(uint4*)(W_feat_bf + (size_t)i*8) = pack8(r);
  } else if (bid < P_O5){
    int kk = bid - P_O4;                // 0..8
    float dx = (float)(kk/3 - 1), dy = (float)(kk%3 - 1);
    __shared__ float h[256];
    float hv = dx*W_p1[t] + dy*W_p1[256 + t] + b_p1[t];
    h[t] = hv > 0.f ? hv : 0.f;
    __syncthreads();
    float acc0 = b_p2[t], acc1 = b_p2[t + 256];
    for (int c = 0; c < 256; c++){
      float hc = h[c];
      acc0 += hc * W_p2[(size_t)c*DD + t];
      acc1 += hc * W_p2[(size_t)c*DD + t + 256];
    }
    meanA[(size_t)(512 + kk)*DD + t]       = f2bf(acc0);
    meanA[(size_t)(512 + kk)*DD + t + 256] = f2bf(acc1);
  } else if (bid < P_O6){
    int i = (bid - P_O5)*256 + t;       // 0..511
    float acc = 0.f;
    for (int k = 0; k < DD; k++)
      acc += b_feat[k] * Wq[(size_t)k*DD + i];
    bfq[i] = acc + bq[i];
  } else {
    biaskv[t]       = bk[t];
    biaskv[256 + t] = bk[256 + t];
    biaskv[512 + t] = bv[t];
    biaskv[768 + t] = bv[256 + t];
  }
}

// ---------------- segment mean via sorted gather: one block per (b,g), 2-wide ILP ----------------
__global__ __launch_bounds__(256) void mean_kernel(
    const u16* __restrict__ feat_bf, const int* __restrict__ order,
    const int* __restrict__ counts, const int* __restrict__ cellstart,
    u16* __restrict__ meanA)
{
  int bg = blockIdx.x;                // 0..511
  int b = bg >> 6;
  int t = threadIdx.x;                // owns dims 2t, 2t+1
  int cnt = counts[bg], start = cellstart[bg];
  const int* ord = order + b*NPT + start;
  float a0 = 0.f, a1 = 0.f, c0 = 0.f, c1 = 0.f;
  int n = 0;
  for (; n + 1 < cnt; n += 2){
    int idx0 = ord[n], idx1 = ord[n+1];
    u32 v0 = *(const u32*)(feat_bf + (((size_t)(b*NPT + idx0)) << 9) + t*2);
    u32 v1 = *(const u32*)(feat_bf + (((size_t)(b*NPT + idx1)) << 9) + t*2);
    a0 += bf2f((u16)v0); a1 += bf2f((u16)(v0 >> 16));
    c0 += bf2f((u16)v1); c1 += bf2f((u16)(v1 >> 16));
  }
  if (n < cnt){
    int idx = ord[n];
    u32 v = *(const u32*)(feat_bf + (((size_t)(b*NPT + idx)) << 9) + t*2);
    a0 += bf2f((u16)v); a1 += bf2f((u16)(v >> 16));
  }
  a0 += c0; a1 += c1;
  float inv = 1.f / (float)(cnt > 0 ? cnt : 1);
  u32 pk = (u32)f2bf(a0*inv) | ((u32)f2bf(a1*inv) << 16);
  *(u32*)(meanA + (size_t)bg*DD + t*2) = pk;
}

// ======== shared GEMM main loop (128x128 tile, 4 waves, global_load_lds, XCD swizzle) ========
// requires gridDim.x*gridDim.y % 8 == 0
#define BM 128
#define BN 128
#define GEMM_MAIN(A, Bt, K)                                                        \
  __shared__ __align__(16) u16 lA[BM*32];                                          \
  __shared__ __align__(16) u16 lB[BN*32];                                          \
  int tid = threadIdx.x;                                                           \
  int nwg_ = gridDim.x*gridDim.y;                                                  \
  int orig_ = blockIdx.y*gridDim.x + blockIdx.x;                                   \
  int swz_ = (orig_ & 7)*(nwg_ >> 3) + (orig_ >> 3);                               \
  int m0 = (swz_ / gridDim.x) * BM, n0 = (swz_ % gridDim.x) * BN;                  \
  int lane = tid & 63;                                                             \
  int wv = tid >> 6;                                                               \
  int wm = (wv >> 1) * 64, wn = (wv & 1) * 64;                                     \
  int lr = lane & 15;                                                              \
  int kg = (lane >> 4) << 3;                                                       \
  f32x4 acc[4][4] = {};                                                            \
  int srow = lane >> 2;                                                            \
  int scol = (lane & 3) << 3;                                                      \
  const u16* gA0 = (A)  + (size_t)(m0 + wv*32 + srow)*(K) + scol;                  \
  const u16* gB0 = (Bt) + (size_t)(n0 + wv*32 + srow)*(K) + scol;                  \
  u16* lA0 = lA + (wv*32)*32;                                                      \
  u16* lB0 = lB + (wv*32)*32;                                                      \
  for (int kt = 0; kt < (K); kt += 32){                                            \
    gload16(gA0 + kt,                  lA0);                                       \
    gload16(gA0 + kt + (size_t)16*(K), lA0 + 16*32);                               \
    gload16(gB0 + kt,                  lB0);                                       \
    gload16(gB0 + kt + (size_t)16*(K), lB0 + 16*32);                               \
    __syncthreads();                                                               \
    bf16x8 af[4], bfv[4];                                                          \
    _Pragma("unroll")                                                              \
    for (int i = 0; i < 4; i++) af[i]  = *(const bf16x8*)&lA[(wm + i*16 + lr)*32 + kg]; \
    _Pragma("unroll")                                                              \
    for (int j = 0; j < 4; j++) bfv[j] = *(const bf16x8*)&lB[(wn + j*16 + lr)*32 + kg]; \
    _Pragma("unroll")                                                              \
    for (int i = 0; i < 4; i++)                                                    \
      _Pragma("unroll")                                                            \
      for (int j = 0; j < 4; j++)                                                  \
        acc[i][j] = __builtin_amdgcn_mfma_f32_16x16x32_bf16(af[i], bfv[j], acc[i][j], 0, 0, 0); \
    __syncthreads();                                                               \
  }                                                                                \
  int lrow = (lane >> 4) << 2;

// ---------------- generic GEMM: C[M][N] = A[M][K]*Bt[N][K]^T (+bias on rows < bias_rows) ----------------
__global__ __launch_bounds__(256) void gemm_bf16(
    const u16* __restrict__ A, const u16* __restrict__ Bt,
    const float* __restrict__ bias, int bias_rows,
    float* __restrict__ C, u16* __restrict__ Cbf,
    int M, int N, int K)
{
  GEMM_MAIN(A, Bt, K)
  int usebias = (bias != nullptr) && (m0 < bias_rows);
  #pragma unroll
  for (int j = 0; j < 4; j++){
    int col = n0 + wn + j*16 + lr;
    float bcol = usebias ? bias[col] : 0.f;
    #pragma unroll
    for (int i = 0; i < 4; i++){
      int row0 = m0 + wm + i*16 + lrow;
      #pragma unroll
      for (int r = 0; r < 4; r++){
        float v = acc[i][j][r] + bcol;
        if (C)   C[(size_t)(row0 + r)*N + col] = v;
        if (Cbf) Cbf[(size_t)(row0 + r)*N + col] = f2bf(v);
      }
    }
  }
}

// ---------------- fused feat+q GEMM: N=1024, cols<512 -> feat_bf, cols>=512 -> q_bf ----------------
__global__ __launch_bounds__(256) void gemm_featq(
    const u16* __restrict__ A, const u16* __restrict__ Bt,
    const float* __restrict__ bias0, const float* __restrict__ bias1,
    u16* __restrict__ out0, u16* __restrict__ out1, int K)
{
  GEMM_MAIN(A, Bt, K)
  int half = n0 >> 9;
  u16* outp = half ? out1 : out0;
  const float* bias = half ? bias1 : bias0;
  int nb = n0 & 511;
  #pragma unroll
  for (int j = 0; j < 4; j++){
    int col = nb + wn + j*16 + lr;
    float bcol = bias[col];
    #pragma unroll
    for (int i = 0; i < 4; i++){
      int row0 = m0 + wm + i*16 + lrow;
      #pragma unroll
      for (int r = 0; r < 4; r++)
        outp[(size_t)(row0 + r)*DD + col] = f2bf(acc[i][j][r] + bcol);
    }
  }
}

// ---------------- cell-centric attention: 4 blocks per (b,cell) ----------------
// meanKV: [640][1024] f32; cols 0..511 = K-proj (+bk for rows<512), 512..1023 = V-proj (+bv);
// rows 512+kk = pe (no bias).
__global__ __launch_bounds__(256) void attn_cells(
    const u16* __restrict__ q, const float* __restrict__ meanKV,
    const int* __restrict__ order, const int* __restrict__ counts,
    const int* __restrict__ cellstart, u16* __restrict__ agg)
{
  int bg4 = blockIdx.x;           // 0..2047
  int bg = bg4 >> 2, part = bg4 & 3;
  int b = bg >> 6, c = bg & 63;
  int gx = c >> 3, gy = c & 7;
  __shared__ __align__(16) u16 Kf[9][DD];   // 9KB bf16
  __shared__ __align__(16) u16 Vf[9][DD];   // 9KB
  __shared__ int vrow[9];
  int t = threadIdx.x;
  if (t < 9){
    int dx = t/3 - 1, dy = t%3 - 1;
    int nx = gx + dx, ny = gy + dy;
    int inb = ((unsigned)nx < 8u) && ((unsigned)ny < 8u);
    int row = b*GG + (((nx&7) << 3) | (ny&7));
    vrow[t] = (inb && counts[row] > 0) ? row : -1;
  }
  __syncthreads();
  int d = 2*t;
  #pragma unroll
  for (int kk = 0; kk < 9; kk++){
    int row = vrow[kk];
    if (row >= 0){
      float2 mk = *(const float2*)&meanKV[(size_t)row*1024 + d];
      float2 pk = *(const float2*)&meanKV[(size_t)(512+kk)*1024 + d];
      float2 mv = *(const float2*)&meanKV[(size_t)row*1024 + 512 + d];
      float2 pv = *(const float2*)&meanKV[(size_t)(512+kk)*1024 + 512 + d];
      *(u32*)&Kf[kk][d] = (u32)f2bf(mk.x+pk.x) | ((u32)f2bf(mk.y+pk.y) << 16);
      *(u32*)&Vf[kk][d] = (u32)f2bf(mv.x+pv.x) | ((u32)f2bf(mv.y+pv.y) << 16);
    }
  }
  __syncthreads();
  int cnt = counts[bg];
  int wv = t >> 6, lane = t & 63;
  int widx = part*4 + wv;               // 0..15: global wave slot for this cell
  const int* ord = order + b*NPT + cellstart[bg];
  for (int i = widx; i < cnt; i += 16){
    size_t p = (size_t)b*NPT + ord[i];
    float qv[8];
    load8bf(q + p*DD + lane*8, qv);
    float s[9];
    #pragma unroll
    for (int kk = 0; kk < 9; kk++){
      float partial = 0.f;
      if (vrow[kk] >= 0){
        float kv[8]; load8bf(&Kf[kk][lane*8], kv);
        #pragma unroll
        for (int j = 0; j < 8; j++) partial += qv[j]*kv[j];
      }
      partial += __shfl_xor(partial, 1);
      partial += __shfl_xor(partial, 2);
      partial += __shfl_xor(partial, 4);
      partial += __shfl_xor(partial, 8);
      s[kk] = (vrow[kk] >= 0) ? partial * 0.08838834764831843f : -1e30f;
    }
    float mx = s[0];
    #pragma unroll
    for (int kk = 1; kk < 9; kk++) mx = fmaxf(mx, s[kk]);
    float w[9], sum = 0.f;
    #pragma unroll
    for (int kk = 0; kk < 9; kk++){
      w[kk] = (vrow[kk] >= 0) ? __expf(s[kk] - mx) : 0.f;
      sum += w[kk];
    }
    float inv = 1.f / sum;
    float a[8] = {0,0,0,0,0,0,0,0};
    #pragma unroll
    for (int kk = 0; kk < 9; kk++){
      if (vrow[kk] >= 0){
        float wk = w[kk] * inv;
        float vv[8]; load8bf(&Vf[kk][lane*8], vv);
        #pragma unroll
        for (int j = 0; j < 8; j++) a[j] += wk*vv[j];
      }
    }
    *(uint4*)&agg[p*DD + lane*8] = pack8(a);
  }
}

// ---------------- residual + layernorm (bf16 inputs): one wave per row ----------------
__global__ __launch_bounds__(256) void ln_kernel(
    const u16* __restrict__ feat, const u16* __restrict__ lin,
    const float* __restrict__ gamma, const float* __restrict__ beta,
    float* __restrict__ out)
{
  int wv = threadIdx.x >> 6, lane = threadIdx.x & 63;
  size_t r = (size_t)blockIdx.x * 4 + wv;
  int d0 = lane * 8;
  float fv[8], lv[8];
  load8bf(feat + r*DD + d0, fv);
  load8bf(lin  + r*DD + d0, lv);
  float e[8], s1 = 0.f, s2 = 0.f;
  #pragma unroll
  for (int j = 0; j < 8; j++){ e[j] = fv[j] + lv[j]; s1 += e[j]; s2 += e[j]*e[j]; }
  #pragma unroll
  for (int m = 1; m < 64; m <<= 1){ s1 += __shfl_xor(s1, m); s2 += __shfl_xor(s2, m); }
  float mu  = s1 * (1.f/512.f);
  float var = s2 * (1.f/512.f) - mu*mu;
  float istd = rsqrtf(var + 1e-5f);
  float gv[8], bev[8];
  load8(gamma + d0, gv); load8(beta + d0, bev);
  float o[8];
  #pragma unroll
  for (int j = 0; j < 8; j++) o[j] = (e[j] - mu)*istd*gv[j] + bev[j];
  store8(out + r*DD + d0, o);
}

extern "C" void kernel_launch(void* const* d_in, const int* in_sizes, int n_in,
                              void* d_out, int out_size, void* d_ws, size_t ws_size,
                              hipStream_t stream) {
  (void)in_sizes; (void)n_in; (void)out_size; (void)ws_size;
  const float* features = (const float*)d_in[0];
  const float* coords   = (const float*)d_in[1];
  const float* W_feat   = (const float*)d_in[2];
  const float* b_feat   = (const float*)d_in[3];
  const float* W_p1     = (const float*)d_in[4];
  const float* b_p1     = (const float*)d_in[5];
  const float* W_p2     = (const float*)d_in[6];
  const float* b_p2     = (const float*)d_in[7];
  const float* Wq = (const float*)d_in[8];  const float* bq = (const float*)d_in[9];
  const float* Wk = (const float*)d_in[10]; const float* bk = (const float*)d_in[11];
  const float* Wv = (const float*)d_in[12]; const float* bv = (const float*)d_in[13];
  const float* Wo = (const float*)d_in[14]; const float* bo = (const float*)d_in[15];
  const float* gamma = (const float*)d_in[16]; const float* beta = (const float*)d_in[17];
  float* out = (float*)d_out;

  char* ws = (char*)d_ws;
  size_t off = 0;
  auto alloc = [&](size_t bytes) -> void* {
    void* p = ws + off;
    off = (off + bytes + 255) & ~(size_t)255;
    return p;
  };
  u16*   featA     = (u16*)  alloc((size_t)NPTS*INDIM*2);   // 8.4 MB
  u16*   feat_bf   = (u16*)  alloc((size_t)NPTS*DD*2);      // 16.8 MB
  u16*   q_bf      = (u16*)  alloc((size_t)NPTS*DD*2);      // 16.8 MB
  u16*   agg_bf    = (u16*)  alloc((size_t)NPTS*DD*2);      // 16.8 MB
  u16*   lin_bf    = (u16*)  alloc((size_t)NPTS*DD*2);      // 16.8 MB
  u16*   WcatT     = (u16*)  alloc((size_t)1024*INDIM*2);   // rows 0..511 WfeatT, 512..1023 WfqT
  u16*   W_feat_bf = (u16*)  alloc((size_t)INDIM*DD*2);
  u16*   WqT       = (u16*)  alloc((size_t)DD*DD*2);
  u16*   WoT       = (u16*)  alloc((size_t)DD*DD*2);
  u16*   WkvT      = (u16*)  alloc((size_t)1024*DD*2);      // rows 0..511 WkT, 512..1023 WvT
  u16*   meanA     = (u16*)  alloc((size_t)MEANROWS*DD*2);  // rows 0..511 mean, 512..520 pe
  float* meanKV    = (float*)alloc((size_t)MEANROWS*1024*4);// [640][1024]: K+bk | V+bv
  float* bfq       = (float*)alloc((size_t)DD*4);
  float* biaskv    = (float*)alloc((size_t)1024*4);
  int*   order     = (int*)  alloc((size_t)NPTS*4);
  int*   counts    = (int*)  alloc((size_t)NBATCH*GG*4);
  int*   cellstart = (int*)  alloc((size_t)NBATCH*GG*4);
  u16*   WfqT      = WcatT + (size_t)512*INDIM;             // [512][256]

  // 1. bucketing metadata (independent, tiny)
  rank_kernel<<<NBATCH, 256, 0, stream>>>(coords, order, counts, cellstart);
  // 2. all independent preprocessing in one launch
  prep_kernel<<<P_NB, 256, 0, stream>>>(
      features, W_feat, Wq, Wk, Wv, Wo, W_p1, b_p1, W_p2, b_p2, b_feat, bq, bk, bv,
      featA, WcatT, W_feat_bf, WqT, WkvT, WoT, meanA, bfq, biaskv);
  // 3. WfqT = Wq^T @ W_feat^T  [512][256]
  gemm_bf16<<<dim3(INDIM/BN + 1, DD/BM), 256, 0, stream>>>(
      WqT, W_feat_bf, nullptr, 0, nullptr, WfqT, DD, INDIM, DD);
  // 4. fused [feat | q] = features @ [W_feat | Wfq]  (M=16384, N=1024, K=256)
  gemm_featq<<<dim3(1024/BN, NPTS/BM), 256, 0, stream>>>(
      featA, WcatT, b_feat, bfq, feat_bf, q_bf, INDIM);
  // 5. segment mean -> meanA rows 0..511
  mean_kernel<<<NBATCH*GG, 256, 0, stream>>>(feat_bf, order, counts, cellstart, meanA);
  // 6. meanKV = meanA @ [Wk | Wv] (+[bk|bv] on mean rows only)
  gemm_bf16<<<dim3(1024/BN, MEANROWS/BM), 256, 0, stream>>>(
      meanA, WkvT, biaskv, 512, meanKV, nullptr, MEANROWS, 1024, DD);
  // 7. cell-centric attention (4 blocks per cell) -> agg (bf16)
  attn_cells<<<NBATCH*GG*4, 256, 0, stream>>>(q_bf, meanKV, order, counts, cellstart, agg_bf);
  // 8. lin = agg @ Wo + bo (bf16)
  gemm_bf16<<<dim3(DD/BN, NPTS/BM), 256, 0, stream>>>(
      agg_bf, WoT, bo, NPTS, nullptr, lin_bf, NPTS, DD, DD);
  // 9. out = LN(feat + lin) * gamma + beta
  ln_kernel<<<NPTS/4, 256, 0, stream>>>(feat_bf, lin_bf, gamma, beta, out);
}

// Round 6
// 132.048 us; speedup vs baseline: 2.3218x; 1.1632x over previous
//
#include <hip/hip_runtime.h>
#include <stdint.h>

typedef unsigned short u16;
typedef unsigned int u32;
typedef __bf16 bf16x8 __attribute__((ext_vector_type(8)));
typedef float f32x4 __attribute__((ext_vector_type(4)));

#define NBATCH 8
#define NPT    2048
#define NPTS   16384     // NBATCH*NPT
#define INDIM  256
#define DD     512
#define GG     64        // 8x8 grid cells

__device__ __forceinline__ u16 f2bf(float f){
  u32 u = __builtin_bit_cast(u32, f);
  u += 0x7fffu + ((u >> 16) & 1u);
  return (u16)(u >> 16);
}
__device__ __forceinline__ float bf2f(u16 h){
  u32 u = ((u32)h) << 16;
  return __builtin_bit_cast(float, u);
}
__device__ __forceinline__ void load8(const float* __restrict__ p, float* r){
  float4 a = *(const float4*)p;
  float4 b = *(const float4*)(p + 4);
  r[0]=a.x;r[1]=a.y;r[2]=a.z;r[3]=a.w;r[4]=b.x;r[5]=b.y;r[6]=b.z;r[7]=b.w;
}
__device__ __forceinline__ void load8bf(const u16* __restrict__ p, float* r){
  uint4 v = *(const uint4*)p;
  r[0]=bf2f((u16)v.x); r[1]=bf2f((u16)(v.x>>16));
  r[2]=bf2f((u16)v.y); r[3]=bf2f((u16)(v.y>>16));
  r[4]=bf2f((u16)v.z); r[5]=bf2f((u16)(v.z>>16));
  r[6]=bf2f((u16)v.w); r[7]=bf2f((u16)(v.w>>16));
}
__device__ __forceinline__ void store8(float* __restrict__ p, const float* r){
  float4 a; a.x=r[0];a.y=r[1];a.z=r[2];a.w=r[3];
  float4 b; b.x=r[4];b.y=r[5];b.z=r[6];b.w=r[7];
  *(float4*)p = a; *(float4*)(p+4) = b;
}
__device__ __forceinline__ uint4 pack8(const float* a){
  uint4 pk;
  pk.x = (u32)f2bf(a[0]) | ((u32)f2bf(a[1]) << 16);
  pk.y = (u32)f2bf(a[2]) | ((u32)f2bf(a[3]) << 16);
  pk.z = (u32)f2bf(a[4]) | ((u32)f2bf(a[5]) << 16);
  pk.w = (u32)f2bf(a[6]) | ((u32)f2bf(a[7]) << 16);
  return pk;
}
typedef __attribute__((address_space(1))) unsigned as1u;
typedef __attribute__((address_space(3))) unsigned as3u;
__device__ __forceinline__ void gload16(const void* g, void* l){
  __builtin_amdgcn_global_load_lds((as1u*)(uintptr_t)g, (as3u*)(uintptr_t)l, 16, 0, 0);
}

// ---- 64x64 LDS-tiled transpose: src f32[*][scols] -> dst bf16[*][dcols], coalesced both ways ----
__device__ __forceinline__ void transpose64(const float* __restrict__ src, int scols,
                                            u16* __restrict__ dst, int dcols,
                                            int r0, int c0, char* smem, int t){
  float (*sh)[65] = (float(*)[65])smem;
  #pragma unroll
  for (int i = 0; i < 16; i++){
    int idx = i*256 + t;
    int r = idx >> 6, c = idx & 63;
    sh[r][c] = src[(size_t)(r0 + r)*scols + c0 + c];
  }
  __syncthreads();
  #pragma unroll
  for (int i = 0; i < 8; i++){
    int idx = i*512 + t*2;
    int oR = idx >> 6, oC = idx & 63;
    u32 pk = (u32)f2bf(sh[oC][oR]) | ((u32)f2bf(sh[oC+1][oR]) << 16);
    *(u32*)(dst + (size_t)(c0 + oR)*dcols + r0 + oC) = pk;
  }
}

// ================= Launch 1: mega-prep (all independent preprocessing + rank) =================
// [0,2048)     featA = bf16(features)
// [2048,2112)  W_feat_bf = bf16(W_feat)           [256][512]
// [2112,2368)  transpose Wq/Wk/Wv/Wo -> WqkvT rows {0,512,1024} / WoT
// [2368,2400)  transpose W_feat -> WcatT rows 0..511  ([512][256])
// [2400,2409)  pos-enc MLP -> peD [9][512] bf16
// [2409,2411)  bfq = b_feat@Wq + bq               [512] f32
// [2411,2415)  biaskv = b_feat@[Wk|Wv] + [bk|bv]  [1024] f32
// [2415,2423)  rank: cell-id + stable counting sort per batch
#define P_R1 2048
#define P_R2 2112
#define P_R3 2368
#define P_R4 2400
#define P_R5 2409
#define P_R6 2411
#define P_R7 2415
#define P_NB 2423
__global__ __launch_bounds__(256) void prep_kernel(
    const float* __restrict__ features, const float* __restrict__ W_feat,
    const float* __restrict__ Wq, const float* __restrict__ Wk,
    const float* __restrict__ Wv, const float* __restrict__ Wo,
    const float* __restrict__ W_p1, const float* __restrict__ b_p1,
    const float* __restrict__ W_p2, const float* __restrict__ b_p2,
    const float* __restrict__ b_feat, const float* __restrict__ bq,
    const float* __restrict__ bk, const float* __restrict__ bv,
    const float* __restrict__ coords,
    u16* __restrict__ featA, u16* __restrict__ W_feat_bf,
    u16* __restrict__ WqkvT, u16* __restrict__ WoT, u16* __restrict__ WcatT,
    u16* __restrict__ peD, float* __restrict__ bfq, float* __restrict__ biaskv,
    int* __restrict__ order, int* __restrict__ counts, int* __restrict__ cellstart)
{
  __shared__ __align__(16) char smem[34048];
  int bid = blockIdx.x, t = threadIdx.x;
  if (bid < P_R1){
    int i = bid*256 + t;
    float r[8]; load8(features + (size_t)i*8, r);
    *(uint4*)(featA + (size_t)i*8) = pack8(r);
  } else if (bid < P_R2){
    int i = (bid - P_R1)*256 + t;
    float r[8]; load8(W_feat + (size_t)i*8, r);
    *(uint4*)(W_feat_bf + (size_t)i*8) = pack8(r);
  } else if (bid < P_R3){
    int rel = bid - P_R2;
    int mat = rel >> 6, tile = rel & 63;
    int r0 = (tile >> 3)*64, c0 = (tile & 7)*64;
    const float* src = mat==0 ? Wq : (mat==1 ? Wk : (mat==2 ? Wv : Wo));
    u16* dst = mat==0 ? WqkvT : (mat==1 ? WqkvT + (size_t)512*DD
                     : (mat==2 ? WqkvT + (size_t)1024*DD : WoT));
    transpose64(src, DD, dst, DD, r0, c0, smem, t);
  } else if (bid < P_R4){
    int rel = bid - P_R3;                 // W_feat [256][512] -> WcatT rows 0..511 ([512][256])
    int r0 = (rel >> 3)*64, c0 = (rel & 7)*64;
    transpose64(W_feat, DD, WcatT, INDIM, r0, c0, smem, t);
  } else if (bid < P_R5){
    int kk = bid - P_R4;                  // 0..8
    float dx = (float)(kk/3 - 1), dy = (float)(kk%3 - 1);
    float* h = (float*)smem;
    float hv = dx*W_p1[t] + dy*W_p1[256 + t] + b_p1[t];
    h[t] = hv > 0.f ? hv : 0.f;
    __syncthreads();
    float acc0 = b_p2[t], acc1 = b_p2[t + 256];
    for (int c = 0; c < 256; c++){
      float hc = h[c];
      acc0 += hc * W_p2[(size_t)c*DD + t];
      acc1 += hc * W_p2[(size_t)c*DD + t + 256];
    }
    peD[(size_t)kk*DD + t]       = f2bf(acc0);
    peD[(size_t)kk*DD + t + 256] = f2bf(acc1);
  } else if (bid < P_R6){
    int i = (bid - P_R5)*256 + t;         // 0..511
    float* bfs = (float*)smem;
    bfs[t] = b_feat[t]; bfs[t + 256] = b_feat[t + 256];
    __syncthreads();
    float acc = 0.f;
    for (int k = 0; k < DD; k++) acc += bfs[k] * Wq[(size_t)k*DD + i];
    bfq[i] = acc + bq[i];
  } else if (bid < P_R7){
    int n = (bid - P_R6)*256 + t;         // 0..1023
    float* bfs = (float*)smem;
    bfs[t] = b_feat[t]; bfs[t + 256] = b_feat[t + 256];
    __syncthreads();
    const float* W = (n < 512) ? Wk : Wv;
    int c = n & 511;
    float acc = 0.f;
    for (int k = 0; k < DD; k++) acc += bfs[k] * W[(size_t)k*DD + c];
    biaskv[n] = acc + ((n < 512) ? bk[c] : bv[c]);
  } else {
    int b = bid - P_R7;                   // 0..7
    u16 (*hist)[65] = (u16(*)[65])smem;
    int* tot  = (int*)(smem + 33280);
    int* base = (int*)(smem + 33536);
    #pragma unroll
    for (int i = 0; i < 65; i++) hist[t][i] = 0;
    int myc[8];
    float cxy[16];
    load8(coords + (size_t)(b*NPT + t*8)*2,     cxy);
    load8(coords + (size_t)(b*NPT + t*8)*2 + 8, cxy + 8);
    #pragma unroll
    for (int i = 0; i < 8; i++){
      int gx = (int)(cxy[2*i]   * (1.0f/32.0f)); gx = gx < 0 ? 0 : (gx > 7 ? 7 : gx);
      int gy = (int)(cxy[2*i+1] * (1.0f/32.0f)); gy = gy < 0 ? 0 : (gy > 7 ? 7 : gy);
      myc[i] = gx*8 + gy;
      hist[t][myc[i]]++;
    }
    __syncthreads();
    if (t < GG){
      int acc = 0;
      for (int tt = 0; tt < 256; tt++){ int v = hist[tt][t]; hist[tt][t] = (u16)acc; acc += v; }
      tot[t] = acc;
    }
    __syncthreads();
    if (t == 0){
      int acc = 0;
      for (int g = 0; g < GG; g++){ base[g] = acc; acc += tot[g]; }
    }
    __syncthreads();
    if (t < GG){
      counts[b*GG + t] = tot[t];
      cellstart[b*GG + t] = base[t];
    }
    #pragma unroll
    for (int i = 0; i < 8; i++){
      int g = myc[i];
      int local = 0;
      #pragma unroll
      for (int j = 0; j < 8; j++) local += (j < i && myc[j] == g) ? 1 : 0;
      order[b*NPT + base[g] + (int)hist[t][g] + local] = t*8 + i;
    }
  }
}

// ======== shared GEMM main loop (128x128 tile, 4 waves, global_load_lds, 1D grid + XCD swizzle) ========
// NWG must be a multiple of 8.
#define BM 128
#define BN 128
#define GEMM_MAIN1D(Aptr, Btptr, Kv, GXv, NWGv)                                    \
  __shared__ __align__(16) u16 lA[BM*32];                                          \
  __shared__ __align__(16) u16 lB[BN*32];                                          \
  int tid = threadIdx.x;                                                           \
  int orig_ = blockIdx.x;                                                          \
  int swz_ = (orig_ & 7)*((NWGv) >> 3) + (orig_ >> 3);                             \
  int m0 = (swz_ / (GXv)) * BM, n0 = (swz_ % (GXv)) * BN;                          \
  int lane = tid & 63;                                                             \
  int wv = tid >> 6;                                                               \
  int wm = (wv >> 1) * 64, wn = (wv & 1) * 64;                                     \
  int lr = lane & 15;                                                              \
  int kg = (lane >> 4) << 3;                                                       \
  f32x4 acc[4][4] = {};                                                            \
  int srow = lane >> 2;                                                            \
  int scol = (lane & 3) << 3;                                                      \
  const u16* gA0 = (Aptr)  + (size_t)(m0 + wv*32 + srow)*(Kv) + scol;              \
  const u16* gB0 = (Btptr) + (size_t)(n0 + wv*32 + srow)*(Kv) + scol;              \
  u16* lA0 = lA + (wv*32)*32;                                                      \
  u16* lB0 = lB + (wv*32)*32;                                                      \
  for (int kt = 0; kt < (Kv); kt += 32){                                           \
    gload16(gA0 + kt,                   lA0);                                      \
    gload16(gA0 + kt + (size_t)16*(Kv), lA0 + 16*32);                              \
    gload16(gB0 + kt,                   lB0);                                      \
    gload16(gB0 + kt + (size_t)16*(Kv), lB0 + 16*32);                              \
    __syncthreads();                                                               \
    bf16x8 af[4], bfv[4];                                                          \
    _Pragma("unroll")                                                              \
    for (int i = 0; i < 4; i++) af[i]  = *(const bf16x8*)&lA[(wm + i*16 + lr)*32 + kg]; \
    _Pragma("unroll")                                                              \
    for (int j = 0; j < 4; j++) bfv[j] = *(const bf16x8*)&lB[(wn + j*16 + lr)*32 + kg]; \
    _Pragma("unroll")                                                              \
    for (int i = 0; i < 4; i++)                                                    \
      _Pragma("unroll")                                                            \
      for (int j = 0; j < 4; j++)                                                  \
        acc[i][j] = __builtin_amdgcn_mfma_f32_16x16x32_bf16(af[i], bfv[j], acc[i][j], 0, 0, 0); \
    __syncthreads();                                                               \
  }                                                                                \
  int lrow = (lane >> 4) << 2;

// ---------------- generic GEMM (1D grid): C[M][N] = A[M][K]*Bt[N][K]^T (+bias) ----------------
__global__ __launch_bounds__(256) void gemm_bf16(
    const u16* __restrict__ A, const u16* __restrict__ Bt,
    const float* __restrict__ bias,
    float* __restrict__ C, u16* __restrict__ Cbf,
    int N, int K, int GX, int NWG)
{
  GEMM_MAIN1D(A, Bt, K, GX, NWG)
  #pragma unroll
  for (int j = 0; j < 4; j++){
    int col = n0 + wn + j*16 + lr;
    float bcol = bias ? bias[col] : 0.f;
    #pragma unroll
    for (int i = 0; i < 4; i++){
      int row0 = m0 + wm + i*16 + lrow;
      #pragma unroll
      for (int r = 0; r < 4; r++){
        float v = acc[i][j][r] + bcol;
        if (C)   C[(size_t)(row0 + r)*N + col] = v;
        if (Cbf) Cbf[(size_t)(row0 + r)*N + col] = f2bf(v);
      }
    }
  }
}

// ========== Launch 2: stacked small GEMM ([Wq;Wk;Wv]^T @ W_feat^T) + peKV vector blocks ==========
// blocks [0,24): gemm M=1536,N=256,K=512 -> Xout=[WfqT(512);WfkvT(1024)][256] bf16
// blocks [24,60): peKV: meanKV rows 512+kk = peD[kk] @ [Wk|Wv]
__global__ __launch_bounds__(256) void smallgemm_kernel(
    const u16* __restrict__ WqkvT, const u16* __restrict__ W_feat_bf,
    const u16* __restrict__ peD, u16* __restrict__ Xout, float* __restrict__ meanKV)
{
  if (blockIdx.x < 24){
    GEMM_MAIN1D(WqkvT, W_feat_bf, 512, 2, 24)
    #pragma unroll
    for (int j = 0; j < 4; j++){
      int col = n0 + wn + j*16 + lr;
      #pragma unroll
      for (int i = 0; i < 4; i++){
        int row0 = m0 + wm + i*16 + lrow;
        #pragma unroll
        for (int r = 0; r < 4; r++)
          Xout[(size_t)(row0 + r)*INDIM + col] = f2bf(acc[i][j][r]);
      }
    }
  } else {
    __shared__ float pesh[512];
    int bid2 = blockIdx.x - 24;
    int kk = bid2 >> 2, seg = bid2 & 3;
    int t = threadIdx.x;
    int n = seg*256 + t;
    pesh[t]       = bf2f(peD[(size_t)kk*DD + t]);
    pesh[t + 256] = bf2f(peD[(size_t)kk*DD + t + 256]);
    __syncthreads();
    const u16* wrow = WqkvT + (size_t)(512 + n)*DD;
    float acc = 0.f;
    for (int d8 = 0; d8 < 64; d8++){
      float w8[8]; load8bf(wrow + d8*8, w8);
      #pragma unroll
      for (int j = 0; j < 8; j++) acc += pesh[d8*8 + j]*w8[j];
    }
    meanKV[(size_t)(512 + kk)*1024 + n] = acc;
  }
}

// ========== Launch 3: fused [feat|q] GEMM + raw-feature segment-mean gather ==========
// blocks [0,1024): gemm M=16384,N=1024,K=256; cols<512 -> feat_bf+b_feat, cols>=512 -> q_bf+bfq
// blocks [1024,1536): meanF[bg][256] = mean of featA rows in cell bg (bf16, deterministic order)
__global__ __launch_bounds__(256) void featq_mean_kernel(
    const u16* __restrict__ featA, const u16* __restrict__ WcatT,
    const float* __restrict__ bias0, const float* __restrict__ bias1,
    u16* __restrict__ feat_bf, u16* __restrict__ q_bf,
    const int* __restrict__ order, const int* __restrict__ counts,
    const int* __restrict__ cellstart, u16* __restrict__ meanF)
{
  if (blockIdx.x < 1024){
    GEMM_MAIN1D(featA, WcatT, 256, 8, 1024)
    int half = n0 >> 9;
    u16* outp = half ? q_bf : feat_bf;
    const float* bias = half ? bias1 : bias0;
    int nb = n0 & 511;
    #pragma unroll
    for (int j = 0; j < 4; j++){
      int col = nb + wn + j*16 + lr;
      float bcol = bias[col];
      #pragma unroll
      for (int i = 0; i < 4; i++){
        int row0 = m0 + wm + i*16 + lrow;
        #pragma unroll
        for (int r = 0; r < 4; r++)
          outp[(size_t)(row0 + r)*DD + col] = f2bf(acc[i][j][r] + bcol);
      }
    }
  } else {
    __shared__ float part[128][2];
    int bg = blockIdx.x - 1024;           // 0..511
    int b = bg >> 6;
    int t = threadIdx.x;
    int p = t & 127, half = t >> 7;
    int cnt = counts[bg], start = cellstart[bg];
    const int* ord = order + b*NPT + start;
    float a0 = 0.f, a1 = 0.f;
    for (int n = half; n < cnt; n += 2){
      u32 v = *(const u32*)(featA + (((size_t)(b*NPT + ord[n])) << 8) + p*2);
      a0 += bf2f((u16)v); a1 += bf2f((u16)(v >> 16));
    }
    if (half){ part[p][0] = a0; part[p][1] = a1; }
    __syncthreads();
    if (!half){
      a0 += part[p][0]; a1 += part[p][1];
      float inv = 1.f / (float)(cnt > 0 ? cnt : 1);
      *(u32*)(meanF + (size_t)bg*INDIM + p*2) =
          (u32)f2bf(a0*inv) | ((u32)f2bf(a1*inv) << 16);
    }
  }
}

// ---------------- cell-centric attention: 4 blocks per (b,cell) ----------------
// meanKV: [640][1024] f32; cols 0..511 K (+bias), 512..1023 V (+bias); rows 512+kk = pe.
__global__ __launch_bounds__(256) void attn_cells(
    const u16* __restrict__ q, const float* __restrict__ meanKV,
    const int* __restrict__ order, const int* __restrict__ counts,
    const int* __restrict__ cellstart, u16* __restrict__ agg)
{
  int bg4 = blockIdx.x;           // 0..2047
  int bg = bg4 >> 2, part = bg4 & 3;
  int b = bg >> 6, c = bg & 63;
  int gx = c >> 3, gy = c & 7;
  __shared__ __align__(16) u16 Kf[9][DD];
  __shared__ __align__(16) u16 Vf[9][DD];
  __shared__ int vrow[9];
  int t = threadIdx.x;
  if (t < 9){
    int dx = t/3 - 1, dy = t%3 - 1;
    int nx = gx + dx, ny = gy + dy;
    int inb = ((unsigned)nx < 8u) && ((unsigned)ny < 8u);
    int row = b*GG + (((nx&7) << 3) | (ny&7));
    vrow[t] = (inb && counts[row] > 0) ? row : -1;
  }
  __syncthreads();
  int d = 2*t;
  #pragma unroll
  for (int kk = 0; kk < 9; kk++){
    int row = vrow[kk];
    if (row >= 0){
      float2 mk = *(const float2*)&meanKV[(size_t)row*1024 + d];
      float2 pk = *(const float2*)&meanKV[(size_t)(512+kk)*1024 + d];
      float2 mv = *(const float2*)&meanKV[(size_t)row*1024 + 512 + d];
      float2 pv = *(const float2*)&meanKV[(size_t)(512+kk)*1024 + 512 + d];
      *(u32*)&Kf[kk][d] = (u32)f2bf(mk.x+pk.x) | ((u32)f2bf(mk.y+pk.y) << 16);
      *(u32*)&Vf[kk][d] = (u32)f2bf(mv.x+pv.x) | ((u32)f2bf(mv.y+pv.y) << 16);
    }
  }
  __syncthreads();
  int cnt = counts[bg];
  int wv = t >> 6, lane = t & 63;
  int widx = part*4 + wv;               // 0..15
  const int* ord = order + b*NPT + cellstart[bg];
  for (int i = widx; i < cnt; i += 16){
    size_t p = (size_t)b*NPT + ord[i];
    float qv[8];
    load8bf(q + p*DD + lane*8, qv);
    float s[9];
    #pragma unroll
    for (int kk = 0; kk < 9; kk++){
      float partial = 0.f;
      if (vrow[kk] >= 0){
        float kv[8]; load8bf(&Kf[kk][lane*8], kv);
        #pragma unroll
        for (int j = 0; j < 8; j++) partial += qv[j]*kv[j];
      }
      partial += __shfl_xor(partial, 1);
      partial += __shfl_xor(partial, 2);
      partial += __shfl_xor(partial, 4);
      partial += __shfl_xor(partial, 8);
      s[kk] = (vrow[kk] >= 0) ? partial * 0.08838834764831843f : -1e30f;
    }
    float mx = s[0];
    #pragma unroll
    for (int kk = 1; kk < 9; kk++) mx = fmaxf(mx, s[kk]);
    float w[9], sum = 0.f;
    #pragma unroll
    for (int kk = 0; kk < 9; kk++){
      w[kk] = (vrow[kk] >= 0) ? __expf(s[kk] - mx) : 0.f;
      sum += w[kk];
    }
    float inv = 1.f / sum;
    float a[8] = {0,0,0,0,0,0,0,0};
    #pragma unroll
    for (int kk = 0; kk < 9; kk++){
      if (vrow[kk] >= 0){
        float wk = w[kk] * inv;
        float vv[8]; load8bf(&Vf[kk][lane*8], vv);
        #pragma unroll
        for (int j = 0; j < 8; j++) a[j] += wk*vv[j];
      }
    }
    *(uint4*)&agg[p*DD + lane*8] = pack8(a);
  }
}

// ---------------- residual + layernorm (bf16 inputs): one wave per row ----------------
__global__ __launch_bounds__(256) void ln_kernel(
    const u16* __restrict__ feat, const u16* __restrict__ lin,
    const float* __restrict__ gamma, const float* __restrict__ beta,
    float* __restrict__ out)
{
  int wv = threadIdx.x >> 6, lane = threadIdx.x & 63;
  size_t r = (size_t)blockIdx.x * 4 + wv;
  int d0 = lane * 8;
  float fv[8], lv[8];
  load8bf(feat + r*DD + d0, fv);
  load8bf(lin  + r*DD + d0, lv);
  float e[8], s1 = 0.f, s2 = 0.f;
  #pragma unroll
  for (int j = 0; j < 8; j++){ e[j] = fv[j] + lv[j]; s1 += e[j]; s2 += e[j]*e[j]; }
  #pragma unroll
  for (int m = 1; m < 64; m <<= 1){ s1 += __shfl_xor(s1, m); s2 += __shfl_xor(s2, m); }
  float mu  = s1 * (1.f/512.f);
  float var = s2 * (1.f/512.f) - mu*mu;
  float istd = rsqrtf(var + 1e-5f);
  float gv[8], bev[8];
  load8(gamma + d0, gv); load8(beta + d0, bev);
  float o[8];
  #pragma unroll
  for (int j = 0; j < 8; j++) o[j] = (e[j] - mu)*istd*gv[j] + bev[j];
  store8(out + r*DD + d0, o);
}

extern "C" void kernel_launch(void* const* d_in, const int* in_sizes, int n_in,
                              void* d_out, int out_size, void* d_ws, size_t ws_size,
                              hipStream_t stream) {
  (void)in_sizes; (void)n_in; (void)out_size; (void)ws_size;
  const float* features = (const float*)d_in[0];
  const float* coords   = (const float*)d_in[1];
  const float* W_feat   = (const float*)d_in[2];
  const float* b_feat   = (const float*)d_in[3];
  const float* W_p1     = (const float*)d_in[4];
  const float* b_p1     = (const float*)d_in[5];
  const float* W_p2     = (const float*)d_in[6];
  const float* b_p2     = (const float*)d_in[7];
  const float* Wq = (const float*)d_in[8];  const float* bq = (const float*)d_in[9];
  const float* Wk = (const float*)d_in[10]; const float* bk = (const float*)d_in[11];
  const float* Wv = (const float*)d_in[12]; const float* bv = (const float*)d_in[13];
  const float* Wo = (const float*)d_in[14]; const float* bo = (const float*)d_in[15];
  const float* gamma = (const float*)d_in[16]; const float* beta = (const float*)d_in[17];
  float* out = (float*)d_out;

  char* ws = (char*)d_ws;
  size_t off = 0;
  auto alloc = [&](size_t bytes) -> void* {
    void* p = ws + off;
    off = (off + bytes + 255) & ~(size_t)255;
    return p;
  };
  u16*   featA     = (u16*)  alloc((size_t)NPTS*INDIM*2);   // 8.4 MB
  u16*   feat_bf   = (u16*)  alloc((size_t)NPTS*DD*2);      // 16.8 MB
  u16*   q_bf      = (u16*)  alloc((size_t)NPTS*DD*2);      // 16.8 MB
  u16*   agg_bf    = (u16*)  alloc((size_t)NPTS*DD*2);      // 16.8 MB
  u16*   lin_bf    = (u16*)  alloc((size_t)NPTS*DD*2);      // 16.8 MB
  u16*   W_feat_bf = (u16*)  alloc((size_t)INDIM*DD*2);     // [256][512]
  u16*   WqkvT     = (u16*)  alloc((size_t)1536*DD*2);      // [Wq^T;Wk^T;Wv^T]
  u16*   WoT       = (u16*)  alloc((size_t)DD*DD*2);
  // WcatT [1024][256] and WfkvT [1024][256] must be CONTIGUOUS (smallgemm writes across them)
  u16*   WcatT     = (u16*)  alloc((size_t)1024*INDIM*2);   // rows 0..511 W_feat^T, 512..1023 WfqT
  u16*   WfkvT     = (u16*)  alloc((size_t)1024*INDIM*2);   // (W_feat@[Wk|Wv])^T
  u16*   peD       = (u16*)  alloc((size_t)9*DD*2);
  u16*   meanF     = (u16*)  alloc((size_t)512*INDIM*2);
  float* meanKV    = (float*)alloc((size_t)640*1024*4);     // rows 0..511 mean-derived, 512..520 pe
  float* bfq       = (float*)alloc((size_t)DD*4);
  float* biaskv    = (float*)alloc((size_t)1024*4);
  int*   order     = (int*)  alloc((size_t)NPTS*4);
  int*   counts    = (int*)  alloc((size_t)NBATCH*GG*4);
  int*   cellstart = (int*)  alloc((size_t)NBATCH*GG*4);
  u16*   Xout      = WcatT + (size_t)512*INDIM;             // [1536][256]: WfqT then WfkvT

  // 1. mega-prep (+rank)
  prep_kernel<<<P_NB, 256, 0, stream>>>(
      features, W_feat, Wq, Wk, Wv, Wo, W_p1, b_p1, W_p2, b_p2,
      b_feat, bq, bk, bv, coords,
      featA, W_feat_bf, WqkvT, WoT, WcatT, peD, bfq, biaskv,
      order, counts, cellstart);
  // 2. [WfqT; WfkvT] = [Wq;Wk;Wv]^T @ W_feat^T  +  peKV rows of meanKV
  smallgemm_kernel<<<60, 256, 0, stream>>>(WqkvT, W_feat_bf, peD, Xout, meanKV);
  // 3. [feat | q] = features @ [W_feat | Wfq]  +  meanF gather
  featq_mean_kernel<<<1536, 256, 0, stream>>>(
      featA, WcatT, b_feat, bfq, feat_bf, q_bf, order, counts, cellstart, meanF);
  // 4. meanKV rows 0..511 = meanF @ WfkvT^T + biaskv
  gemm_bf16<<<32, 256, 0, stream>>>(meanF, WfkvT, biaskv, meanKV, nullptr, 1024, INDIM, 8, 32);
  // 5. cell-centric attention -> agg
  attn_cells<<<NBATCH*GG*4, 256, 0, stream>>>(q_bf, meanKV, order, counts, cellstart, agg_bf);
  // 6. lin = agg @ Wo + bo
  gemm_bf16<<<512, 256, 0, stream>>>(agg_bf, WoT, bo, nullptr, lin_bf, DD, DD, 4, 512);
  // 7. out = LN(feat + lin) * gamma + beta
  ln_kernel<<<NPTS/4, 256, 0, stream>>>(feat_bf, lin_bf, gamma, beta, out);
}

// Round 8
// 117.539 us; speedup vs baseline: 2.6084x; 1.1234x over previous
//
#include <hip/hip_runtime.h>
#include <stdint.h>

typedef unsigned short u16;
typedef unsigned int u32;
typedef __bf16 bf16x8 __attribute__((ext_vector_type(8)));
typedef float f32x4 __attribute__((ext_vector_type(4)));

#define NBATCH 8
#define NPT    2048
#define NPTS   16384     // NBATCH*NPT
#define INDIM  256
#define DD     512
#define GG     64        // 8x8 grid cells

__device__ __forceinline__ u16 f2bf(float f){
  u32 u = __builtin_bit_cast(u32, f);
  u += 0x7fffu + ((u >> 16) & 1u);
  return (u16)(u >> 16);
}
__device__ __forceinline__ float bf2f(u16 h){
  u32 u = ((u32)h) << 16;
  return __builtin_bit_cast(float, u);
}
__device__ __forceinline__ void load8(const float* __restrict__ p, float* r){
  float4 a = *(const float4*)p;
  float4 b = *(const float4*)(p + 4);
  r[0]=a.x;r[1]=a.y;r[2]=a.z;r[3]=a.w;r[4]=b.x;r[5]=b.y;r[6]=b.z;r[7]=b.w;
}
__device__ __forceinline__ void load8bf(const u16* __restrict__ p, float* r){
  uint4 v = *(const uint4*)p;
  r[0]=bf2f((u16)v.x); r[1]=bf2f((u16)(v.x>>16));
  r[2]=bf2f((u16)v.y); r[3]=bf2f((u16)(v.y>>16));
  r[4]=bf2f((u16)v.z); r[5]=bf2f((u16)(v.z>>16));
  r[6]=bf2f((u16)v.w); r[7]=bf2f((u16)(v.w>>16));
}
__device__ __forceinline__ void store8(float* __restrict__ p, const float* r){
  float4 a; a.x=r[0];a.y=r[1];a.z=r[2];a.w=r[3];
  float4 b; b.x=r[4];b.y=r[5];b.z=r[6];b.w=r[7];
  *(float4*)p = a; *(float4*)(p+4) = b;
}
__device__ __forceinline__ uint4 pack8(const float* a){
  uint4 pk;
  pk.x = (u32)f2bf(a[0]) | ((u32)f2bf(a[1]) << 16);
  pk.y = (u32)f2bf(a[2]) | ((u32)f2bf(a[3]) << 16);
  pk.z = (u32)f2bf(a[4]) | ((u32)f2bf(a[5]) << 16);
  pk.w = (u32)f2bf(a[6]) | ((u32)f2bf(a[7]) << 16);
  return pk;
}
typedef __attribute__((address_space(1))) unsigned as1u;
typedef __attribute__((address_space(3))) unsigned as3u;
__device__ __forceinline__ void gload16(const void* g, void* l){
  __builtin_amdgcn_global_load_lds((as1u*)(uintptr_t)g, (as3u*)(uintptr_t)l, 16, 0, 0);
}

// ---- 64x64 LDS-tiled transpose: src f32[*][scols] -> dst bf16[*][dcols] ----
__device__ __forceinline__ void transpose64(const float* __restrict__ src, int scols,
                                            u16* __restrict__ dst, int dcols,
                                            int r0, int c0, char* smem, int t){
  float (*sh)[65] = (float(*)[65])smem;
  #pragma unroll
  for (int i = 0; i < 16; i++){
    int idx = i*256 + t;
    int r = idx >> 6, c = idx & 63;
    sh[r][c] = src[(size_t)(r0 + r)*scols + c0 + c];
  }
  __syncthreads();
  #pragma unroll
  for (int i = 0; i < 8; i++){
    int idx = i*512 + t*2;
    int oR = idx >> 6, oC = idx & 63;
    u32 pk = (u32)f2bf(sh[oC][oR]) | ((u32)f2bf(sh[oC+1][oR]) << 16);
    *(u32*)(dst + (size_t)(c0 + oR)*dcols + r0 + oC) = pk;
  }
}

// ================= Launch 1: mega-prep (all independent preprocessing + rank) =================
#define P_R1 2048
#define P_R2 2112
#define P_R3 2368
#define P_R4 2400
#define P_R5 2409
#define P_R6 2411
#define P_R7 2415
#define P_NB 2423
__global__ __launch_bounds__(256) void prep_kernel(
    const float* __restrict__ features, const float* __restrict__ W_feat,
    const float* __restrict__ Wq, const float* __restrict__ Wk,
    const float* __restrict__ Wv, const float* __restrict__ Wo,
    const float* __restrict__ W_p1, const float* __restrict__ b_p1,
    const float* __restrict__ W_p2, const float* __restrict__ b_p2,
    const float* __restrict__ b_feat, const float* __restrict__ bq,
    const float* __restrict__ bk, const float* __restrict__ bv,
    const float* __restrict__ coords,
    u16* __restrict__ featA, u16* __restrict__ W_feat_bf,
    u16* __restrict__ WqkvT, u16* __restrict__ WoT, u16* __restrict__ WcatT,
    u16* __restrict__ peD, float* __restrict__ bfq, float* __restrict__ biaskv,
    int* __restrict__ order, int* __restrict__ counts, int* __restrict__ cellstart)
{
  __shared__ __align__(16) char smem[34048];
  int bid = blockIdx.x, t = threadIdx.x;
  if (bid < P_R1){
    int i = bid*256 + t;
    float r[8]; load8(features + (size_t)i*8, r);
    *(uint4*)(featA + (size_t)i*8) = pack8(r);
  } else if (bid < P_R2){
    int i = (bid - P_R1)*256 + t;
    float r[8]; load8(W_feat + (size_t)i*8, r);
    *(uint4*)(W_feat_bf + (size_t)i*8) = pack8(r);
  } else if (bid < P_R3){
    int rel = bid - P_R2;
    int mat = rel >> 6, tile = rel & 63;
    int r0 = (tile >> 3)*64, c0 = (tile & 7)*64;
    const float* src = mat==0 ? Wq : (mat==1 ? Wk : (mat==2 ? Wv : Wo));
    u16* dst = mat==0 ? WqkvT : (mat==1 ? WqkvT + (size_t)512*DD
                     : (mat==2 ? WqkvT + (size_t)1024*DD : WoT));
    transpose64(src, DD, dst, DD, r0, c0, smem, t);
  } else if (bid < P_R4){
    int rel = bid - P_R3;                 // W_feat [256][512] -> WcatT rows 0..511
    int r0 = (rel >> 3)*64, c0 = (rel & 7)*64;
    transpose64(W_feat, DD, WcatT, INDIM, r0, c0, smem, t);
  } else if (bid < P_R5){
    int kk = bid - P_R4;                  // pos-enc MLP -> peD
    float dx = (float)(kk/3 - 1), dy = (float)(kk%3 - 1);
    float* h = (float*)smem;
    float hv = dx*W_p1[t] + dy*W_p1[256 + t] + b_p1[t];
    h[t] = hv > 0.f ? hv : 0.f;
    __syncthreads();
    float acc0 = b_p2[t], acc1 = b_p2[t + 256];
    for (int c = 0; c < 256; c++){
      float hc = h[c];
      acc0 += hc * W_p2[(size_t)c*DD + t];
      acc1 += hc * W_p2[(size_t)c*DD + t + 256];
    }
    peD[(size_t)kk*DD + t]       = f2bf(acc0);
    peD[(size_t)kk*DD + t + 256] = f2bf(acc1);
  } else if (bid < P_R6){
    int i = (bid - P_R5)*256 + t;         // bfq = b_feat@Wq + bq
    float* bfs = (float*)smem;
    bfs[t] = b_feat[t]; bfs[t + 256] = b_feat[t + 256];
    __syncthreads();
    float acc = 0.f;
    for (int k = 0; k < DD; k++) acc += bfs[k] * Wq[(size_t)k*DD + i];
    bfq[i] = acc + bq[i];
  } else if (bid < P_R7){
    int n = (bid - P_R6)*256 + t;         // biaskv = b_feat@[Wk|Wv] + [bk|bv]
    float* bfs = (float*)smem;
    bfs[t] = b_feat[t]; bfs[t + 256] = b_feat[t + 256];
    __syncthreads();
    const float* W = (n < 512) ? Wk : Wv;
    int c = n & 511;
    float acc = 0.f;
    for (int k = 0; k < DD; k++) acc += bfs[k] * W[(size_t)k*DD + c];
    biaskv[n] = acc + ((n < 512) ? bk[c] : bv[c]);
  } else {
    int b = bid - P_R7;                   // rank: cell-id + stable counting sort
    u16 (*hist)[65] = (u16(*)[65])smem;
    int* tot  = (int*)(smem + 33280);
    int* base = (int*)(smem + 33536);
    #pragma unroll
    for (int i = 0; i < 65; i++) hist[t][i] = 0;
    int myc[8];
    float cxy[16];
    load8(coords + (size_t)(b*NPT + t*8)*2,     cxy);
    load8(coords + (size_t)(b*NPT + t*8)*2 + 8, cxy + 8);
    #pragma unroll
    for (int i = 0; i < 8; i++){
      int gx = (int)(cxy[2*i]   * (1.0f/32.0f)); gx = gx < 0 ? 0 : (gx > 7 ? 7 : gx);
      int gy = (int)(cxy[2*i+1] * (1.0f/32.0f)); gy = gy < 0 ? 0 : (gy > 7 ? 7 : gy);
      myc[i] = gx*8 + gy;
      hist[t][myc[i]]++;
    }
    __syncthreads();
    if (t < GG){
      int acc = 0;
      for (int tt = 0; tt < 256; tt++){ int v = hist[tt][t]; hist[tt][t] = (u16)acc; acc += v; }
      tot[t] = acc;
    }
    __syncthreads();
    if (t == 0){
      int acc = 0;
      for (int g = 0; g < GG; g++){ base[g] = acc; acc += tot[g]; }
    }
    __syncthreads();
    if (t < GG){
      counts[b*GG + t] = tot[t];
      cellstart[b*GG + t] = base[t];
    }
    #pragma unroll
    for (int i = 0; i < 8; i++){
      int g = myc[i];
      int local = 0;
      #pragma unroll
      for (int j = 0; j < 8; j++) local += (j < i && myc[j] == g) ? 1 : 0;
      order[b*NPT + base[g] + (int)hist[t][g] + local] = t*8 + i;
    }
  }
}

// ======== shared GEMM main loop (128x128 tile, 4 waves, global_load_lds, 1D idx + XCD swizzle) ========
// NWGv must be a multiple of 8.
#define BM 128
#define BN 128
#define GEMM_MAIN1D(Aptr, Btptr, Kv, GXv, NWGv, UIDX)                              \
  __shared__ __align__(16) u16 lA[BM*32];                                          \
  __shared__ __align__(16) u16 lB[BN*32];                                          \
  int tid = threadIdx.x;                                                           \
  int orig_ = (UIDX);                                                              \
  int swz_ = (orig_ & 7)*((NWGv) >> 3) + (orig_ >> 3);                             \
  int m0 = (swz_ / (GXv)) * BM, n0 = (swz_ % (GXv)) * BN;                          \
  int lane = tid & 63;                                                             \
  int wv = tid >> 6;                                                               \
  int wm = (wv >> 1) * 64, wn = (wv & 1) * 64;                                     \
  int lr = lane & 15;                                                              \
  int kg = (lane >> 4) << 3;                                                       \
  f32x4 acc[4][4] = {};                                                            \
  int srow = lane >> 2;                                                            \
  int scol = (lane & 3) << 3;                                                      \
  const u16* gA0 = (Aptr)  + (size_t)(m0 + wv*32 + srow)*(Kv) + scol;              \
  const u16* gB0 = (Btptr) + (size_t)(n0 + wv*32 + srow)*(Kv) + scol;              \
  u16* lA0 = lA + (wv*32)*32;                                                      \
  u16* lB0 = lB + (wv*32)*32;                                                      \
  for (int kt = 0; kt < (Kv); kt += 32){                                           \
    gload16(gA0 + kt,                   lA0);                                      \
    gload16(gA0 + kt + (size_t)16*(Kv), lA0 + 16*32);                              \
    gload16(gB0 + kt,                   lB0);                                      \
    gload16(gB0 + kt + (size_t)16*(Kv), lB0 + 16*32);                              \
    __syncthreads();                                                               \
    bf16x8 af[4], bfv[4];                                                          \
    _Pragma("unroll")                                                              \
    for (int i = 0; i < 4; i++) af[i]  = *(const bf16x8*)&lA[(wm + i*16 + lr)*32 + kg]; \
    _Pragma("unroll")                                                              \
    for (int j = 0; j < 4; j++) bfv[j] = *(const bf16x8*)&lB[(wn + j*16 + lr)*32 + kg]; \
    _Pragma("unroll")                                                              \
    for (int i = 0; i < 4; i++)                                                    \
      _Pragma("unroll")                                                            \
      for (int j = 0; j < 4; j++)                                                  \
        acc[i][j] = __builtin_amdgcn_mfma_f32_16x16x32_bf16(af[i], bfv[j], acc[i][j], 0, 0, 0); \
    __syncthreads();                                                               \
  }                                                                                \
  int lrow = (lane >> 4) << 2;

// ========== Launch 2: smallgemm (24) + peKV (36) + meanF gather (512) = 572 blocks ==========
__global__ __launch_bounds__(256) void mid_kernel(
    const u16* __restrict__ WqkvT, const u16* __restrict__ W_feat_bf,
    const u16* __restrict__ peD, u16* __restrict__ Xout, float* __restrict__ meanKV,
    const u16* __restrict__ featA, const int* __restrict__ order,
    const int* __restrict__ counts, const int* __restrict__ cellstart,
    u16* __restrict__ meanF)
{
  if (blockIdx.x < 24){
    // Xout[1536][256] = [Wq;Wk;Wv]^T @ W_feat^T  (bf16)
    GEMM_MAIN1D(WqkvT, W_feat_bf, 512, 2, 24, (int)blockIdx.x)
    #pragma unroll
    for (int j = 0; j < 4; j++){
      int col = n0 + wn + j*16 + lr;
      #pragma unroll
      for (int i = 0; i < 4; i++){
        int row0 = m0 + wm + i*16 + lrow;
        #pragma unroll
        for (int r = 0; r < 4; r++)
          Xout[(size_t)(row0 + r)*INDIM + col] = f2bf(acc[i][j][r]);
      }
    }
  } else if (blockIdx.x < 60){
    __shared__ float pesh[512];
    int bid2 = blockIdx.x - 24;
    int kk = bid2 >> 2, seg = bid2 & 3;
    int t = threadIdx.x;
    int n = seg*256 + t;
    pesh[t]       = bf2f(peD[(size_t)kk*DD + t]);
    pesh[t + 256] = bf2f(peD[(size_t)kk*DD + t + 256]);
    __syncthreads();
    const u16* wrow = WqkvT + (size_t)(512 + n)*DD;
    float acc = 0.f;
    for (int d8 = 0; d8 < 64; d8++){
      float w8[8]; load8bf(wrow + d8*8, w8);
      #pragma unroll
      for (int j = 0; j < 8; j++) acc += pesh[d8*8 + j]*w8[j];
    }
    meanKV[(size_t)(512 + kk)*1024 + n] = acc;
  } else {
    __shared__ float part[128][2];
    int bg = blockIdx.x - 60;             // 0..511
    int b = bg >> 6;
    int t = threadIdx.x;
    int p = t & 127, half = t >> 7;
    int cnt = counts[bg], start = cellstart[bg];
    const int* ord = order + b*NPT + start;
    float a0 = 0.f, a1 = 0.f;
    for (int n = half; n < cnt; n += 2){
      u32 v = *(const u32*)(featA + (((size_t)(b*NPT + ord[n])) << 8) + p*2);
      a0 += bf2f((u16)v); a1 += bf2f((u16)(v >> 16));
    }
    if (half){ part[p][0] = a0; part[p][1] = a1; }
    __syncthreads();
    if (!half){
      a0 += part[p][0]; a1 += part[p][1];
      float inv = 1.f / (float)(cnt > 0 ? cnt : 1);
      *(u32*)(meanF + (size_t)bg*INDIM + p*2) =
          (u32)f2bf(a0*inv) | ((u32)f2bf(a1*inv) << 16);
    }
  }
}

// ========== Launch 3: featq GEMM (1024) + meanKV GEMM (32) = 1056 blocks (same K=256/GX=8 core) ==========
__global__ __launch_bounds__(256) void featq_kernel(
    const u16* __restrict__ featA, const u16* __restrict__ WcatT,
    const u16* __restrict__ meanF, const u16* __restrict__ WfkvT,
    const float* __restrict__ bias0, const float* __restrict__ bias1,
    const float* __restrict__ biaskv,
    u16* __restrict__ feat_bf, u16* __restrict__ q_bf, float* __restrict__ meanKV)
{
  int isMean = blockIdx.x >= 1024;
  const u16* A  = isMean ? meanF : featA;
  const u16* Bt = isMean ? WfkvT : WcatT;
  int uidx = isMean ? ((int)blockIdx.x - 1024) : (int)blockIdx.x;
  int NWG  = isMean ? 32 : 1024;
  GEMM_MAIN1D(A, Bt, 256, 8, NWG, uidx)
  if (!isMean){
    int half = n0 >> 9;
    u16* outp = half ? q_bf : feat_bf;
    const float* bias = half ? bias1 : bias0;
    int nb = n0 & 511;
    #pragma unroll
    for (int j = 0; j < 4; j++){
      int col = nb + wn + j*16 + lr;
      float bcol = bias[col];
      #pragma unroll
      for (int i = 0; i < 4; i++){
        int row0 = m0 + wm + i*16 + lrow;
        #pragma unroll
        for (int r = 0; r < 4; r++)
          outp[(size_t)(row0 + r)*DD + col] = f2bf(acc[i][j][r] + bcol);
      }
    }
  } else {
    #pragma unroll
    for (int j = 0; j < 4; j++){
      int col = n0 + wn + j*16 + lr;
      float bcol = biaskv[col];
      #pragma unroll
      for (int i = 0; i < 4; i++){
        int row0 = m0 + wm + i*16 + lrow;
        #pragma unroll
        for (int r = 0; r < 4; r++)
          meanKV[(size_t)(row0 + r)*1024 + col] = acc[i][j][r] + bcol;
      }
    }
  }
}

// ---------------- Launch 5: lin = agg @ Wo + bo ----------------
__global__ __launch_bounds__(256) void lin_kernel(
    const u16* __restrict__ agg_bf, const u16* __restrict__ WoT,
    const float* __restrict__ bo, u16* __restrict__ lin_bf)
{
  GEMM_MAIN1D(agg_bf, WoT, 512, 4, 512, (int)blockIdx.x)
  #pragma unroll
  for (int j = 0; j < 4; j++){
    int col = n0 + wn + j*16 + lr;
    float bcol = bo[col];
    #pragma unroll
    for (int i = 0; i < 4; i++){
      int row0 = m0 + wm + i*16 + lrow;
      #pragma unroll
      for (int r = 0; r < 4; r++)
        lin_bf[(size_t)(row0 + r)*DD + col] = f2bf(acc[i][j][r] + bcol);
    }
  }
}

// ---------------- Launch 4: cell-centric attention: 4 blocks per (b,cell) ----------------
__global__ __launch_bounds__(256) void attn_cells(
    const u16* __restrict__ q, const float* __restrict__ meanKV,
    const int* __restrict__ order, const int* __restrict__ counts,
    const int* __restrict__ cellstart, u16* __restrict__ agg)
{
  int bg4 = blockIdx.x;           // 0..2047
  int bg = bg4 >> 2, part = bg4 & 3;
  int b = bg >> 6, c = bg & 63;
  int gx = c >> 3, gy = c & 7;
  __shared__ __align__(16) u16 Kf[9][DD];
  __shared__ __align__(16) u16 Vf[9][DD];
  __shared__ int vrow[9];
  int t = threadIdx.x;
  if (t < 9){
    int dx = t/3 - 1, dy = t%3 - 1;
    int nx = gx + dx, ny = gy + dy;
    int inb = ((unsigned)nx < 8u) && ((unsigned)ny < 8u);
    int row = b*GG + (((nx&7) << 3) | (ny&7));
    vrow[t] = (inb && counts[row] > 0) ? row : -1;
  }
  __syncthreads();
  int d = 2*t;
  #pragma unroll
  for (int kk = 0; kk < 9; kk++){
    int row = vrow[kk];
    if (row >= 0){
      float2 mk = *(const float2*)&meanKV[(size_t)row*1024 + d];
      float2 pk = *(const float2*)&meanKV[(size_t)(512+kk)*1024 + d];
      float2 mv = *(const float2*)&meanKV[(size_t)row*1024 + 512 + d];
      float2 pv = *(const float2*)&meanKV[(size_t)(512+kk)*1024 + 512 + d];
      *(u32*)&Kf[kk][d] = (u32)f2bf(mk.x+pk.x) | ((u32)f2bf(mk.y+pk.y) << 16);
      *(u32*)&Vf[kk][d] = (u32)f2bf(mv.x+pv.x) | ((u32)f2bf(mv.y+pv.y) << 16);
    }
  }
  __syncthreads();
  int cnt = counts[bg];
  int wv = t >> 6, lane = t & 63;
  int widx = part*4 + wv;               // 0..15
  const int* ord = order + b*NPT + cellstart[bg];
  for (int i = widx; i < cnt; i += 16){
    size_t p = (size_t)b*NPT + ord[i];
    float qv[8];
    load8bf(q + p*DD + lane*8, qv);
    float s[9];
    #pragma unroll
    for (int kk = 0; kk < 9; kk++){
      float partial = 0.f;
      if (vrow[kk] >= 0){
        float kv[8]; load8bf(&Kf[kk][lane*8], kv);
        #pragma unroll
        for (int j = 0; j < 8; j++) partial += qv[j]*kv[j];
      }
      partial += __shfl_xor(partial, 1);
      partial += __shfl_xor(partial, 2);
      partial += __shfl_xor(partial, 4);
      partial += __shfl_xor(partial, 8);
      s[kk] = (vrow[kk] >= 0) ? partial * 0.08838834764831843f : -1e30f;
    }
    float mx = s[0];
    #pragma unroll
    for (int kk = 1; kk < 9; kk++) mx = fmaxf(mx, s[kk]);
    float w[9], sum = 0.f;
    #pragma unroll
    for (int kk = 0; kk < 9; kk++){
      w[kk] = (vrow[kk] >= 0) ? __expf(s[kk] - mx) : 0.f;
      sum += w[kk];
    }
    float inv = 1.f / sum;
    float a[8] = {0,0,0,0,0,0,0,0};
    #pragma unroll
    for (int kk = 0; kk < 9; kk++){
      if (vrow[kk] >= 0){
        float wk = w[kk] * inv;
        float vv[8]; load8bf(&Vf[kk][lane*8], vv);
        #pragma unroll
        for (int j = 0; j < 8; j++) a[j] += wk*vv[j];
      }
    }
    *(uint4*)&agg[p*DD + lane*8] = pack8(a);
  }
}

// ---------------- Launch 6: residual + layernorm ----------------
__global__ __launch_bounds__(256) void ln_kernel(
    const u16* __restrict__ feat, const u16* __restrict__ lin,
    const float* __restrict__ gamma, const float* __restrict__ beta,
    float* __restrict__ out)
{
  int wv = threadIdx.x >> 6, lane = threadIdx.x & 63;
  size_t r = (size_t)blockIdx.x * 4 + wv;
  int d0 = lane * 8;
  float fv[8], lv[8];
  load8bf(feat + r*DD + d0, fv);
  load8bf(lin  + r*DD + d0, lv);
  float e[8], s1 = 0.f, s2 = 0.f;
  #pragma unroll
  for (int j = 0; j < 8; j++){ e[j] = fv[j] + lv[j]; s1 += e[j]; s2 += e[j]*e[j]; }
  #pragma unroll
  for (int m = 1; m < 64; m <<= 1){ s1 += __shfl_xor(s1, m); s2 += __shfl_xor(s2, m); }
  float mu  = s1 * (1.f/512.f);
  float var = s2 * (1.f/512.f) - mu*mu;
  float istd = rsqrtf(var + 1e-5f);
  float gv[8], bev[8];
  load8(gamma + d0, gv); load8(beta + d0, bev);
  float o[8];
  #pragma unroll
  for (int j = 0; j < 8; j++) o[j] = (e[j] - mu)*istd*gv[j] + bev[j];
  store8(out + r*DD + d0, o);
}

extern "C" void kernel_launch(void* const* d_in, const int* in_sizes, int n_in,
                              void* d_out, int out_size, void* d_ws, size_t ws_size,
                              hipStream_t stream) {
  (void)in_sizes; (void)n_in; (void)out_size; (void)ws_size;
  const float* features = (const float*)d_in[0];
  const float* coords   = (const float*)d_in[1];
  const float* W_feat   = (const float*)d_in[2];
  const float* b_feat   = (const float*)d_in[3];
  const float* W_p1     = (const float*)d_in[4];
  const float* b_p1     = (const float*)d_in[5];
  const float* W_p2     = (const float*)d_in[6];
  const float* b_p2     = (const float*)d_in[7];
  const float* Wq = (const float*)d_in[8];  const float* bq = (const float*)d_in[9];
  const float* Wk = (const float*)d_in[10]; const float* bk = (const float*)d_in[11];
  const float* Wv = (const float*)d_in[12]; const float* bv = (const float*)d_in[13];
  const float* Wo = (const float*)d_in[14]; const float* bo = (const float*)d_in[15];
  const float* gamma = (const float*)d_in[16]; const float* beta = (const float*)d_in[17];
  float* out = (float*)d_out;

  char* ws = (char*)d_ws;
  size_t off = 0;
  auto alloc = [&](size_t bytes) -> void* {
    void* p = ws + off;
    off = (off + bytes + 255) & ~(size_t)255;
    return p;
  };
  u16*   featA     = (u16*)  alloc((size_t)NPTS*INDIM*2);   // 8.4 MB
  u16*   feat_bf   = (u16*)  alloc((size_t)NPTS*DD*2);      // 16.8 MB
  u16*   q_bf      = (u16*)  alloc((size_t)NPTS*DD*2);      // 16.8 MB
  u16*   agg_bf    = (u16*)  alloc((size_t)NPTS*DD*2);      // 16.8 MB
  u16*   lin_bf    = (u16*)  alloc((size_t)NPTS*DD*2);      // 16.8 MB
  u16*   W_feat_bf = (u16*)  alloc((size_t)INDIM*DD*2);     // [256][512]
  u16*   WqkvT     = (u16*)  alloc((size_t)1536*DD*2);      // [Wq^T;Wk^T;Wv^T]
  u16*   WoT       = (u16*)  alloc((size_t)DD*DD*2);
  // WcatT [1024][256] and WfkvT [1024][256] must be CONTIGUOUS (smallgemm writes across both)
  u16*   WcatT     = (u16*)  alloc((size_t)1024*INDIM*2);   // rows 0..511 W_feat^T, 512..1023 WfqT
  u16*   WfkvT     = (u16*)  alloc((size_t)1024*INDIM*2);   // (W_feat@[Wk|Wv])^T
  u16*   peD       = (u16*)  alloc((size_t)9*DD*2);
  u16*   meanF     = (u16*)  alloc((size_t)512*INDIM*2);
  float* meanKV    = (float*)alloc((size_t)640*1024*4);     // rows 0..511 mean-derived, 512..520 pe
  float* bfq       = (float*)alloc((size_t)DD*4);
  float* biaskv    = (float*)alloc((size_t)1024*4);
  int*   order     = (int*)  alloc((size_t)NPTS*4);
  int*   counts    = (int*)  alloc((size_t)NBATCH*GG*4);
  int*   cellstart = (int*)  alloc((size_t)NBATCH*GG*4);
  u16*   Xout      = WcatT + (size_t)512*INDIM;             // [1536][256]: WfqT then WfkvT

  // 1. mega-prep (+rank)
  prep_kernel<<<P_NB, 256, 0, stream>>>(
      features, W_feat, Wq, Wk, Wv, Wo, W_p1, b_p1, W_p2, b_p2,
      b_feat, bq, bk, bv, coords,
      featA, W_feat_bf, WqkvT, WoT, WcatT, peD, bfq, biaskv,
      order, counts, cellstart);
  // 2. [WfqT;WfkvT] GEMM + peKV rows + meanF gather
  mid_kernel<<<572, 256, 0, stream>>>(
      WqkvT, W_feat_bf, peD, Xout, meanKV, featA, order, counts, cellstart, meanF);
  // 3. [feat | q] GEMM + meanKV rows 0..511 GEMM
  featq_kernel<<<1056, 256, 0, stream>>>(
      featA, WcatT, meanF, WfkvT, b_feat, bfq, biaskv, feat_bf, q_bf, meanKV);
  // 4. cell-centric attention -> agg
  attn_cells<<<NBATCH*GG*4, 256, 0, stream>>>(q_bf, meanKV, order, counts, cellstart, agg_bf);
  // 5. lin = agg @ Wo + bo
  lin_kernel<<<512, 256, 0, stream>>>(agg_bf, WoT, bo, lin_bf);
  // 6. out = LN(feat + lin) * gamma + beta
  ln_kernel<<<NPTS/4, 256, 0, stream>>>(feat_bf, lin_bf, gamma, beta, out);
}

// Round 9
// 108.927 us; speedup vs baseline: 2.8147x; 1.0791x over previous
//
#include <hip/hip_runtime.h>
#include <stdint.h>

typedef unsigned short u16;
typedef unsigned int u32;
typedef __bf16 bf16x8 __attribute__((ext_vector_type(8)));
typedef float f32x4 __attribute__((ext_vector_type(4)));

#define NBATCH 8
#define NPT    2048
#define NPTS   16384     // NBATCH*NPT
#define INDIM  256
#define DD     512
#define GG     64        // 8x8 grid cells

__device__ __forceinline__ u16 f2bf(float f){
  u32 u = __builtin_bit_cast(u32, f);
  u += 0x7fffu + ((u >> 16) & 1u);
  return (u16)(u >> 16);
}
__device__ __forceinline__ float bf2f(u16 h){
  u32 u = ((u32)h) << 16;
  return __builtin_bit_cast(float, u);
}
__device__ __forceinline__ void load8(const float* __restrict__ p, float* r){
  float4 a = *(const float4*)p;
  float4 b = *(const float4*)(p + 4);
  r[0]=a.x;r[1]=a.y;r[2]=a.z;r[3]=a.w;r[4]=b.x;r[5]=b.y;r[6]=b.z;r[7]=b.w;
}
__device__ __forceinline__ void load8bf(const u16* __restrict__ p, float* r){
  uint4 v = *(const uint4*)p;
  r[0]=bf2f((u16)v.x); r[1]=bf2f((u16)(v.x>>16));
  r[2]=bf2f((u16)v.y); r[3]=bf2f((u16)(v.y>>16));
  r[4]=bf2f((u16)v.z); r[5]=bf2f((u16)(v.z>>16));
  r[6]=bf2f((u16)v.w); r[7]=bf2f((u16)(v.w>>16));
}
__device__ __forceinline__ void store8(float* __restrict__ p, const float* r){
  float4 a; a.x=r[0];a.y=r[1];a.z=r[2];a.w=r[3];
  float4 b; b.x=r[4];b.y=r[5];b.z=r[6];b.w=r[7];
  *(float4*)p = a; *(float4*)(p+4) = b;
}
__device__ __forceinline__ uint4 pack8(const float* a){
  uint4 pk;
  pk.x = (u32)f2bf(a[0]) | ((u32)f2bf(a[1]) << 16);
  pk.y = (u32)f2bf(a[2]) | ((u32)f2bf(a[3]) << 16);
  pk.z = (u32)f2bf(a[4]) | ((u32)f2bf(a[5]) << 16);
  pk.w = (u32)f2bf(a[6]) | ((u32)f2bf(a[7]) << 16);
  return pk;
}
typedef __attribute__((address_space(1))) unsigned as1u;
typedef __attribute__((address_space(3))) unsigned as3u;
__device__ __forceinline__ void gload16(const void* g, void* l){
  __builtin_amdgcn_global_load_lds((as1u*)(uintptr_t)g, (as3u*)(uintptr_t)l, 16, 0, 0);
}

// ---- 64x64 LDS-tiled transpose: src f32[*][scols] -> dst bf16[*][dcols] ----
__device__ __forceinline__ void transpose64(const float* __restrict__ src, int scols,
                                            u16* __restrict__ dst, int dcols,
                                            int r0, int c0, char* smem, int t){
  float (*sh)[65] = (float(*)[65])smem;
  #pragma unroll
  for (int i = 0; i < 16; i++){
    int idx = i*256 + t;
    int r = idx >> 6, c = idx & 63;
    sh[r][c] = src[(size_t)(r0 + r)*scols + c0 + c];
  }
  __syncthreads();
  #pragma unroll
  for (int i = 0; i < 8; i++){
    int idx = i*512 + t*2;
    int oR = idx >> 6, oC = idx & 63;
    u32 pk = (u32)f2bf(sh[oC][oR]) | ((u32)f2bf(sh[oC+1][oR]) << 16);
    *(u32*)(dst + (size_t)(c0 + oR)*dcols + r0 + oC) = pk;
  }
}

// ================= Launch 1: mega-prep (all independent preprocessing + rank) =================
#define P_R1 2048
#define P_R2 2112
#define P_R3 2368
#define P_R4 2400
#define P_R5 2409
#define P_R6 2411
#define P_R7 2415
#define P_NB 2423
__global__ __launch_bounds__(256) void prep_kernel(
    const float* __restrict__ features, const float* __restrict__ W_feat,
    const float* __restrict__ Wq, const float* __restrict__ Wk,
    const float* __restrict__ Wv, const float* __restrict__ Wo,
    const float* __restrict__ W_p1, const float* __restrict__ b_p1,
    const float* __restrict__ W_p2, const float* __restrict__ b_p2,
    const float* __restrict__ b_feat, const float* __restrict__ bq,
    const float* __restrict__ bk, const float* __restrict__ bv,
    const float* __restrict__ coords,
    u16* __restrict__ featA, u16* __restrict__ W_feat_bf,
    u16* __restrict__ WqkvT, u16* __restrict__ WoT, u16* __restrict__ WcatT,
    u16* __restrict__ peD, float* __restrict__ bfq, float* __restrict__ biaskv,
    int* __restrict__ order, int* __restrict__ counts, int* __restrict__ cellstart)
{
  __shared__ __align__(16) char smem[34048];
  int bid = blockIdx.x, t = threadIdx.x;
  if (bid < P_R1){
    int i = bid*256 + t;
    float r[8]; load8(features + (size_t)i*8, r);
    *(uint4*)(featA + (size_t)i*8) = pack8(r);
  } else if (bid < P_R2){
    int i = (bid - P_R1)*256 + t;
    float r[8]; load8(W_feat + (size_t)i*8, r);
    *(uint4*)(W_feat_bf + (size_t)i*8) = pack8(r);
  } else if (bid < P_R3){
    int rel = bid - P_R2;
    int mat = rel >> 6, tile = rel & 63;
    int r0 = (tile >> 3)*64, c0 = (tile & 7)*64;
    const float* src = mat==0 ? Wq : (mat==1 ? Wk : (mat==2 ? Wv : Wo));
    u16* dst = mat==0 ? WqkvT : (mat==1 ? WqkvT + (size_t)512*DD
                     : (mat==2 ? WqkvT + (size_t)1024*DD : WoT));
    transpose64(src, DD, dst, DD, r0, c0, smem, t);
  } else if (bid < P_R4){
    int rel = bid - P_R3;                 // W_feat [256][512] -> WcatT rows 0..511
    int r0 = (rel >> 3)*64, c0 = (rel & 7)*64;
    transpose64(W_feat, DD, WcatT, INDIM, r0, c0, smem, t);
  } else if (bid < P_R5){
    int kk = bid - P_R4;                  // pos-enc MLP -> peD
    float dx = (float)(kk/3 - 1), dy = (float)(kk%3 - 1);
    float* h = (float*)smem;
    float hv = dx*W_p1[t] + dy*W_p1[256 + t] + b_p1[t];
    h[t] = hv > 0.f ? hv : 0.f;
    __syncthreads();
    float acc0 = b_p2[t], acc1 = b_p2[t + 256];
    for (int c = 0; c < 256; c++){
      float hc = h[c];
      acc0 += hc * W_p2[(size_t)c*DD + t];
      acc1 += hc * W_p2[(size_t)c*DD + t + 256];
    }
    peD[(size_t)kk*DD + t]       = f2bf(acc0);
    peD[(size_t)kk*DD + t + 256] = f2bf(acc1);
  } else if (bid < P_R6){
    int i = (bid - P_R5)*256 + t;         // bfq = b_feat@Wq + bq
    float* bfs = (float*)smem;
    bfs[t] = b_feat[t]; bfs[t + 256] = b_feat[t + 256];
    __syncthreads();
    float acc = 0.f;
    for (int k = 0; k < DD; k++) acc += bfs[k] * Wq[(size_t)k*DD + i];
    bfq[i] = acc + bq[i];
  } else if (bid < P_R7){
    int n = (bid - P_R6)*256 + t;         // biaskv = b_feat@[Wk|Wv] + [bk|bv]
    float* bfs = (float*)smem;
    bfs[t] = b_feat[t]; bfs[t + 256] = b_feat[t + 256];
    __syncthreads();
    const float* W = (n < 512) ? Wk : Wv;
    int c = n & 511;
    float acc = 0.f;
    for (int k = 0; k < DD; k++) acc += bfs[k] * W[(size_t)k*DD + c];
    biaskv[n] = acc + ((n < 512) ? bk[c] : bv[c]);
  } else {
    int b = bid - P_R7;                   // rank: cell-id + stable counting sort
    u16 (*hist)[65] = (u16(*)[65])smem;
    int* tot  = (int*)(smem + 33280);
    int* base = (int*)(smem + 33536);
    #pragma unroll
    for (int i = 0; i < 65; i++) hist[t][i] = 0;
    int myc[8];
    float cxy[16];
    load8(coords + (size_t)(b*NPT + t*8)*2,     cxy);
    load8(coords + (size_t)(b*NPT + t*8)*2 + 8, cxy + 8);
    #pragma unroll
    for (int i = 0; i < 8; i++){
      int gx = (int)(cxy[2*i]   * (1.0f/32.0f)); gx = gx < 0 ? 0 : (gx > 7 ? 7 : gx);
      int gy = (int)(cxy[2*i+1] * (1.0f/32.0f)); gy = gy < 0 ? 0 : (gy > 7 ? 7 : gy);
      myc[i] = gx*8 + gy;
      hist[t][myc[i]]++;
    }
    __syncthreads();
    if (t < GG){
      int acc = 0;
      for (int tt = 0; tt < 256; tt++){ int v = hist[tt][t]; hist[tt][t] = (u16)acc; acc += v; }
      tot[t] = acc;
    }
    __syncthreads();
    if (t == 0){
      int acc = 0;
      for (int g = 0; g < GG; g++){ base[g] = acc; acc += tot[g]; }
    }
    __syncthreads();
    if (t < GG){
      counts[b*GG + t] = tot[t];
      cellstart[b*GG + t] = base[t];
    }
    #pragma unroll
    for (int i = 0; i < 8; i++){
      int g = myc[i];
      int local = 0;
      #pragma unroll
      for (int j = 0; j < 8; j++) local += (j < i && myc[j] == g) ? 1 : 0;
      order[b*NPT + base[g] + (int)hist[t][g] + local] = t*8 + i;
    }
  }
}

// ======== 2-phase pipelined GEMM core: 128x128 tile, 4 waves, dbuf LDS, XCD swizzle ========
// T3-minimum recipe: STAGE(s+1) issued BEFORE compute(s); one barrier per K-step.
// NWGv must be a multiple of 8.
#define BM 128
#define BN 128
#define GEMM_PIPE(Aptr, Btptr, Kv, GXv, NWGv, UIDX)                                \
  __shared__ __align__(16) u16 lA[2][BM*32];                                       \
  __shared__ __align__(16) u16 lB[2][BN*32];                                       \
  int tid = threadIdx.x;                                                           \
  int orig_ = (UIDX);                                                              \
  int swz_ = (orig_ & 7)*((NWGv) >> 3) + (orig_ >> 3);                             \
  int m0 = (swz_ / (GXv)) * BM, n0 = (swz_ % (GXv)) * BN;                          \
  int lane = tid & 63;                                                             \
  int wv = tid >> 6;                                                               \
  int wm = (wv >> 1) * 64, wn = (wv & 1) * 64;                                     \
  int lr = lane & 15;                                                              \
  int kg = (lane >> 4) << 3;                                                       \
  f32x4 acc[4][4] = {};                                                            \
  {                                                                                \
    int srow = lane >> 2;                                                          \
    int scol = (lane & 3) << 3;                                                    \
    const u16* gA0 = (Aptr)  + (size_t)(m0 + wv*32 + srow)*(Kv) + scol;            \
    const u16* gB0 = (Btptr) + (size_t)(n0 + wv*32 + srow)*(Kv) + scol;            \
    int lofs = (wv*32)*32;                                                         \
    int steps = (Kv) >> 5;                                                         \
    gload16(gA0,                   lA[0] + lofs);                                  \
    gload16(gA0 + (size_t)16*(Kv), lA[0] + lofs + 16*32);                          \
    gload16(gB0,                   lB[0] + lofs);                                  \
    gload16(gB0 + (size_t)16*(Kv), lB[0] + lofs + 16*32);                          \
    __syncthreads();                                                               \
    for (int s = 0; s < steps; s++){                                               \
      int cur = s & 1;                                                             \
      if (s + 1 < steps){                                                          \
        int kt = (s + 1) << 5;                                                     \
        gload16(gA0 + kt,                   lA[cur^1] + lofs);                     \
        gload16(gA0 + kt + (size_t)16*(Kv), lA[cur^1] + lofs + 16*32);             \
        gload16(gB0 + kt,                   lB[cur^1] + lofs);                     \
        gload16(gB0 + kt + (size_t)16*(Kv), lB[cur^1] + lofs + 16*32);             \
      }                                                                            \
      bf16x8 af[4], bfv[4];                                                        \
      _Pragma("unroll")                                                            \
      for (int i = 0; i < 4; i++) af[i]  = *(const bf16x8*)&lA[cur][(wm + i*16 + lr)*32 + kg]; \
      _Pragma("unroll")                                                            \
      for (int j = 0; j < 4; j++) bfv[j] = *(const bf16x8*)&lB[cur][(wn + j*16 + lr)*32 + kg]; \
      _Pragma("unroll")                                                            \
      for (int i = 0; i < 4; i++)                                                  \
        _Pragma("unroll")                                                          \
        for (int j = 0; j < 4; j++)                                                \
          acc[i][j] = __builtin_amdgcn_mfma_f32_16x16x32_bf16(af[i], bfv[j], acc[i][j], 0, 0, 0); \
      __syncthreads();                                                             \
    }                                                                              \
  }                                                                                \
  int lrow = (lane >> 4) << 2;

// ========== Launch 2: smallgemm (24) + peKV (36) + meanF gather (512) = 572 blocks ==========
__global__ __launch_bounds__(256) void mid_kernel(
    const u16* __restrict__ WqkvT, const u16* __restrict__ W_feat_bf,
    const u16* __restrict__ peD, u16* __restrict__ Xout, float* __restrict__ meanKV,
    const u16* __restrict__ featA, const int* __restrict__ order,
    const int* __restrict__ counts, const int* __restrict__ cellstart,
    u16* __restrict__ meanF)
{
  if (blockIdx.x < 24){
    // Xout[1536][256] = [Wq;Wk;Wv]^T @ W_feat^T  (bf16)
    GEMM_PIPE(WqkvT, W_feat_bf, 512, 2, 24, (int)blockIdx.x)
    #pragma unroll
    for (int j = 0; j < 4; j++){
      int col = n0 + wn + j*16 + lr;
      #pragma unroll
      for (int i = 0; i < 4; i++){
        int row0 = m0 + wm + i*16 + lrow;
        #pragma unroll
        for (int r = 0; r < 4; r++)
          Xout[(size_t)(row0 + r)*INDIM + col] = f2bf(acc[i][j][r]);
      }
    }
  } else if (blockIdx.x < 60){
    __shared__ float pesh[512];
    int bid2 = blockIdx.x - 24;
    int kk = bid2 >> 2, seg = bid2 & 3;
    int t = threadIdx.x;
    int n = seg*256 + t;
    pesh[t]       = bf2f(peD[(size_t)kk*DD + t]);
    pesh[t + 256] = bf2f(peD[(size_t)kk*DD + t + 256]);
    __syncthreads();
    const u16* wrow = WqkvT + (size_t)(512 + n)*DD;
    float acc = 0.f;
    for (int d8 = 0; d8 < 64; d8++){
      float w8[8]; load8bf(wrow + d8*8, w8);
      #pragma unroll
      for (int j = 0; j < 8; j++) acc += pesh[d8*8 + j]*w8[j];
    }
    meanKV[(size_t)(512 + kk)*1024 + n] = acc;
  } else {
    __shared__ float part[128][2];
    int bg = blockIdx.x - 60;             // 0..511
    int b = bg >> 6;
    int t = threadIdx.x;
    int p = t & 127, half = t >> 7;
    int cnt = counts[bg], start = cellstart[bg];
    const int* ord = order + b*NPT + start;
    float a0 = 0.f, a1 = 0.f;
    for (int n = half; n < cnt; n += 2){
      u32 v = *(const u32*)(featA + (((size_t)(b*NPT + ord[n])) << 8) + p*2);
      a0 += bf2f((u16)v); a1 += bf2f((u16)(v >> 16));
    }
    if (half){ part[p][0] = a0; part[p][1] = a1; }
    __syncthreads();
    if (!half){
      a0 += part[p][0]; a1 += part[p][1];
      float inv = 1.f / (float)(cnt > 0 ? cnt : 1);
      *(u32*)(meanF + (size_t)bg*INDIM + p*2) =
          (u32)f2bf(a0*inv) | ((u32)f2bf(a1*inv) << 16);
    }
  }
}

// ========== Launch 3: featq GEMM (1024) + meanKV GEMM (32) = 1056 blocks ==========
__global__ __launch_bounds__(256) void featq_kernel(
    const u16* __restrict__ featA, const u16* __restrict__ WcatT,
    const u16* __restrict__ meanF, const u16* __restrict__ WfkvT,
    const float* __restrict__ bias0, const float* __restrict__ bias1,
    const float* __restrict__ biaskv,
    u16* __restrict__ feat_bf, u16* __restrict__ q_bf, float* __restrict__ meanKV)
{
  int isMean = blockIdx.x >= 1024;
  const u16* A  = isMean ? meanF : featA;
  const u16* Bt = isMean ? WfkvT : WcatT;
  int uidx = isMean ? ((int)blockIdx.x - 1024) : (int)blockIdx.x;
  int NWG  = isMean ? 32 : 1024;
  GEMM_PIPE(A, Bt, 256, 8, NWG, uidx)
  if (!isMean){
    int half = n0 >> 9;
    u16* outp = half ? q_bf : feat_bf;
    const float* bias = half ? bias1 : bias0;
    int nb = n0 & 511;
    #pragma unroll
    for (int j = 0; j < 4; j++){
      int col = nb + wn + j*16 + lr;
      float bcol = bias[col];
      #pragma unroll
      for (int i = 0; i < 4; i++){
        int row0 = m0 + wm + i*16 + lrow;
        #pragma unroll
        for (int r = 0; r < 4; r++)
          outp[(size_t)(row0 + r)*DD + col] = f2bf(acc[i][j][r] + bcol);
      }
    }
  } else {
    #pragma unroll
    for (int j = 0; j < 4; j++){
      int col = n0 + wn + j*16 + lr;
      float bcol = biaskv[col];
      #pragma unroll
      for (int i = 0; i < 4; i++){
        int row0 = m0 + wm + i*16 + lrow;
        #pragma unroll
        for (int r = 0; r < 4; r++)
          meanKV[(size_t)(row0 + r)*1024 + col] = acc[i][j][r] + bcol;
      }
    }
  }
}

// ---------------- Launch 4: cell-centric attention: 1 block (1024 thr) per (b,cell) ----------------
__global__ __launch_bounds__(1024) void attn_cells(
    const u16* __restrict__ q, const float* __restrict__ meanKV,
    const int* __restrict__ order, const int* __restrict__ counts,
    const int* __restrict__ cellstart, u16* __restrict__ agg)
{
  int bg = blockIdx.x;            // 0..511
  int b = bg >> 6, c = bg & 63;
  int gx = c >> 3, gy = c & 7;
  __shared__ __align__(16) u16 Kf[9][DD];
  __shared__ __align__(16) u16 Vf[9][DD];
  __shared__ int vrow[9];
  int t = threadIdx.x;
  if (t < 9){
    int dx = t/3 - 1, dy = t%3 - 1;
    int nx = gx + dx, ny = gy + dy;
    int inb = ((unsigned)nx < 8u) && ((unsigned)ny < 8u);
    int row = b*GG + (((nx&7) << 3) | (ny&7));
    vrow[t] = (inb && counts[row] > 0) ? row : -1;
  }
  __syncthreads();
  int d = 2*(t & 255);
  for (int kk = (t >> 8); kk < 9; kk += 4){
    int row = vrow[kk];
    if (row >= 0){
      float2 mk = *(const float2*)&meanKV[(size_t)row*1024 + d];
      float2 pk = *(const float2*)&meanKV[(size_t)(512+kk)*1024 + d];
      float2 mv = *(const float2*)&meanKV[(size_t)row*1024 + 512 + d];
      float2 pv = *(const float2*)&meanKV[(size_t)(512+kk)*1024 + 512 + d];
      *(u32*)&Kf[kk][d] = (u32)f2bf(mk.x+pk.x) | ((u32)f2bf(mk.y+pk.y) << 16);
      *(u32*)&Vf[kk][d] = (u32)f2bf(mv.x+pv.x) | ((u32)f2bf(mv.y+pv.y) << 16);
    }
  }
  __syncthreads();
  int cnt = counts[bg];
  int wv = t >> 6, lane = t & 63;     // wv: 0..15
  const int* ord = order + b*NPT + cellstart[bg];
  for (int i = wv; i < cnt; i += 16){
    size_t p = (size_t)b*NPT + ord[i];
    float qv[8];
    load8bf(q + p*DD + lane*8, qv);
    float s[9];
    #pragma unroll
    for (int kk = 0; kk < 9; kk++){
      float partial = 0.f;
      if (vrow[kk] >= 0){
        float kv[8]; load8bf(&Kf[kk][lane*8], kv);
        #pragma unroll
        for (int j = 0; j < 8; j++) partial += qv[j]*kv[j];
      }
      partial += __shfl_xor(partial, 1);
      partial += __shfl_xor(partial, 2);
      partial += __shfl_xor(partial, 4);
      partial += __shfl_xor(partial, 8);
      s[kk] = (vrow[kk] >= 0) ? partial * 0.08838834764831843f : -1e30f;
    }
    float mx = s[0];
    #pragma unroll
    for (int kk = 1; kk < 9; kk++) mx = fmaxf(mx, s[kk]);
    float w[9], sum = 0.f;
    #pragma unroll
    for (int kk = 0; kk < 9; kk++){
      w[kk] = (vrow[kk] >= 0) ? __expf(s[kk] - mx) : 0.f;
      sum += w[kk];
    }
    float inv = 1.f / sum;
    float a[8] = {0,0,0,0,0,0,0,0};
    #pragma unroll
    for (int kk = 0; kk < 9; kk++){
      if (vrow[kk] >= 0){
        float wk = w[kk] * inv;
        float vv[8]; load8bf(&Vf[kk][lane*8], vv);
        #pragma unroll
        for (int j = 0; j < 8; j++) a[j] += wk*vv[j];
      }
    }
    *(uint4*)&agg[p*DD + lane*8] = pack8(a);
  }
}

// ---------------- Launch 5: lin = agg @ Wo + bo ----------------
__global__ __launch_bounds__(256) void lin_kernel(
    const u16* __restrict__ agg_bf, const u16* __restrict__ WoT,
    const float* __restrict__ bo, u16* __restrict__ lin_bf)
{
  GEMM_PIPE(agg_bf, WoT, 512, 4, 512, (int)blockIdx.x)
  #pragma unroll
  for (int j = 0; j < 4; j++){
    int col = n0 + wn + j*16 + lr;
    float bcol = bo[col];
    #pragma unroll
    for (int i = 0; i < 4; i++){
      int row0 = m0 + wm + i*16 + lrow;
      #pragma unroll
      for (int r = 0; r < 4; r++)
        lin_bf[(size_t)(row0 + r)*DD + col] = f2bf(acc[i][j][r] + bcol);
    }
  }
}

// ---------------- Launch 6: residual + layernorm ----------------
__global__ __launch_bounds__(256) void ln_kernel(
    const u16* __restrict__ feat, const u16* __restrict__ lin,
    const float* __restrict__ gamma, const float* __restrict__ beta,
    float* __restrict__ out)
{
  int wv = threadIdx.x >> 6, lane = threadIdx.x & 63;
  size_t r = (size_t)blockIdx.x * 4 + wv;
  int d0 = lane * 8;
  float fv[8], lv[8];
  load8bf(feat + r*DD + d0, fv);
  load8bf(lin  + r*DD + d0, lv);
  float e[8], s1 = 0.f, s2 = 0.f;
  #pragma unroll
  for (int j = 0; j < 8; j++){ e[j] = fv[j] + lv[j]; s1 += e[j]; s2 += e[j]*e[j]; }
  #pragma unroll
  for (int m = 1; m < 64; m <<= 1){ s1 += __shfl_xor(s1, m); s2 += __shfl_xor(s2, m); }
  float mu  = s1 * (1.f/512.f);
  float var = s2 * (1.f/512.f) - mu*mu;
  float istd = rsqrtf(var + 1e-5f);
  float gv[8], bev[8];
  load8(gamma + d0, gv); load8(beta + d0, bev);
  float o[8];
  #pragma unroll
  for (int j = 0; j < 8; j++) o[j] = (e[j] - mu)*istd*gv[j] + bev[j];
  store8(out + r*DD + d0, o);
}

extern "C" void kernel_launch(void* const* d_in, const int* in_sizes, int n_in,
                              void* d_out, int out_size, void* d_ws, size_t ws_size,
                              hipStream_t stream) {
  (void)in_sizes; (void)n_in; (void)out_size; (void)ws_size;
  const float* features = (const float*)d_in[0];
  const float* coords   = (const float*)d_in[1];
  const float* W_feat   = (const float*)d_in[2];
  const float* b_feat   = (const float*)d_in[3];
  const float* W_p1     = (const float*)d_in[4];
  const float* b_p1     = (const float*)d_in[5];
  const float* W_p2     = (const float*)d_in[6];
  const float* b_p2     = (const float*)d_in[7];
  const float* Wq = (const float*)d_in[8];  const float* bq = (const float*)d_in[9];
  const float* Wk = (const float*)d_in[10]; const float* bk = (const float*)d_in[11];
  const float* Wv = (const float*)d_in[12]; const float* bv = (const float*)d_in[13];
  const float* Wo = (const float*)d_in[14]; const float* bo = (const float*)d_in[15];
  const float* gamma = (const float*)d_in[16]; const float* beta = (const float*)d_in[17];
  float* out = (float*)d_out;

  char* ws = (char*)d_ws;
  size_t off = 0;
  auto alloc = [&](size_t bytes) -> void* {
    void* p = ws + off;
    off = (off + bytes + 255) & ~(size_t)255;
    return p;
  };
  u16*   featA     = (u16*)  alloc((size_t)NPTS*INDIM*2);   // 8.4 MB
  u16*   feat_bf   = (u16*)  alloc((size_t)NPTS*DD*2);      // 16.8 MB
  u16*   q_bf      = (u16*)  alloc((size_t)NPTS*DD*2);      // 16.8 MB
  u16*   agg_bf    = (u16*)  alloc((size_t)NPTS*DD*2);      // 16.8 MB
  u16*   lin_bf    = (u16*)  alloc((size_t)NPTS*DD*2);      // 16.8 MB
  u16*   W_feat_bf = (u16*)  alloc((size_t)INDIM*DD*2);     // [256][512]
  u16*   WqkvT     = (u16*)  alloc((size_t)1536*DD*2);      // [Wq^T;Wk^T;Wv^T]
  u16*   WoT       = (u16*)  alloc((size_t)DD*DD*2);
  // WcatT [1024][256] and WfkvT [1024][256] must be CONTIGUOUS (smallgemm writes across both)
  u16*   WcatT     = (u16*)  alloc((size_t)1024*INDIM*2);   // rows 0..511 W_feat^T, 512..1023 WfqT
  u16*   WfkvT     = (u16*)  alloc((size_t)1024*INDIM*2);   // (W_feat@[Wk|Wv])^T
  u16*   peD       = (u16*)  alloc((size_t)9*DD*2);
  u16*   meanF     = (u16*)  alloc((size_t)512*INDIM*2);
  float* meanKV    = (float*)alloc((size_t)640*1024*4);     // rows 0..511 mean-derived, 512..520 pe
  float* bfq       = (float*)alloc((size_t)DD*4);
  float* biaskv    = (float*)alloc((size_t)1024*4);
  int*   order     = (int*)  alloc((size_t)NPTS*4);
  int*   counts    = (int*)  alloc((size_t)NBATCH*GG*4);
  int*   cellstart = (int*)  alloc((size_t)NBATCH*GG*4);
  u16*   Xout      = WcatT + (size_t)512*INDIM;             // [1536][256]: WfqT then WfkvT

  // 1. mega-prep (+rank)
  prep_kernel<<<P_NB, 256, 0, stream>>>(
      features, W_feat, Wq, Wk, Wv, Wo, W_p1, b_p1, W_p2, b_p2,
      b_feat, bq, bk, bv, coords,
      featA, W_feat_bf, WqkvT, WoT, WcatT, peD, bfq, biaskv,
      order, counts, cellstart);
  // 2. [WfqT;WfkvT] GEMM + peKV rows + meanF gather
  mid_kernel<<<572, 256, 0, stream>>>(
      WqkvT, W_feat_bf, peD, Xout, meanKV, featA, order, counts, cellstart, meanF);
  // 3. [feat | q] GEMM + meanKV rows 0..511 GEMM
  featq_kernel<<<1056, 256, 0, stream>>>(
      featA, WcatT, meanF, WfkvT, b_feat, bfq, biaskv, feat_bf, q_bf, meanKV);
  // 4. cell-centric attention -> agg
  attn_cells<<<NBATCH*GG, 1024, 0, stream>>>(q_bf, meanKV, order, counts, cellstart, agg_bf);
  // 5. lin = agg @ Wo + bo
  lin_kernel<<<512, 256, 0, stream>>>(agg_bf, WoT, bo, lin_bf);
  // 6. out = LN(feat + lin) * gamma + beta
  ln_kernel<<<NPTS/4, 256, 0, stream>>>(feat_bf, lin_bf, gamma, beta, out);
}

// Round 10
// 102.838 us; speedup vs baseline: 2.9813x; 1.0592x over previous
//
#include <hip/hip_runtime.h>
#include <stdint.h>

typedef unsigned short u16;
typedef unsigned int u32;
typedef __bf16 bf16x8 __attribute__((ext_vector_type(8)));
typedef float f32x4 __attribute__((ext_vector_type(4)));

#define NBATCH 8
#define NPT    2048
#define NPTS   16384     // NBATCH*NPT
#define INDIM  256
#define DD     512
#define GG     64        // 8x8 grid cells

__device__ __forceinline__ u16 f2bf(float f){
  u32 u = __builtin_bit_cast(u32, f);
  u += 0x7fffu + ((u >> 16) & 1u);
  return (u16)(u >> 16);
}
__device__ __forceinline__ float bf2f(u16 h){
  u32 u = ((u32)h) << 16;
  return __builtin_bit_cast(float, u);
}
__device__ __forceinline__ void load8(const float* __restrict__ p, float* r){
  float4 a = *(const float4*)p;
  float4 b = *(const float4*)(p + 4);
  r[0]=a.x;r[1]=a.y;r[2]=a.z;r[3]=a.w;r[4]=b.x;r[5]=b.y;r[6]=b.z;r[7]=b.w;
}
__device__ __forceinline__ void load8bf(const u16* __restrict__ p, float* r){
  uint4 v = *(const uint4*)p;
  r[0]=bf2f((u16)v.x); r[1]=bf2f((u16)(v.x>>16));
  r[2]=bf2f((u16)v.y); r[3]=bf2f((u16)(v.y>>16));
  r[4]=bf2f((u16)v.z); r[5]=bf2f((u16)(v.z>>16));
  r[6]=bf2f((u16)v.w); r[7]=bf2f((u16)(v.w>>16));
}
__device__ __forceinline__ void store8(float* __restrict__ p, const float* r){
  float4 a; a.x=r[0];a.y=r[1];a.z=r[2];a.w=r[3];
  float4 b; b.x=r[4];b.y=r[5];b.z=r[6];b.w=r[7];
  *(float4*)p = a; *(float4*)(p+4) = b;
}
__device__ __forceinline__ uint4 pack8(const float* a){
  uint4 pk;
  pk.x = (u32)f2bf(a[0]) | ((u32)f2bf(a[1]) << 16);
  pk.y = (u32)f2bf(a[2]) | ((u32)f2bf(a[3]) << 16);
  pk.z = (u32)f2bf(a[4]) | ((u32)f2bf(a[5]) << 16);
  pk.w = (u32)f2bf(a[6]) | ((u32)f2bf(a[7]) << 16);
  return pk;
}
typedef __attribute__((address_space(1))) unsigned as1u;
typedef __attribute__((address_space(3))) unsigned as3u;
__device__ __forceinline__ void gload16(const void* g, void* l){
  __builtin_amdgcn_global_load_lds((as1u*)(uintptr_t)g, (as3u*)(uintptr_t)l, 16, 0, 0);
}

// ---- 64x64 LDS-tiled transpose: src f32[*][scols] -> dst bf16[*][dcols] ----
__device__ __forceinline__ void transpose64(const float* __restrict__ src, int scols,
                                            u16* __restrict__ dst, int dcols,
                                            int r0, int c0, char* smem, int t){
  float (*sh)[65] = (float(*)[65])smem;
  #pragma unroll
  for (int i = 0; i < 16; i++){
    int idx = i*256 + t;
    int r = idx >> 6, c = idx & 63;
    sh[r][c] = src[(size_t)(r0 + r)*scols + c0 + c];
  }
  __syncthreads();
  #pragma unroll
  for (int i = 0; i < 8; i++){
    int idx = i*512 + t*2;
    int oR = idx >> 6, oC = idx & 63;
    u32 pk = (u32)f2bf(sh[oC][oR]) | ((u32)f2bf(sh[oC+1][oR]) << 16);
    *(u32*)(dst + (size_t)(c0 + oR)*dcols + r0 + oC) = pk;
  }
}

// ================= Launch 1: mega-prep (all independent preprocessing + rank) =================
#define P_R1 2048
#define P_R2 2112
#define P_R3 2368
#define P_R4 2400
#define P_R5 2409
#define P_R6 2411
#define P_R7 2415
#define P_NB 2423
__global__ __launch_bounds__(256) void prep_kernel(
    const float* __restrict__ features, const float* __restrict__ W_feat,
    const float* __restrict__ Wq, const float* __restrict__ Wk,
    const float* __restrict__ Wv, const float* __restrict__ Wo,
    const float* __restrict__ W_p1, const float* __restrict__ b_p1,
    const float* __restrict__ W_p2, const float* __restrict__ b_p2,
    const float* __restrict__ b_feat, const float* __restrict__ bq,
    const float* __restrict__ bk, const float* __restrict__ bv,
    const float* __restrict__ coords,
    u16* __restrict__ featA, u16* __restrict__ W_feat_bf,
    u16* __restrict__ WqkvT, u16* __restrict__ WoT, u16* __restrict__ WcatT,
    u16* __restrict__ peD, float* __restrict__ bfq, float* __restrict__ biaskv,
    int* __restrict__ order, int* __restrict__ counts, int* __restrict__ cellstart)
{
  __shared__ __align__(16) char smem[34048];
  int bid = blockIdx.x, t = threadIdx.x;
  if (bid < P_R1){
    int i = bid*256 + t;
    float r[8]; load8(features + (size_t)i*8, r);
    *(uint4*)(featA + (size_t)i*8) = pack8(r);
  } else if (bid < P_R2){
    int i = (bid - P_R1)*256 + t;
    float r[8]; load8(W_feat + (size_t)i*8, r);
    *(uint4*)(W_feat_bf + (size_t)i*8) = pack8(r);
  } else if (bid < P_R3){
    int rel = bid - P_R2;
    int mat = rel >> 6, tile = rel & 63;
    int r0 = (tile >> 3)*64, c0 = (tile & 7)*64;
    const float* src = mat==0 ? Wq : (mat==1 ? Wk : (mat==2 ? Wv : Wo));
    u16* dst = mat==0 ? WqkvT : (mat==1 ? WqkvT + (size_t)512*DD
                     : (mat==2 ? WqkvT + (size_t)1024*DD : WoT));
    transpose64(src, DD, dst, DD, r0, c0, smem, t);
  } else if (bid < P_R4){
    int rel = bid - P_R3;                 // W_feat [256][512] -> WcatT [512][256]
    int r0 = (rel >> 3)*64, c0 = (rel & 7)*64;
    transpose64(W_feat, DD, WcatT, INDIM, r0, c0, smem, t);
  } else if (bid < P_R5){
    int kk = bid - P_R4;                  // pos-enc MLP -> peD
    float dx = (float)(kk/3 - 1), dy = (float)(kk%3 - 1);
    float* h = (float*)smem;
    float hv = dx*W_p1[t] + dy*W_p1[256 + t] + b_p1[t];
    h[t] = hv > 0.f ? hv : 0.f;
    __syncthreads();
    float acc0 = b_p2[t], acc1 = b_p2[t + 256];
    for (int c = 0; c < 256; c++){
      float hc = h[c];
      acc0 += hc * W_p2[(size_t)c*DD + t];
      acc1 += hc * W_p2[(size_t)c*DD + t + 256];
    }
    peD[(size_t)kk*DD + t]       = f2bf(acc0);
    peD[(size_t)kk*DD + t + 256] = f2bf(acc1);
  } else if (bid < P_R6){
    int i = (bid - P_R5)*256 + t;         // bfq = b_feat@Wq + bq
    float* bfs = (float*)smem;
    bfs[t] = b_feat[t]; bfs[t + 256] = b_feat[t + 256];
    __syncthreads();
    float acc = 0.f;
    for (int k = 0; k < DD; k++) acc += bfs[k] * Wq[(size_t)k*DD + i];
    bfq[i] = acc + bq[i];
  } else if (bid < P_R7){
    int n = (bid - P_R6)*256 + t;         // biaskv = b_feat@[Wk|Wv] + [bk|bv]
    float* bfs = (float*)smem;
    bfs[t] = b_feat[t]; bfs[t + 256] = b_feat[t + 256];
    __syncthreads();
    const float* W = (n < 512) ? Wk : Wv;
    int c = n & 511;
    float acc = 0.f;
    for (int k = 0; k < DD; k++) acc += bfs[k] * W[(size_t)k*DD + c];
    biaskv[n] = acc + ((n < 512) ? bk[c] : bv[c]);
  } else {
    int b = bid - P_R7;                   // rank: cell-id + stable counting sort
    u16 (*hist)[65] = (u16(*)[65])smem;
    int* tot  = (int*)(smem + 33280);
    int* base = (int*)(smem + 33536);
    #pragma unroll
    for (int i = 0; i < 65; i++) hist[t][i] = 0;
    int myc[8];
    float cxy[16];
    load8(coords + (size_t)(b*NPT + t*8)*2,     cxy);
    load8(coords + (size_t)(b*NPT + t*8)*2 + 8, cxy + 8);
    #pragma unroll
    for (int i = 0; i < 8; i++){
      int gx = (int)(cxy[2*i]   * (1.0f/32.0f)); gx = gx < 0 ? 0 : (gx > 7 ? 7 : gx);
      int gy = (int)(cxy[2*i+1] * (1.0f/32.0f)); gy = gy < 0 ? 0 : (gy > 7 ? 7 : gy);
      myc[i] = gx*8 + gy;
      hist[t][myc[i]]++;
    }
    __syncthreads();
    if (t < GG){
      int acc = 0;
      for (int tt = 0; tt < 256; tt++){ int v = hist[tt][t]; hist[tt][t] = (u16)acc; acc += v; }
      tot[t] = acc;
    }
    __syncthreads();
    if (t == 0){
      int acc = 0;
      for (int g = 0; g < GG; g++){ base[g] = acc; acc += tot[g]; }
    }
    __syncthreads();
    if (t < GG){
      counts[b*GG + t] = tot[t];
      cellstart[b*GG + t] = base[t];
    }
    #pragma unroll
    for (int i = 0; i < 8; i++){
      int g = myc[i];
      int local = 0;
      #pragma unroll
      for (int j = 0; j < 8; j++) local += (j < i && myc[j] == g) ? 1 : 0;
      order[b*NPT + base[g] + (int)hist[t][g] + local] = t*8 + i;
    }
  }
}

// ======== 2-phase pipelined GEMM core (shared SMEM buffer) ========
// SMEMB: >= 34816 bytes. lA dbuf [2][4096] u16, lB dbuf [2][4096] u16.
// Leaves acc/m0/n0/lane/lr/lrow/wn/wm/tid in scope. NWGv % 8 == 0.
#define BM 128
#define BN 128
#define GEMM_PIPE(SMEMB, Aptr, Btptr, Kv, GXv, NWGv, UIDX)                         \
  u16* lA_ = (u16*)(SMEMB);                                                        \
  u16* lB_ = (u16*)((char*)(SMEMB) + 16384);                                       \
  int orig_ = (UIDX);                                                              \
  int swz_ = (orig_ & 7)*((NWGv) >> 3) + (orig_ >> 3);                             \
  int m0 = (swz_ / (GXv)) * BM, n0 = (swz_ % (GXv)) * BN;                          \
  int lane = tid & 63;                                                             \
  int wv = tid >> 6;                                                               \
  int wm = (wv >> 1) * 64, wn = (wv & 1) * 64;                                     \
  int lr = lane & 15;                                                              \
  int kg = (lane >> 4) << 3;                                                       \
  f32x4 acc[4][4] = {};                                                            \
  {                                                                                \
    int srow = lane >> 2;                                                          \
    int scol = (lane & 3) << 3;                                                    \
    const u16* gA0 = (Aptr)  + (size_t)(m0 + wv*32 + srow)*(Kv) + scol;            \
    const u16* gB0 = (Btptr) + (size_t)(n0 + wv*32 + srow)*(Kv) + scol;            \
    int lofs = (wv*32)*32;                                                         \
    int steps = (Kv) >> 5;                                                         \
    gload16(gA0,                   lA_ + lofs);                                    \
    gload16(gA0 + (size_t)16*(Kv), lA_ + lofs + 512);                              \
    gload16(gB0,                   lB_ + lofs);                                    \
    gload16(gB0 + (size_t)16*(Kv), lB_ + lofs + 512);                              \
    __syncthreads();                                                               \
    for (int s = 0; s < steps; s++){                                               \
      int cur = s & 1;                                                             \
      u16* lAc = lA_ + cur*4096;                                                   \
      u16* lBc = lB_ + cur*4096;                                                   \
      if (s + 1 < steps){                                                          \
        int kt = (s + 1) << 5;                                                     \
        u16* lAn = lA_ + (cur^1)*4096;                                             \
        u16* lBn = lB_ + (cur^1)*4096;                                             \
        gload16(gA0 + kt,                   lAn + lofs);                           \
        gload16(gA0 + kt + (size_t)16*(Kv), lAn + lofs + 512);                     \
        gload16(gB0 + kt,                   lBn + lofs);                           \
        gload16(gB0 + kt + (size_t)16*(Kv), lBn + lofs + 512);                     \
      }                                                                            \
      bf16x8 af[4], bfv[4];                                                        \
      _Pragma("unroll")                                                            \
      for (int i = 0; i < 4; i++) af[i]  = *(const bf16x8*)&lAc[(wm + i*16 + lr)*32 + kg]; \
      _Pragma("unroll")                                                            \
      for (int j = 0; j < 4; j++) bfv[j] = *(const bf16x8*)&lBc[(wn + j*16 + lr)*32 + kg]; \
      _Pragma("unroll")                                                            \
      for (int i = 0; i < 4; i++)                                                  \
        _Pragma("unroll")                                                          \
        for (int j = 0; j < 4; j++)                                                \
          acc[i][j] = __builtin_amdgcn_mfma_f32_16x16x32_bf16(af[i], bfv[j], acc[i][j], 0, 0, 0); \
      __syncthreads();                                                             \
    }                                                                              \
  }                                                                                \
  int lrow = (lane >> 4) << 2;

// Coalesced bf16 epilogue: acc -> LDS [128][136] (2-way banks) -> 256B-contiguous stores.
#define EPI_BF16(SMEMB, DST, LDN, BIAS)                                            \
  {                                                                                \
    u16* Cs = (u16*)(SMEMB);                                                       \
    _Pragma("unroll")                                                              \
    for (int j = 0; j < 4; j++){                                                   \
      int col = wn + j*16 + lr;                                                    \
      float bcol = (BIAS)[n0 + col];                                               \
      _Pragma("unroll")                                                            \
      for (int i = 0; i < 4; i++){                                                 \
        int r0 = wm + i*16 + lrow;                                                 \
        _Pragma("unroll")                                                          \
        for (int r = 0; r < 4; r++)                                                \
          Cs[(r0 + r)*136 + col] = f2bf(acc[i][j][r] + bcol);                      \
      }                                                                            \
    }                                                                              \
    __syncthreads();                                                               \
    _Pragma("unroll")                                                              \
    for (int k = 0; k < 8; k++){                                                   \
      int idx = k*256 + tid;                                                       \
      int row = idx >> 4, c8 = (idx & 15) << 3;                                    \
      *(uint4*)&(DST)[(size_t)(m0 + row)*(LDN) + n0 + c8] = *(uint4*)&Cs[row*136 + c8]; \
    }                                                                              \
  }

// ========== Launch 2: smallgemm (24) + peKV (36) + meanF gather (512) + feat GEMM (512) ==========
__global__ __launch_bounds__(256) void mid_kernel(
    const u16* __restrict__ WqkvT, const u16* __restrict__ W_feat_bf,
    const u16* __restrict__ peD, u16* __restrict__ Xout, float* __restrict__ meanKV,
    const u16* __restrict__ featA, const int* __restrict__ order,
    const int* __restrict__ counts, const int* __restrict__ cellstart,
    u16* __restrict__ meanF, const u16* __restrict__ WcatT,
    const float* __restrict__ b_feat, u16* __restrict__ feat_bf)
{
  __shared__ __align__(16) char SMEM[34816];
  int tid = threadIdx.x;
  if (blockIdx.x < 24){
    // Xout[1536][256] = [Wq;Wk;Wv]^T @ W_feat^T  (bf16)
    GEMM_PIPE(SMEM, WqkvT, W_feat_bf, 512, 2, 24, (int)blockIdx.x)
    #pragma unroll
    for (int j = 0; j < 4; j++){
      int col = n0 + wn + j*16 + lr;
      #pragma unroll
      for (int i = 0; i < 4; i++){
        int row0 = m0 + wm + i*16 + lrow;
        #pragma unroll
        for (int r = 0; r < 4; r++)
          Xout[(size_t)(row0 + r)*INDIM + col] = f2bf(acc[i][j][r]);
      }
    }
  } else if (blockIdx.x < 60){
    float* pesh = (float*)SMEM;
    int bid2 = blockIdx.x - 24;
    int kk = bid2 >> 2, seg = bid2 & 3;
    int n = seg*256 + tid;
    pesh[tid]       = bf2f(peD[(size_t)kk*DD + tid]);
    pesh[tid + 256] = bf2f(peD[(size_t)kk*DD + tid + 256]);
    __syncthreads();
    const u16* wrow = WqkvT + (size_t)(512 + n)*DD;
    float acc = 0.f;
    for (int d8 = 0; d8 < 64; d8++){
      float w8[8]; load8bf(wrow + d8*8, w8);
      #pragma unroll
      for (int j = 0; j < 8; j++) acc += pesh[d8*8 + j]*w8[j];
    }
    meanKV[(size_t)(512 + kk)*1024 + n] = acc;
  } else if (blockIdx.x < 572){
    float (*part)[2] = (float(*)[2])SMEM;
    int bg = blockIdx.x - 60;             // 0..511
    int b = bg >> 6;
    int p = tid & 127, half = tid >> 7;
    int cnt = counts[bg], start = cellstart[bg];
    const int* ord = order + b*NPT + start;
    float a0 = 0.f, a1 = 0.f;
    for (int n = half; n < cnt; n += 2){
      u32 v = *(const u32*)(featA + (((size_t)(b*NPT + ord[n])) << 8) + p*2);
      a0 += bf2f((u16)v); a1 += bf2f((u16)(v >> 16));
    }
    if (half){ part[p][0] = a0; part[p][1] = a1; }
    __syncthreads();
    if (!half){
      a0 += part[p][0]; a1 += part[p][1];
      float inv = 1.f / (float)(cnt > 0 ? cnt : 1);
      *(u32*)(meanF + (size_t)bg*INDIM + p*2) =
          (u32)f2bf(a0*inv) | ((u32)f2bf(a1*inv) << 16);
    }
  } else {
    // feat = featA @ W_feat^T + b_feat  (M=16384, N=512, K=256)
    GEMM_PIPE(SMEM, featA, WcatT, 256, 4, 512, (int)blockIdx.x - 572)
    EPI_BF16(SMEM, feat_bf, DD, b_feat)
  }
}

// ========== Launch 3: q GEMM (512) + meanKV GEMM (32) = 544 blocks ==========
__global__ __launch_bounds__(256) void qmean_kernel(
    const u16* __restrict__ featA, const u16* __restrict__ WfqT,
    const u16* __restrict__ meanF, const u16* __restrict__ WfkvT,
    const float* __restrict__ bfq, const float* __restrict__ biaskv,
    u16* __restrict__ q_bf, float* __restrict__ meanKV)
{
  __shared__ __align__(16) char SMEM[34816];
  int tid = threadIdx.x;
  if (blockIdx.x < 512){
    // q = featA @ Wfq + bfq  (M=16384, N=512, K=256)
    GEMM_PIPE(SMEM, featA, WfqT, 256, 4, 512, (int)blockIdx.x)
    EPI_BF16(SMEM, q_bf, DD, bfq)
  } else {
    // meanKV rows 0..511 = meanF @ WfkvT^T + biaskv  (M=512, N=1024, K=256)
    GEMM_PIPE(SMEM, meanF, WfkvT, 256, 8, 32, (int)blockIdx.x - 512)
    #pragma unroll
    for (int j = 0; j < 4; j++){
      int col = n0 + wn + j*16 + lr;
      float bcol = biaskv[col];
      #pragma unroll
      for (int i = 0; i < 4; i++){
        int row0 = m0 + wm + i*16 + lrow;
        #pragma unroll
        for (int r = 0; r < 4; r++)
          meanKV[(size_t)(row0 + r)*1024 + col] = acc[i][j][r] + bcol;
      }
    }
  }
}

// ---------------- Launch 4: cell-centric attention: 1 block (1024 thr) per (b,cell) ----------------
__global__ __launch_bounds__(1024) void attn_cells(
    const u16* __restrict__ q, const float* __restrict__ meanKV,
    const int* __restrict__ order, const int* __restrict__ counts,
    const int* __restrict__ cellstart, u16* __restrict__ agg)
{
  int bg = blockIdx.x;            // 0..511
  int b = bg >> 6, c = bg & 63;
  int gx = c >> 3, gy = c & 7;
  __shared__ __align__(16) u16 Kf[9][DD];
  __shared__ __align__(16) u16 Vf[9][DD];
  __shared__ int vrow[9];
  int t = threadIdx.x;
  if (t < 9){
    int dx = t/3 - 1, dy = t%3 - 1;
    int nx = gx + dx, ny = gy + dy;
    int inb = ((unsigned)nx < 8u) && ((unsigned)ny < 8u);
    int row = b*GG + (((nx&7) << 3) | (ny&7));
    vrow[t] = (inb && counts[row] > 0) ? row : -1;
  }
  __syncthreads();
  int d = 2*(t & 255);
  for (int kk = (t >> 8); kk < 9; kk += 4){
    int row = vrow[kk];
    if (row >= 0){
      float2 mk = *(const float2*)&meanKV[(size_t)row*1024 + d];
      float2 pk = *(const float2*)&meanKV[(size_t)(512+kk)*1024 + d];
      float2 mv = *(const float2*)&meanKV[(size_t)row*1024 + 512 + d];
      float2 pv = *(const float2*)&meanKV[(size_t)(512+kk)*1024 + 512 + d];
      *(u32*)&Kf[kk][d] = (u32)f2bf(mk.x+pk.x) | ((u32)f2bf(mk.y+pk.y) << 16);
      *(u32*)&Vf[kk][d] = (u32)f2bf(mv.x+pv.x) | ((u32)f2bf(mv.y+pv.y) << 16);
    }
  }
  __syncthreads();
  int cnt = counts[bg];
  int wv = t >> 6, lane = t & 63;     // wv: 0..15
  const int* ord = order + b*NPT + cellstart[bg];
  for (int i = wv; i < cnt; i += 16){
    size_t p = (size_t)b*NPT + ord[i];
    float qv[8];
    load8bf(q + p*DD + lane*8, qv);
    float s[9];
    #pragma unroll
    for (int kk = 0; kk < 9; kk++){
      float partial = 0.f;
      if (vrow[kk] >= 0){
        float kv[8]; load8bf(&Kf[kk][lane*8], kv);
        #pragma unroll
        for (int j = 0; j < 8; j++) partial += qv[j]*kv[j];
      }
      partial += __shfl_xor(partial, 1);
      partial += __shfl_xor(partial, 2);
      partial += __shfl_xor(partial, 4);
      partial += __shfl_xor(partial, 8);
      s[kk] = (vrow[kk] >= 0) ? partial * 0.08838834764831843f : -1e30f;
    }
    float mx = s[0];
    #pragma unroll
    for (int kk = 1; kk < 9; kk++) mx = fmaxf(mx, s[kk]);
    float w[9], sum = 0.f;
    #pragma unroll
    for (int kk = 0; kk < 9; kk++){
      w[kk] = (vrow[kk] >= 0) ? __expf(s[kk] - mx) : 0.f;
      sum += w[kk];
    }
    float inv = 1.f / sum;
    float a[8] = {0,0,0,0,0,0,0,0};
    #pragma unroll
    for (int kk = 0; kk < 9; kk++){
      if (vrow[kk] >= 0){
        float wk = w[kk] * inv;
        float vv[8]; load8bf(&Vf[kk][lane*8], vv);
        #pragma unroll
        for (int j = 0; j < 8; j++) a[j] += wk*vv[j];
      }
    }
    *(uint4*)&agg[p*DD + lane*8] = pack8(a);
  }
}

// ---------------- Launch 5: lin = agg @ Wo + bo ----------------
__global__ __launch_bounds__(256) void lin_kernel(
    const u16* __restrict__ agg_bf, const u16* __restrict__ WoT,
    const float* __restrict__ bo, u16* __restrict__ lin_bf)
{
  __shared__ __align__(16) char SMEM[34816];
  int tid = threadIdx.x;
  GEMM_PIPE(SMEM, agg_bf, WoT, 512, 4, 512, (int)blockIdx.x)
  EPI_BF16(SMEM, lin_bf, DD, bo)
}

// ---------------- Launch 6: residual + layernorm ----------------
__global__ __launch_bounds__(256) void ln_kernel(
    const u16* __restrict__ feat, const u16* __restrict__ lin,
    const float* __restrict__ gamma, const float* __restrict__ beta,
    float* __restrict__ out)
{
  int wv = threadIdx.x >> 6, lane = threadIdx.x & 63;
  size_t r = (size_t)blockIdx.x * 4 + wv;
  int d0 = lane * 8;
  float fv[8], lv[8];
  load8bf(feat + r*DD + d0, fv);
  load8bf(lin  + r*DD + d0, lv);
  float e[8], s1 = 0.f, s2 = 0.f;
  #pragma unroll
  for (int j = 0; j < 8; j++){ e[j] = fv[j] + lv[j]; s1 += e[j]; s2 += e[j]*e[j]; }
  #pragma unroll
  for (int m = 1; m < 64; m <<= 1){ s1 += __shfl_xor(s1, m); s2 += __shfl_xor(s2, m); }
  float mu  = s1 * (1.f/512.f);
  float var = s2 * (1.f/512.f) - mu*mu;
  float istd = rsqrtf(var + 1e-5f);
  float gv[8], bev[8];
  load8(gamma + d0, gv); load8(beta + d0, bev);
  float o[8];
  #pragma unroll
  for (int j = 0; j < 8; j++) o[j] = (e[j] - mu)*istd*gv[j] + bev[j];
  store8(out + r*DD + d0, o);
}

extern "C" void kernel_launch(void* const* d_in, const int* in_sizes, int n_in,
                              void* d_out, int out_size, void* d_ws, size_t ws_size,
                              hipStream_t stream) {
  (void)in_sizes; (void)n_in; (void)out_size; (void)ws_size;
  const float* features = (const float*)d_in[0];
  const float* coords   = (const float*)d_in[1];
  const float* W_feat   = (const float*)d_in[2];
  const float* b_feat   = (const float*)d_in[3];
  const float* W_p1     = (const float*)d_in[4];
  const float* b_p1     = (const float*)d_in[5];
  const float* W_p2     = (const float*)d_in[6];
  const float* b_p2     = (const float*)d_in[7];
  const float* Wq = (const float*)d_in[8];  const float* bq = (const float*)d_in[9];
  const float* Wk = (const float*)d_in[10]; const float* bk = (const float*)d_in[11];
  const float* Wv = (const float*)d_in[12]; const float* bv = (const float*)d_in[13];
  const float* Wo = (const float*)d_in[14]; const float* bo = (const float*)d_in[15];
  const float* gamma = (const float*)d_in[16]; const float* beta = (const float*)d_in[17];
  float* out = (float*)d_out;

  char* ws = (char*)d_ws;
  size_t off = 0;
  auto alloc = [&](size_t bytes) -> void* {
    void* p = ws + off;
    off = (off + bytes + 255) & ~(size_t)255;
    return p;
  };
  u16*   featA     = (u16*)  alloc((size_t)NPTS*INDIM*2);   // 8.4 MB
  u16*   feat_bf   = (u16*)  alloc((size_t)NPTS*DD*2);      // 16.8 MB
  u16*   q_bf      = (u16*)  alloc((size_t)NPTS*DD*2);      // 16.8 MB
  u16*   agg_bf    = (u16*)  alloc((size_t)NPTS*DD*2);      // 16.8 MB
  u16*   lin_bf    = (u16*)  alloc((size_t)NPTS*DD*2);      // 16.8 MB
  u16*   W_feat_bf = (u16*)  alloc((size_t)INDIM*DD*2);     // [256][512]
  u16*   WqkvT     = (u16*)  alloc((size_t)1536*DD*2);      // [Wq^T;Wk^T;Wv^T]
  u16*   WoT       = (u16*)  alloc((size_t)DD*DD*2);
  u16*   WcatT     = (u16*)  alloc((size_t)512*INDIM*2);    // W_feat^T [512][256]
  u16*   Xout      = (u16*)  alloc((size_t)1536*INDIM*2);   // [WfqT(512); WfkvT(1024)][256]
  u16*   peD       = (u16*)  alloc((size_t)9*DD*2);
  u16*   meanF     = (u16*)  alloc((size_t)512*INDIM*2);
  float* meanKV    = (float*)alloc((size_t)640*1024*4);     // rows 0..511 mean-derived, 512..520 pe
  float* bfq       = (float*)alloc((size_t)DD*4);
  float* biaskv    = (float*)alloc((size_t)1024*4);
  int*   order     = (int*)  alloc((size_t)NPTS*4);
  int*   counts    = (int*)  alloc((size_t)NBATCH*GG*4);
  int*   cellstart = (int*)  alloc((size_t)NBATCH*GG*4);
  u16*   WfqT      = Xout;                                  // [512][256]
  u16*   WfkvT     = Xout + (size_t)512*INDIM;              // [1024][256]

  // 1. mega-prep (+rank)
  prep_kernel<<<P_NB, 256, 0, stream>>>(
      features, W_feat, Wq, Wk, Wv, Wo, W_p1, b_p1, W_p2, b_p2,
      b_feat, bq, bk, bv, coords,
      featA, W_feat_bf, WqkvT, WoT, WcatT, peD, bfq, biaskv,
      order, counts, cellstart);
  // 2. [WfqT;WfkvT] GEMM + peKV rows + meanF gather + feat GEMM
  mid_kernel<<<1084, 256, 0, stream>>>(
      WqkvT, W_feat_bf, peD, Xout, meanKV, featA, order, counts, cellstart,
      meanF, WcatT, b_feat, feat_bf);
  // 3. q GEMM + meanKV rows 0..511 GEMM
  qmean_kernel<<<544, 256, 0, stream>>>(
      featA, WfqT, meanF, WfkvT, bfq, biaskv, q_bf, meanKV);
  // 4. cell-centric attention -> agg
  attn_cells<<<NBATCH*GG, 1024, 0, stream>>>(q_bf, meanKV, order, counts, cellstart, agg_bf);
  // 5. lin = agg @ Wo + bo
  lin_kernel<<<512, 256, 0, stream>>>(agg_bf, WoT, bo, lin_bf);
  // 6. out = LN(feat + lin) * gamma + beta
  ln_kernel<<<NPTS/4, 256, 0, stream>>>(feat_bf, lin_bf, gamma, beta, out);
}

// Round 11
// 102.040 us; speedup vs baseline: 3.0047x; 1.0078x over previous
//
#include <hip/hip_runtime.h>
#include <stdint.h>

typedef unsigned short u16;
typedef unsigned int u32;
typedef __bf16 bf16x8 __attribute__((ext_vector_type(8)));
typedef float f32x4 __attribute__((ext_vector_type(4)));

#define NBATCH 8
#define NPT    2048
#define NPTS   16384     // NBATCH*NPT
#define INDIM  256
#define DD     512
#define GG     64        // 8x8 grid cells

__device__ __forceinline__ u16 f2bf(float f){
  u32 u = __builtin_bit_cast(u32, f);
  u += 0x7fffu + ((u >> 16) & 1u);
  return (u16)(u >> 16);
}
__device__ __forceinline__ float bf2f(u16 h){
  u32 u = ((u32)h) << 16;
  return __builtin_bit_cast(float, u);
}
__device__ __forceinline__ void load8(const float* __restrict__ p, float* r){
  float4 a = *(const float4*)p;
  float4 b = *(const float4*)(p + 4);
  r[0]=a.x;r[1]=a.y;r[2]=a.z;r[3]=a.w;r[4]=b.x;r[5]=b.y;r[6]=b.z;r[7]=b.w;
}
__device__ __forceinline__ void load8bf(const u16* __restrict__ p, float* r){
  uint4 v = *(const uint4*)p;
  r[0]=bf2f((u16)v.x); r[1]=bf2f((u16)(v.x>>16));
  r[2]=bf2f((u16)v.y); r[3]=bf2f((u16)(v.y>>16));
  r[4]=bf2f((u16)v.z); r[5]=bf2f((u16)(v.z>>16));
  r[6]=bf2f((u16)v.w); r[7]=bf2f((u16)(v.w>>16));
}
__device__ __forceinline__ void load8bf_lds(const u16* p, float* r){
  uint4 v = *(const uint4*)p;
  r[0]=bf2f((u16)v.x); r[1]=bf2f((u16)(v.x>>16));
  r[2]=bf2f((u16)v.y); r[3]=bf2f((u16)(v.y>>16));
  r[4]=bf2f((u16)v.z); r[5]=bf2f((u16)(v.z>>16));
  r[6]=bf2f((u16)v.w); r[7]=bf2f((u16)(v.w>>16));
}
__device__ __forceinline__ void store8(float* __restrict__ p, const float* r){
  float4 a; a.x=r[0];a.y=r[1];a.z=r[2];a.w=r[3];
  float4 b; b.x=r[4];b.y=r[5];b.z=r[6];b.w=r[7];
  *(float4*)p = a; *(float4*)(p+4) = b;
}
__device__ __forceinline__ uint4 pack8(const float* a){
  uint4 pk;
  pk.x = (u32)f2bf(a[0]) | ((u32)f2bf(a[1]) << 16);
  pk.y = (u32)f2bf(a[2]) | ((u32)f2bf(a[3]) << 16);
  pk.z = (u32)f2bf(a[4]) | ((u32)f2bf(a[5]) << 16);
  pk.w = (u32)f2bf(a[6]) | ((u32)f2bf(a[7]) << 16);
  return pk;
}
typedef __attribute__((address_space(1))) unsigned as1u;
typedef __attribute__((address_space(3))) unsigned as3u;
__device__ __forceinline__ void gload16(const void* g, void* l){
  __builtin_amdgcn_global_load_lds((as1u*)(uintptr_t)g, (as3u*)(uintptr_t)l, 16, 0, 0);
}

// ---- 64x64 LDS-tiled transpose: src f32[*][scols] -> dst bf16[*][dcols] ----
__device__ __forceinline__ void transpose64(const float* __restrict__ src, int scols,
                                            u16* __restrict__ dst, int dcols,
                                            int r0, int c0, char* smem, int t){
  float (*sh)[65] = (float(*)[65])smem;
  #pragma unroll
  for (int i = 0; i < 16; i++){
    int idx = i*256 + t;
    int r = idx >> 6, c = idx & 63;
    sh[r][c] = src[(size_t)(r0 + r)*scols + c0 + c];
  }
  __syncthreads();
  #pragma unroll
  for (int i = 0; i < 8; i++){
    int idx = i*512 + t*2;
    int oR = idx >> 6, oC = idx & 63;
    u32 pk = (u32)f2bf(sh[oC][oR]) | ((u32)f2bf(sh[oC+1][oR]) << 16);
    *(u32*)(dst + (size_t)(c0 + oR)*dcols + r0 + oC) = pk;
  }
}

// ================= Launch 1: mega-prep (all independent preprocessing + rank) =================
#define P_R1 2048
#define P_R2 2112
#define P_R3 2368
#define P_R4 2400
#define P_R5 2409
#define P_R6 2411
#define P_R7 2415
#define P_NB 2423
__global__ __launch_bounds__(256) void prep_kernel(
    const float* __restrict__ features, const float* __restrict__ W_feat,
    const float* __restrict__ Wq, const float* __restrict__ Wk,
    const float* __restrict__ Wv, const float* __restrict__ Wo,
    const float* __restrict__ W_p1, const float* __restrict__ b_p1,
    const float* __restrict__ W_p2, const float* __restrict__ b_p2,
    const float* __restrict__ b_feat, const float* __restrict__ bq,
    const float* __restrict__ bk, const float* __restrict__ bv,
    const float* __restrict__ coords,
    u16* __restrict__ featA, u16* __restrict__ W_feat_bf,
    u16* __restrict__ WqkvT, u16* __restrict__ WoT, u16* __restrict__ WcatT,
    u16* __restrict__ peD, float* __restrict__ bfq, float* __restrict__ biaskv,
    int* __restrict__ order, int* __restrict__ counts, int* __restrict__ cellstart)
{
  __shared__ __align__(16) char smem[34048];
  int bid = blockIdx.x, t = threadIdx.x;
  if (bid < P_R1){
    int i = bid*256 + t;
    float r[8]; load8(features + (size_t)i*8, r);
    *(uint4*)(featA + (size_t)i*8) = pack8(r);
  } else if (bid < P_R2){
    int i = (bid - P_R1)*256 + t;
    float r[8]; load8(W_feat + (size_t)i*8, r);
    *(uint4*)(W_feat_bf + (size_t)i*8) = pack8(r);
  } else if (bid < P_R3){
    int rel = bid - P_R2;
    int mat = rel >> 6, tile = rel & 63;
    int r0 = (tile >> 3)*64, c0 = (tile & 7)*64;
    const float* src = mat==0 ? Wq : (mat==1 ? Wk : (mat==2 ? Wv : Wo));
    u16* dst = mat==0 ? WqkvT : (mat==1 ? WqkvT + (size_t)512*DD
                     : (mat==2 ? WqkvT + (size_t)1024*DD : WoT));
    transpose64(src, DD, dst, DD, r0, c0, smem, t);
  } else if (bid < P_R4){
    int rel = bid - P_R3;                 // W_feat [256][512] -> WcatT [512][256]
    int r0 = (rel >> 3)*64, c0 = (rel & 7)*64;
    transpose64(W_feat, DD, WcatT, INDIM, r0, c0, smem, t);
  } else if (bid < P_R5){
    int kk = bid - P_R4;                  // pos-enc MLP -> peD
    float dx = (float)(kk/3 - 1), dy = (float)(kk%3 - 1);
    float* h = (float*)smem;
    float hv = dx*W_p1[t] + dy*W_p1[256 + t] + b_p1[t];
    h[t] = hv > 0.f ? hv : 0.f;
    __syncthreads();
    float acc0 = b_p2[t], acc1 = b_p2[t + 256];
    for (int c = 0; c < 256; c++){
      float hc = h[c];
      acc0 += hc * W_p2[(size_t)c*DD + t];
      acc1 += hc * W_p2[(size_t)c*DD + t + 256];
    }
    peD[(size_t)kk*DD + t]       = f2bf(acc0);
    peD[(size_t)kk*DD + t + 256] = f2bf(acc1);
  } else if (bid < P_R6){
    int i = (bid - P_R5)*256 + t;         // bfq = b_feat@Wq + bq
    float* bfs = (float*)smem;
    bfs[t] = b_feat[t]; bfs[t + 256] = b_feat[t + 256];
    __syncthreads();
    float acc = 0.f;
    for (int k = 0; k < DD; k++) acc += bfs[k] * Wq[(size_t)k*DD + i];
    bfq[i] = acc + bq[i];
  } else if (bid < P_R7){
    int n = (bid - P_R6)*256 + t;         // biaskv = b_feat@[Wk|Wv] + [bk|bv]
    float* bfs = (float*)smem;
    bfs[t] = b_feat[t]; bfs[t + 256] = b_feat[t + 256];
    __syncthreads();
    const float* W = (n < 512) ? Wk : Wv;
    int c = n & 511;
    float acc = 0.f;
    for (int k = 0; k < DD; k++) acc += bfs[k] * W[(size_t)k*DD + c];
    biaskv[n] = acc + ((n < 512) ? bk[c] : bv[c]);
  } else {
    int b = bid - P_R7;                   // rank: cell-id + stable counting sort
    u16 (*hist)[65] = (u16(*)[65])smem;
    int* tot  = (int*)(smem + 33280);
    int* base = (int*)(smem + 33536);
    #pragma unroll
    for (int i = 0; i < 65; i++) hist[t][i] = 0;
    int myc[8];
    float cxy[16];
    load8(coords + (size_t)(b*NPT + t*8)*2,     cxy);
    load8(coords + (size_t)(b*NPT + t*8)*2 + 8, cxy + 8);
    #pragma unroll
    for (int i = 0; i < 8; i++){
      int gx = (int)(cxy[2*i]   * (1.0f/32.0f)); gx = gx < 0 ? 0 : (gx > 7 ? 7 : gx);
      int gy = (int)(cxy[2*i+1] * (1.0f/32.0f)); gy = gy < 0 ? 0 : (gy > 7 ? 7 : gy);
      myc[i] = gx*8 + gy;
      hist[t][myc[i]]++;
    }
    __syncthreads();
    if (t < GG){
      int acc = 0;
      for (int tt = 0; tt < 256; tt++){ int v = hist[tt][t]; hist[tt][t] = (u16)acc; acc += v; }
      tot[t] = acc;
    }
    __syncthreads();
    if (t == 0){
      int acc = 0;
      for (int g = 0; g < GG; g++){ base[g] = acc; acc += tot[g]; }
    }
    __syncthreads();
    if (t < GG){
      counts[b*GG + t] = tot[t];
      cellstart[b*GG + t] = base[t];
    }
    #pragma unroll
    for (int i = 0; i < 8; i++){
      int g = myc[i];
      int local = 0;
      #pragma unroll
      for (int j = 0; j < 8; j++) local += (j < i && myc[j] == g) ? 1 : 0;
      order[b*NPT + base[g] + (int)hist[t][g] + local] = t*8 + i;
    }
  }
}

// ======== 2-phase pipelined GEMM core (shared SMEM buffer) ========
// SMEMB: >= 34816 bytes. lA dbuf [2][4096] u16, lB dbuf [2][4096] u16.
// Leaves acc/m0/n0/lane/lr/lrow/wn/wm/tid in scope. NWGv % 8 == 0.
#define BM 128
#define BN 128
#define GEMM_PIPE(SMEMB, Aptr, Btptr, Kv, GXv, NWGv, UIDX)                         \
  u16* lA_ = (u16*)(SMEMB);                                                        \
  u16* lB_ = (u16*)((char*)(SMEMB) + 16384);                                       \
  int orig_ = (UIDX);                                                              \
  int swz_ = (orig_ & 7)*((NWGv) >> 3) + (orig_ >> 3);                             \
  int m0 = (swz_ / (GXv)) * BM, n0 = (swz_ % (GXv)) * BN;                          \
  int lane = tid & 63;                                                             \
  int wv = tid >> 6;                                                               \
  int wm = (wv >> 1) * 64, wn = (wv & 1) * 64;                                     \
  int lr = lane & 15;                                                              \
  int kg = (lane >> 4) << 3;                                                       \
  f32x4 acc[4][4] = {};                                                            \
  {                                                                                \
    int srow = lane >> 2;                                                          \
    int scol = (lane & 3) << 3;                                                    \
    const u16* gA0 = (Aptr)  + (size_t)(m0 + wv*32 + srow)*(Kv) + scol;            \
    const u16* gB0 = (Btptr) + (size_t)(n0 + wv*32 + srow)*(Kv) + scol;            \
    int lofs = (wv*32)*32;                                                         \
    int steps = (Kv) >> 5;                                                         \
    gload16(gA0,                   lA_ + lofs);                                    \
    gload16(gA0 + (size_t)16*(Kv), lA_ + lofs + 512);                              \
    gload16(gB0,                   lB_ + lofs);                                    \
    gload16(gB0 + (size_t)16*(Kv), lB_ + lofs + 512);                              \
    __syncthreads();                                                               \
    for (int s = 0; s < steps; s++){                                               \
      int cur = s & 1;                                                             \
      u16* lAc = lA_ + cur*4096;                                                   \
      u16* lBc = lB_ + cur*4096;                                                   \
      if (s + 1 < steps){                                                          \
        int kt = (s + 1) << 5;                                                     \
        u16* lAn = lA_ + (cur^1)*4096;                                             \
        u16* lBn = lB_ + (cur^1)*4096;                                             \
        gload16(gA0 + kt,                   lAn + lofs);                           \
        gload16(gA0 + kt + (size_t)16*(Kv), lAn + lofs + 512);                     \
        gload16(gB0 + kt,                   lBn + lofs);                           \
        gload16(gB0 + kt + (size_t)16*(Kv), lBn + lofs + 512);                     \
      }                                                                            \
      bf16x8 af[4], bfv[4];                                                        \
      _Pragma("unroll")                                                            \
      for (int i = 0; i < 4; i++) af[i]  = *(const bf16x8*)&lAc[(wm + i*16 + lr)*32 + kg]; \
      _Pragma("unroll")                                                            \
      for (int j = 0; j < 4; j++) bfv[j] = *(const bf16x8*)&lBc[(wn + j*16 + lr)*32 + kg]; \
      _Pragma("unroll")                                                            \
      for (int i = 0; i < 4; i++)                                                  \
        _Pragma("unroll")                                                          \
        for (int j = 0; j < 4; j++)                                                \
          acc[i][j] = __builtin_amdgcn_mfma_f32_16x16x32_bf16(af[i], bfv[j], acc[i][j], 0, 0, 0); \
      __syncthreads();                                                             \
    }                                                                              \
  }                                                                                \
  int lrow = (lane >> 4) << 2;

// Coalesced bf16 epilogue: acc -> LDS [128][136] (2-way banks) -> 256B-contiguous stores.
#define EPI_BF16(SMEMB, DST, LDN, BIAS)                                            \
  {                                                                                \
    u16* Cs = (u16*)(SMEMB);                                                       \
    _Pragma("unroll")                                                              \
    for (int j = 0; j < 4; j++){                                                   \
      int col = wn + j*16 + lr;                                                    \
      float bcol = (BIAS)[n0 + col];                                               \
      _Pragma("unroll")                                                            \
      for (int i = 0; i < 4; i++){                                                 \
        int r0 = wm + i*16 + lrow;                                                 \
        _Pragma("unroll")                                                          \
        for (int r = 0; r < 4; r++)                                                \
          Cs[(r0 + r)*136 + col] = f2bf(acc[i][j][r] + bcol);                      \
      }                                                                            \
    }                                                                              \
    __syncthreads();                                                               \
    _Pragma("unroll")                                                              \
    for (int k = 0; k < 8; k++){                                                   \
      int idx = k*256 + tid;                                                       \
      int row = idx >> 4, c8 = (idx & 15) << 3;                                    \
      *(uint4*)&(DST)[(size_t)(m0 + row)*(LDN) + n0 + c8] = *(uint4*)&Cs[row*136 + c8]; \
    }                                                                              \
  }

// ========== Launch 2: smallgemm (24) + peKV (36) + meanF gather (512) + feat GEMM (512) ==========
__global__ __launch_bounds__(256) void mid_kernel(
    const u16* __restrict__ WqkvT, const u16* __restrict__ W_feat_bf,
    const u16* __restrict__ peD, u16* __restrict__ Xout, float* __restrict__ meanKV,
    const u16* __restrict__ featA, const int* __restrict__ order,
    const int* __restrict__ counts, const int* __restrict__ cellstart,
    u16* __restrict__ meanF, const u16* __restrict__ WcatT,
    const float* __restrict__ b_feat, u16* __restrict__ feat_bf)
{
  __shared__ __align__(16) char SMEM[34816];
  int tid = threadIdx.x;
  if (blockIdx.x < 24){
    // Xout[1536][256] = [Wq;Wk;Wv]^T @ W_feat^T  (bf16)
    GEMM_PIPE(SMEM, WqkvT, W_feat_bf, 512, 2, 24, (int)blockIdx.x)
    #pragma unroll
    for (int j = 0; j < 4; j++){
      int col = n0 + wn + j*16 + lr;
      #pragma unroll
      for (int i = 0; i < 4; i++){
        int row0 = m0 + wm + i*16 + lrow;
        #pragma unroll
        for (int r = 0; r < 4; r++)
          Xout[(size_t)(row0 + r)*INDIM + col] = f2bf(acc[i][j][r]);
      }
    }
  } else if (blockIdx.x < 60){
    float* pesh = (float*)SMEM;
    int bid2 = blockIdx.x - 24;
    int kk = bid2 >> 2, seg = bid2 & 3;
    int n = seg*256 + tid;
    pesh[tid]       = bf2f(peD[(size_t)kk*DD + tid]);
    pesh[tid + 256] = bf2f(peD[(size_t)kk*DD + tid + 256]);
    __syncthreads();
    const u16* wrow = WqkvT + (size_t)(512 + n)*DD;
    float acc = 0.f;
    for (int d8 = 0; d8 < 64; d8++){
      float w8[8]; load8bf(wrow + d8*8, w8);
      #pragma unroll
      for (int j = 0; j < 8; j++) acc += pesh[d8*8 + j]*w8[j];
    }
    meanKV[(size_t)(512 + kk)*1024 + n] = acc;
  } else if (blockIdx.x < 572){
    float (*part)[2] = (float(*)[2])SMEM;
    int bg = blockIdx.x - 60;             // 0..511
    int b = bg >> 6;
    int p = tid & 127, half = tid >> 7;
    int cnt = counts[bg], start = cellstart[bg];
    const int* ord = order + b*NPT + start;
    float a0 = 0.f, a1 = 0.f;
    for (int n = half; n < cnt; n += 2){
      u32 v = *(const u32*)(featA + (((size_t)(b*NPT + ord[n])) << 8) + p*2);
      a0 += bf2f((u16)v); a1 += bf2f((u16)(v >> 16));
    }
    if (half){ part[p][0] = a0; part[p][1] = a1; }
    __syncthreads();
    if (!half){
      a0 += part[p][0]; a1 += part[p][1];
      float inv = 1.f / (float)(cnt > 0 ? cnt : 1);
      *(u32*)(meanF + (size_t)bg*INDIM + p*2) =
          (u32)f2bf(a0*inv) | ((u32)f2bf(a1*inv) << 16);
    }
  } else {
    // feat = featA @ W_feat^T + b_feat  (M=16384, N=512, K=256)
    GEMM_PIPE(SMEM, featA, WcatT, 256, 4, 512, (int)blockIdx.x - 572)
    EPI_BF16(SMEM, feat_bf, DD, b_feat)
  }
}

// ========== Launch 3: q GEMM (512) + meanKV GEMM (32) = 544 blocks ==========
__global__ __launch_bounds__(256) void qmean_kernel(
    const u16* __restrict__ featA, const u16* __restrict__ WfqT,
    const u16* __restrict__ meanF, const u16* __restrict__ WfkvT,
    const float* __restrict__ bfq, const float* __restrict__ biaskv,
    u16* __restrict__ q_bf, float* __restrict__ meanKV)
{
  __shared__ __align__(16) char SMEM[34816];
  int tid = threadIdx.x;
  if (blockIdx.x < 512){
    // q = featA @ Wfq + bfq  (M=16384, N=512, K=256)
    GEMM_PIPE(SMEM, featA, WfqT, 256, 4, 512, (int)blockIdx.x)
    EPI_BF16(SMEM, q_bf, DD, bfq)
  } else {
    // meanKV rows 0..511 = meanF @ WfkvT^T + biaskv  (M=512, N=1024, K=256)
    GEMM_PIPE(SMEM, meanF, WfkvT, 256, 8, 32, (int)blockIdx.x - 512)
    #pragma unroll
    for (int j = 0; j < 4; j++){
      int col = n0 + wn + j*16 + lr;
      float bcol = biaskv[col];
      #pragma unroll
      for (int i = 0; i < 4; i++){
        int row0 = m0 + wm + i*16 + lrow;
        #pragma unroll
        for (int r = 0; r < 4; r++)
          meanKV[(size_t)(row0 + r)*1024 + col] = acc[i][j][r] + bcol;
      }
    }
  }
}

// ---------------- Launch 4: cell-centric attention: 1 block (1024 thr) per (b,cell) ----------------
__global__ __launch_bounds__(1024) void attn_cells(
    const u16* __restrict__ q, const float* __restrict__ meanKV,
    const int* __restrict__ order, const int* __restrict__ counts,
    const int* __restrict__ cellstart, u16* __restrict__ agg)
{
  int bg = blockIdx.x;            // 0..511
  int b = bg >> 6, c = bg & 63;
  int gx = c >> 3, gy = c & 7;
  __shared__ __align__(16) u16 Kf[9][DD];
  __shared__ __align__(16) u16 Vf[9][DD];
  __shared__ int vrow[9];
  int t = threadIdx.x;
  if (t < 9){
    int dx = t/3 - 1, dy = t%3 - 1;
    int nx = gx + dx, ny = gy + dy;
    int inb = ((unsigned)nx < 8u) && ((unsigned)ny < 8u);
    int row = b*GG + (((nx&7) << 3) | (ny&7));
    vrow[t] = (inb && counts[row] > 0) ? row : -1;
  }
  __syncthreads();
  int d = 2*(t & 255);
  for (int kk = (t >> 8); kk < 9; kk += 4){
    int row = vrow[kk];
    if (row >= 0){
      float2 mk = *(const float2*)&meanKV[(size_t)row*1024 + d];
      float2 pk = *(const float2*)&meanKV[(size_t)(512+kk)*1024 + d];
      float2 mv = *(const float2*)&meanKV[(size_t)row*1024 + 512 + d];
      float2 pv = *(const float2*)&meanKV[(size_t)(512+kk)*1024 + 512 + d];
      *(u32*)&Kf[kk][d] = (u32)f2bf(mk.x+pk.x) | ((u32)f2bf(mk.y+pk.y) << 16);
      *(u32*)&Vf[kk][d] = (u32)f2bf(mv.x+pv.x) | ((u32)f2bf(mv.y+pv.y) << 16);
    }
  }
  __syncthreads();
  int cnt = counts[bg];
  int wv = t >> 6, lane = t & 63;     // wv: 0..15
  const int* ord = order + b*NPT + cellstart[bg];
  for (int i = wv; i < cnt; i += 16){
    size_t p = (size_t)b*NPT + ord[i];
    float qv[8];
    load8bf(q + p*DD + lane*8, qv);
    float s[9];
    #pragma unroll
    for (int kk = 0; kk < 9; kk++){
      float partial = 0.f;
      if (vrow[kk] >= 0){
        float kv[8]; load8bf(&Kf[kk][lane*8], kv);
        #pragma unroll
        for (int j = 0; j < 8; j++) partial += qv[j]*kv[j];
      }
      partial += __shfl_xor(partial, 1);
      partial += __shfl_xor(partial, 2);
      partial += __shfl_xor(partial, 4);
      partial += __shfl_xor(partial, 8);
      s[kk] = (vrow[kk] >= 0) ? partial * 0.08838834764831843f : -1e30f;
    }
    float mx = s[0];
    #pragma unroll
    for (int kk = 1; kk < 9; kk++) mx = fmaxf(mx, s[kk]);
    float w[9], sum = 0.f;
    #pragma unroll
    for (int kk = 0; kk < 9; kk++){
      w[kk] = (vrow[kk] >= 0) ? __expf(s[kk] - mx) : 0.f;
      sum += w[kk];
    }
    float inv = 1.f / sum;
    float a[8] = {0,0,0,0,0,0,0,0};
    #pragma unroll
    for (int kk = 0; kk < 9; kk++){
      if (vrow[kk] >= 0){
        float wk = w[kk] * inv;
        float vv[8]; load8bf(&Vf[kk][lane*8], vv);
        #pragma unroll
        for (int j = 0; j < 8; j++) a[j] += wk*vv[j];
      }
    }
    *(uint4*)&agg[p*DD + lane*8] = pack8(a);
  }
}

// ========== Launch 5: fused lin+LN. BM=64 x BN=512 (full row), 8 waves, 2-phase pipe ==========
// out = LN(feat + (agg @ Wo + bo)) * gamma + beta
__global__ __launch_bounds__(512) void linln_kernel(
    const u16* __restrict__ agg_bf, const u16* __restrict__ WoT,
    const float* __restrict__ bo, const u16* __restrict__ feat_bf,
    const float* __restrict__ gamma, const float* __restrict__ beta,
    float* __restrict__ out)
{
  __shared__ __align__(16) char SMEM[73728];   // lA dbuf 8KB | lB dbuf 64KB; epilogue reuses
  u16* lA = (u16*)SMEM;                        // [2][2048] u16
  u16* lB = (u16*)(SMEM + 8192);               // [2][16384] u16
  int tid = threadIdx.x;
  int lane = tid & 63;
  int wvv = tid >> 6;                          // 0..7
  int m0 = blockIdx.x * 64;
  int wm2 = (wvv >> 2) * 32;                   // 0 / 32
  int wn2 = (wvv & 3) * 128;                   // 0..384
  int lr = lane & 15;
  int kg = (lane >> 4) << 3;
  int srow = lane >> 2;
  int scol = (lane & 3) << 3;
  f32x4 acc[2][8] = {};
  {
    const u16* gB0 = WoT + (size_t)(wvv*64 + srow)*DD + scol;   // wave stages B rows [wvv*64, +64)
    int lBoff = (wvv*64)*32;
    const u16* gA0 = agg_bf + (size_t)(m0 + (wvv&3)*16 + srow)*DD + scol;
    int lAoff = ((wvv&3)*16)*32;
    bool doA = (wvv < 4);
    // prologue: stage buf0
    #pragma unroll
    for (int c = 0; c < 4; c++)
      gload16(gB0 + (size_t)(c*16)*DD, lB + lBoff + c*16*32);
    if (doA) gload16(gA0, lA + lAoff);
    __syncthreads();
    for (int s = 0; s < 16; s++){
      int cur = s & 1;
      u16* lAc = lA + cur*2048;
      u16* lBc = lB + cur*16384;
      if (s + 1 < 16){
        int kt = (s + 1) << 5;
        u16* lAn = lA + (cur^1)*2048;
        u16* lBn = lB + (cur^1)*16384;
        #pragma unroll
        for (int c = 0; c < 4; c++)
          gload16(gB0 + kt + (size_t)(c*16)*DD, lBn + lBoff + c*16*32);
        if (doA) gload16(gA0 + kt, lAn + lAoff);
      }
      bf16x8 af[2], bfv[8];
      #pragma unroll
      for (int i = 0; i < 2; i++) af[i]  = *(const bf16x8*)&lAc[(wm2 + i*16 + lr)*32 + kg];
      #pragma unroll
      for (int j = 0; j < 8; j++) bfv[j] = *(const bf16x8*)&lBc[(wn2 + j*16 + lr)*32 + kg];
      #pragma unroll
      for (int i = 0; i < 2; i++)
        #pragma unroll
        for (int j = 0; j < 8; j++)
          acc[i][j] = __builtin_amdgcn_mfma_f32_16x16x32_bf16(af[i], bfv[j], acc[i][j], 0, 0, 0);
      __syncthreads();
    }
  }
  // epilogue: acc + bo -> LDS bf16 [64][520] (same rounding as old lin_bf)
  int lrow = (lane >> 4) << 2;
  u16* Cs = (u16*)SMEM;                        // 64*520*2 = 66560 <= 73728
  #pragma unroll
  for (int j = 0; j < 8; j++){
    int col = wn2 + j*16 + lr;
    float bcol = bo[col];
    #pragma unroll
    for (int i = 0; i < 2; i++){
      int r0 = wm2 + i*16 + lrow;
      #pragma unroll
      for (int r = 0; r < 4; r++)
        Cs[(r0 + r)*520 + col] = f2bf(acc[i][j][r] + bcol);
    }
  }
  __syncthreads();
  // LN: wave wvv handles rows [wvv*8, +8); identical reduction order to old ln_kernel
  float gv[8], bev[8];
  load8(gamma + lane*8, gv);
  load8(beta + lane*8, bev);
  for (int rr = 0; rr < 8; rr++){
    int row = wvv*8 + rr;
    float lv[8], fv[8];
    load8bf_lds(&Cs[row*520 + lane*8], lv);
    load8bf(feat_bf + (size_t)(m0 + row)*DD + lane*8, fv);
    float e[8], s1 = 0.f, s2 = 0.f;
    #pragma unroll
    for (int j = 0; j < 8; j++){ e[j] = fv[j] + lv[j]; s1 += e[j]; s2 += e[j]*e[j]; }
    #pragma unroll
    for (int m = 1; m < 64; m <<= 1){ s1 += __shfl_xor(s1, m); s2 += __shfl_xor(s2, m); }
    float mu  = s1 * (1.f/512.f);
    float var = s2 * (1.f/512.f) - mu*mu;
    float istd = rsqrtf(var + 1e-5f);
    float o[8];
    #pragma unroll
    for (int j = 0; j < 8; j++) o[j] = (e[j] - mu)*istd*gv[j] + bev[j];
    store8(out + (size_t)(m0 + row)*DD + lane*8, o);
  }
}

extern "C" void kernel_launch(void* const* d_in, const int* in_sizes, int n_in,
                              void* d_out, int out_size, void* d_ws, size_t ws_size,
                              hipStream_t stream) {
  (void)in_sizes; (void)n_in; (void)out_size; (void)ws_size;
  const float* features = (const float*)d_in[0];
  const float* coords   = (const float*)d_in[1];
  const float* W_feat   = (const float*)d_in[2];
  const float* b_feat   = (const float*)d_in[3];
  const float* W_p1     = (const float*)d_in[4];
  const float* b_p1     = (const float*)d_in[5];
  const float* W_p2     = (const float*)d_in[6];
  const float* b_p2     = (const float*)d_in[7];
  const float* Wq = (const float*)d_in[8];  const float* bq = (const float*)d_in[9];
  const float* Wk = (const float*)d_in[10]; const float* bk = (const float*)d_in[11];
  const float* Wv = (const float*)d_in[12]; const float* bv = (const float*)d_in[13];
  const float* Wo = (const float*)d_in[14]; const float* bo = (const float*)d_in[15];
  const float* gamma = (const float*)d_in[16]; const float* beta = (const float*)d_in[17];
  float* out = (float*)d_out;

  char* ws = (char*)d_ws;
  size_t off = 0;
  auto alloc = [&](size_t bytes) -> void* {
    void* p = ws + off;
    off = (off + bytes + 255) & ~(size_t)255;
    return p;
  };
  u16*   featA     = (u16*)  alloc((size_t)NPTS*INDIM*2);   // 8.4 MB
  u16*   feat_bf   = (u16*)  alloc((size_t)NPTS*DD*2);      // 16.8 MB
  u16*   q_bf      = (u16*)  alloc((size_t)NPTS*DD*2);      // 16.8 MB
  u16*   agg_bf    = (u16*)  alloc((size_t)NPTS*DD*2);      // 16.8 MB
  u16*   W_feat_bf = (u16*)  alloc((size_t)INDIM*DD*2);     // [256][512]
  u16*   WqkvT     = (u16*)  alloc((size_t)1536*DD*2);      // [Wq^T;Wk^T;Wv^T]
  u16*   WoT       = (u16*)  alloc((size_t)DD*DD*2);
  u16*   WcatT     = (u16*)  alloc((size_t)512*INDIM*2);    // W_feat^T [512][256]
  u16*   Xout      = (u16*)  alloc((size_t)1536*INDIM*2);   // [WfqT(512); WfkvT(1024)][256]
  u16*   peD       = (u16*)  alloc((size_t)9*DD*2);
  u16*   meanF     = (u16*)  alloc((size_t)512*INDIM*2);
  float* meanKV    = (float*)alloc((size_t)640*1024*4);     // rows 0..511 mean-derived, 512..520 pe
  float* bfq       = (float*)alloc((size_t)DD*4);
  float* biaskv    = (float*)alloc((size_t)1024*4);
  int*   order     = (int*)  alloc((size_t)NPTS*4);
  int*   counts    = (int*)  alloc((size_t)NBATCH*GG*4);
  int*   cellstart = (int*)  alloc((size_t)NBATCH*GG*4);
  u16*   WfqT      = Xout;                                  // [512][256]
  u16*   WfkvT     = Xout + (size_t)512*INDIM;              // [1024][256]

  // 1. mega-prep (+rank)
  prep_kernel<<<P_NB, 256, 0, stream>>>(
      features, W_feat, Wq, Wk, Wv, Wo, W_p1, b_p1, W_p2, b_p2,
      b_feat, bq, bk, bv, coords,
      featA, W_feat_bf, WqkvT, WoT, WcatT, peD, bfq, biaskv,
      order, counts, cellstart);
  // 2. [WfqT;WfkvT] GEMM + peKV rows + meanF gather + feat GEMM
  mid_kernel<<<1084, 256, 0, stream>>>(
      WqkvT, W_feat_bf, peD, Xout, meanKV, featA, order, counts, cellstart,
      meanF, WcatT, b_feat, feat_bf);
  // 3. q GEMM + meanKV rows 0..511 GEMM
  qmean_kernel<<<544, 256, 0, stream>>>(
      featA, WfqT, meanF, WfkvT, bfq, biaskv, q_bf, meanKV);
  // 4. cell-centric attention -> agg
  attn_cells<<<NBATCH*GG, 1024, 0, stream>>>(q_bf, meanKV, order, counts, cellstart, agg_bf);
  // 5. fused lin GEMM + residual + layernorm
  linln_kernel<<<NPTS/64, 512, 0, stream>>>(agg_bf, WoT, bo, feat_bf, gamma, beta, out);
}